// Round 1
// baseline (371.918 us; speedup 1.0000x reference)
//
#include <hip/hip_runtime.h>
#include <hip/hip_bf16.h>
#include <type_traits>

typedef __hip_bfloat16 bf16;
typedef short bf16x8 __attribute__((ext_vector_type(8)));
typedef float f32x4 __attribute__((ext_vector_type(4)));

#define NB 8      // batch
#define SM 512    // block size M
#define SL 1024   // attn span L
#define SH 512    // hidden
#define NH 8      // heads
#define HD 64     // head dim
#define SN 1536   // M + L (key length)

static __device__ __forceinline__ short bf_bits(float x) {
  union { bf16 b; short s; } u; u.b = __float2bfloat16(x); return u.s;
}
static __device__ __forceinline__ bf16x8 ld8any(const bf16* p) {
  return *reinterpret_cast<const bf16x8*>(p);
}
static __device__ __forceinline__ bf16x8 ld8any(const float* p) {
  float4 a = *reinterpret_cast<const float4*>(p);
  float4 b = *reinterpret_cast<const float4*>(p + 4);
  bf16x8 r;
  r[0] = bf_bits(a.x); r[1] = bf_bits(a.y); r[2] = bf_bits(a.z); r[3] = bf_bits(a.w);
  r[4] = bf_bits(b.x); r[5] = bf_bits(b.y); r[6] = bf_bits(b.z); r[7] = bf_bits(b.w);
  return r;
}
static __device__ __forceinline__ void st1(bf16* p, float v) { *p = __float2bfloat16(v); }
static __device__ __forceinline__ void st1(float* p, float v) { *p = v; }
static __device__ __forceinline__ f32x4 mfma16(bf16x8 a, bf16x8 b, f32x4 c) {
  return __builtin_amdgcn_mfma_f32_16x16x32_bf16(a, b, c, 0, 0, 0);
}

// ---------------------------------------------------------------------------
// f32 -> bf16 bulk conversion, 8 el/thread, fully coalesced.
// ---------------------------------------------------------------------------
__global__ __launch_bounds__(256) void conv_bf16(const float* __restrict__ src,
                                                 bf16* __restrict__ dst) {
  const int i = blockIdx.x * 256 + threadIdx.x;
  *reinterpret_cast<bf16x8*>(dst + (size_t)i * 8) = ld8any(src + (size_t)i * 8);
}

__global__ __launch_bounds__(256) void conv_w4(const float* __restrict__ w0,
                                               const float* __restrict__ w1,
                                               const float* __restrict__ w2,
                                               const float* __restrict__ w3,
                                               bf16* __restrict__ dst) {
  const float* srcs[4] = {w0, w1, w2, w3};
  const float* s = srcs[blockIdx.y];
  bf16* d = dst + (size_t)blockIdx.y * 262144;
  const int i = blockIdx.x * 256 + threadIdx.x;
  *reinterpret_cast<bf16x8*>(d + (size_t)i * 8) = ld8any(s + (size_t)i * 8);
}

// ---------------------------------------------------------------------------
// Y[R x 512] = X[R x 512] @ W^T. BM=128, BN=64 (64 = head dim -> MODE1/2
// head-aligned). 4 waves, wave tile 64x32. grid = (R/128)*8, XCD-swizzled:
// id = xcd + 8*(yblk + 8*xhi); xblk = xcd + 8*xhi.
// MODE 0: row-major.  MODE 1: k_head [((b*8+h)*1536+s)*64+d] (direct, h=yblk).
// MODE 2: vT [((b*8+h)*64+d)*1536+s] (LDS-staged transpose).
// ---------------------------------------------------------------------------
#define T2STR 136

template <int MODE, typename TX, typename TW, typename TY>
__global__ __launch_bounds__(256) void gemmbn64(const TX* __restrict__ X,
                                                const TW* __restrict__ W,
                                                TY* __restrict__ Y) {
  __shared__ __align__(16) bf16 tile[(MODE == 2) ? 64 * T2STR : 8];
  const int id   = blockIdx.x;
  const int s_   = id >> 3;
  const int xblk = (id & 7) + 8 * (s_ >> 3);
  const int yblk = s_ & 7;
  const int tid  = threadIdx.x;
  const int lane = tid & 63, w = tid >> 6;
  const int col16 = lane & 15, quad = lane >> 4, kq = quad << 3;
  const int wm = w >> 1, wn = w & 1;
  const int m0 = xblk * 128 + wm * 64;
  const int n0 = yblk * 64 + wn * 32;
  const TX* xr = X + (size_t)(m0 + col16) * SH + kq;
  const TW* wr = W + (size_t)(n0 + col16) * SH + kq;
  f32x4 acc[4][2];
#pragma unroll
  for (int i = 0; i < 4; ++i)
#pragma unroll
    for (int j = 0; j < 2; ++j) acc[i][j] = f32x4{0.f,0.f,0.f,0.f};
#pragma unroll
  for (int k0 = 0; k0 < SH; k0 += 32) {
    bf16x8 af[4], bfr[2];
#pragma unroll
    for (int t = 0; t < 4; ++t) af[t]  = ld8any(xr + (size_t)(t*16) * SH + k0);
#pragma unroll
    for (int t = 0; t < 2; ++t) bfr[t] = ld8any(wr + (size_t)(t*16) * SH + k0);
#pragma unroll
    for (int mt = 0; mt < 4; ++mt)
#pragma unroll
      for (int nt = 0; nt < 2; ++nt)
        acc[mt][nt] = mfma16(af[mt], bfr[nt], acc[mt][nt]);
  }

  if constexpr (MODE == 0) {
#pragma unroll
    for (int mt = 0; mt < 4; ++mt)
#pragma unroll
      for (int r = 0; r < 4; ++r) {
        const int row = m0 + mt*16 + quad*4 + r;
        TY* yr = Y + (size_t)row * SH + n0 + col16;
        st1(yr,      acc[mt][0][r]);
        st1(yr + 16, acc[mt][1][r]);
      }
  } else if constexpr (MODE == 1) {
#pragma unroll
    for (int mt = 0; mt < 4; ++mt)
#pragma unroll
      for (int r = 0; r < 4; ++r) {
        const int row = m0 + mt*16 + quad*4 + r;
        const int b = row / SN, sr = row - b * SN;
        bf16* yr = (bf16*)Y + (size_t)((b*NH + yblk)*SN + sr) * HD
                 + wn*32 + col16;
        yr[0]  = __float2bfloat16(acc[mt][0][r]);
        yr[16] = __float2bfloat16(acc[mt][1][r]);
      }
  } else {
    // stage transposed: tile[d][row_loc]
#pragma unroll
    for (int mt = 0; mt < 4; ++mt)
#pragma unroll
      for (int r = 0; r < 4; ++r) {
        const int row_loc = wm*64 + mt*16 + quad*4 + r;
#pragma unroll
        for (int nt = 0; nt < 2; ++nt) {
          const int d = wn*32 + nt*16 + col16;
          tile[d * T2STR + row_loc] = __float2bfloat16(acc[mt][nt][r]);
        }
      }
    __syncthreads();
    const int d  = tid >> 2;      // 0..63
    const int hq = tid & 3;       // 32-row quarter
    const bf16* src = tile + d * T2STR + hq * 32;
    const int row0 = xblk*128 + hq*32;
    const int b = row0 / SN, sr0 = row0 - b * SN;
    bf16* dst = (bf16*)Y + (size_t)((b*NH + yblk)*HD + d) * SN + sr0;
#pragma unroll
    for (int i = 0; i < 4; ++i)
      reinterpret_cast<uint4*>(dst)[i] = reinterpret_cast<const uint4*>(src)[i];
  }
}

// ---------------------------------------------------------------------------
// peT[l][d] = bf16(pe[d][l])
// ---------------------------------------------------------------------------
__global__ void transpose_pe(const float* __restrict__ pe, bf16* __restrict__ peT) {
  int idx = blockIdx.x * 256 + threadIdx.x;
  int l = idx >> 6, d = idx & 63;
  peT[idx] = __float2bfloat16(pe[d * SL + l]);
}

// ---------------------------------------------------------------------------
// 4-wave fused attention: 16 rows/unit, one unit per 256-thread block.
// grid 2048. 2 barriers/chunk.
// Phase1 split: w0 cont{0,16}, w1 cont{32,48}, w2 cont{64}+pos{0},
// w3 pos{16,32,48}. Phase2: 16 lanes/row, 4 cols each. Phase3: d-tile=w*16.
//
// v2 (latency pipeline): all global reads are register-prefetched so no
// chunk-critical-path waits on cache latency:
//   - V fragments issued at chunk top, consumed in phase 3 (2 barriers later)
//   - K/peT fragments for chunk ch+1 issued right after phase-1 MFMAs of
//     chunk ch; in flight across both barriers (T14 issue-early pattern).
// ---------------------------------------------------------------------------
#define CSTR4 84
#define PSTR4 65
#define BSTR4 104

__global__ __launch_bounds__(256) void attn4(
    const bf16* __restrict__ qp, const bf16* __restrict__ Kh,
    const bf16* __restrict__ VT, const bf16* __restrict__ peT,
    const float* __restrict__ spanv, bf16* __restrict__ ctx) {
  __shared__ __align__(16) float cont_s[16][CSTR4];
  __shared__ __align__(16) float pos_s[16][PSTR4];
  __shared__ __align__(16) bf16  P_s[16][BSTR4];
  __shared__ float alpha_s[16];
  __shared__ float S_s[16];

  const int id = blockIdx.x;
  const int h  = id & 7;
  const int s_ = id >> 3;
  const int m0 = (s_ & 31) * 16;
  const int b  = s_ >> 5;
  const int hb = b * 8 + h;
  const int tid = threadIdx.x, lane = tid & 63, w = tid >> 6;
  const int col16 = lane & 15, quad = lane >> 4, kq = quad << 3;
  const int wr = quad << 2;

  // zero P band once (band positions are chunk-invariant; init visible after
  // the first phase-1 barrier, before any P_s read in phase 3)
  for (int i = tid; i < 16 * BSTR4; i += 256)
    (&P_s[0][0])[i] = __float2bfloat16(0.0f);

  const bf16* qb = qp + (size_t)(b*SM + m0 + col16) * SH + h*HD + kq;
  const bf16x8 qf0 = ld8any(qb), qf1 = ld8any(qb + 32);

  const bf16* kb = Kh + (size_t)(hb * SN) * HD + kq;
  const bf16* vb = VT + (size_t)(hb * HD) * SN;

  const int srow = tid >> 4, sj = tid & 15;  // softmax: 16 rows x 16 lanes
  float Mrun = -1.0e30f, Srun = 0.0f;
  const float span = spanv[h];
  const int dt = w * 16;
  f32x4 o = {0.f,0.f,0.f,0.f};

  // phase-1 operand registers (role-dependent; loaded one chunk ahead)
  bf16x8 f0, f1, f2, f3, f4, f5;
  auto loadP1 = [&](int l0p) {
    const int nbp = m0 + l0p;
    if (w < 2) {
      const bf16* kr0 = kb + (size_t)(nbp + w*32 + col16) * HD;
      f0 = ld8any(kr0);          f1 = ld8any(kr0 + 32);
      const bf16* kr1 = kr0 + 16 * HD;
      f2 = ld8any(kr1);          f3 = ld8any(kr1 + 32);
    } else if (w == 2) {
      const bf16* kr = kb + (size_t)(nbp + 64 + col16) * HD;
      f0 = ld8any(kr);           f1 = ld8any(kr + 32);
      const bf16* pr = peT + (size_t)(l0p + col16) * HD + kq;
      f2 = ld8any(pr);           f3 = ld8any(pr + 32);
    } else {
      const bf16* pr1 = peT + (size_t)(l0p + 16 + col16) * HD + kq;
      f0 = ld8any(pr1);             f1 = ld8any(pr1 + 32);
      f2 = ld8any(pr1 + 16*HD);     f3 = ld8any(pr1 + 16*HD + 32);
      f4 = ld8any(pr1 + 32*HD);     f5 = ld8any(pr1 + 32*HD + 32);
    }
  };

  loadP1(0);  // prologue: chunk-0 operands

  for (int ch = 0; ch < 16; ++ch) {
    const int l0 = ch << 6;
    const int nb_ = m0 + l0;   // abs key base; max 496+960, +79 < 1536

    // ---- early V issue (consumed in phase 3, two barriers from now) ----
    bf16x8 vf0, vf1, vf2;
    {
      const bf16* v0 = vb + (size_t)(dt + col16) * SN + nb_ + kq;
      vf0 = ld8any(v0);
      vf1 = ld8any(v0 + 32);
      vf2 = ld8any(v0 + 64);
    }

    // ---- phase 1: MFMA on operands prefetched last iteration ----
    if (w < 2) {
      f32x4 c0 = {0.f,0.f,0.f,0.f}, c1 = c0;
      c0 = mfma16(qf0, f0, c0);
      c0 = mfma16(qf1, f1, c0);
      c1 = mfma16(qf0, f2, c1);
      c1 = mfma16(qf1, f3, c1);
#pragma unroll
      for (int r = 0; r < 4; ++r) {
        cont_s[wr + r][w*32 + col16]      = c0[r];
        cont_s[wr + r][w*32 + 16 + col16] = c1[r];
      }
    } else if (w == 2) {
      f32x4 c0 = {0.f,0.f,0.f,0.f}, p0 = c0;
      c0 = mfma16(qf0, f0, c0);
      c0 = mfma16(qf1, f1, c0);
      p0 = mfma16(qf0, f2, p0);
      p0 = mfma16(qf1, f3, p0);
#pragma unroll
      for (int r = 0; r < 4; ++r) {
        cont_s[wr + r][64 + col16] = c0[r];
        pos_s[wr + r][col16]       = p0[r];
      }
    } else {
      f32x4 p1 = {0.f,0.f,0.f,0.f}, p2 = p1, p3 = p1;
      p1 = mfma16(qf0, f0, p1);
      p1 = mfma16(qf1, f1, p1);
      p2 = mfma16(qf0, f2, p2);
      p2 = mfma16(qf1, f3, p2);
      p3 = mfma16(qf0, f4, p3);
      p3 = mfma16(qf1, f5, p3);
#pragma unroll
      for (int r = 0; r < 4; ++r) {
        pos_s[wr + r][16 + col16] = p1[r];
        pos_s[wr + r][32 + col16] = p2[r];
        pos_s[wr + r][48 + col16] = p3[r];
      }
    }

    // ---- prefetch next chunk's phase-1 operands; loads stay in flight
    // across both barriers (plain global->VGPR loads are not drained by
    // __syncthreads). ch==15: re-issue chunk 15 (dead values, in-bounds).
    loadP1(ch < 15 ? (l0 + 64) : l0);

    __syncthreads();

    // ---- phase 2: combine + online softmax (4 cols/thread) ----
    float sc[4];
    float mc = -1.0e30f;
    const float* crow = &cont_s[srow][srow + sj*4];
    const float* prow = &pos_s[srow][sj*4];
#pragma unroll
    for (int i = 0; i < 4; ++i) {
      float v = (crow[i] + prow[i]) * 0.125f;
      sc[i] = v;
      mc = fmaxf(mc, v);
    }
    mc = fmaxf(mc, __shfl_xor(mc, 1));
    mc = fmaxf(mc, __shfl_xor(mc, 2));
    mc = fmaxf(mc, __shfl_xor(mc, 4));
    mc = fmaxf(mc, __shfl_xor(mc, 8));
    const float Mnew = fmaxf(Mrun, mc);
    const float alpha = __expf(Mrun - Mnew);
    float ls = 0.0f;
    bf16* pw = &P_s[srow][srow + sj*4];
#pragma unroll
    for (int i = 0; i < 4; ++i) {
      float p = __expf(sc[i] - Mnew);
      ls += p;
      const float tpl = (float)(l0 + sj*4 + i) - 1023.0f;
      float mv = (tpl + span * 1024.0f) * 0.03125f + 1.0f;
      mv = fminf(fmaxf(mv, 0.0f), 1.0f);
      pw[i] = __float2bfloat16(p * mv);
    }
    ls += __shfl_xor(ls, 1);
    ls += __shfl_xor(ls, 2);
    ls += __shfl_xor(ls, 4);
    ls += __shfl_xor(ls, 8);
    Srun = Srun * alpha + ls;
    Mrun = Mnew;
    if (sj == 0) { alpha_s[srow] = alpha; S_s[srow] = Srun; }
    __syncthreads();

    // ---- phase 3: rescale O, PV MFMA over 96-key band (V from regs) ----
    float al[4];
#pragma unroll
    for (int r = 0; r < 4; ++r) al[r] = alpha_s[wr + r];
#pragma unroll
    for (int r = 0; r < 4; ++r) o[r] *= al[r];
    {
      const bf16x8 ap0 = ld8any(&P_s[col16][kq]);
      o = mfma16(ap0, vf0, o);
      const bf16x8 ap1 = ld8any(&P_s[col16][32 + kq]);
      o = mfma16(ap1, vf1, o);
      const bf16x8 ap2 = ld8any(&P_s[col16][64 + kq]);
      o = mfma16(ap2, vf2, o);
    }
    // no barrier: next phase1 writes cont/pos only; P_s/alpha_s rewritten
    // only after the next phase1 barrier.
  }

  // ---- epilogue ----
#pragma unroll
  for (int r = 0; r < 4; ++r) {
    const float inv = 1.0f / S_s[wr + r];
    bf16* cr = ctx + (size_t)(b*SM + m0 + wr + r) * SH + h*HD + dt + col16;
    *cr = __float2bfloat16(o[r] * inv);
  }
}

// ---------------------------------------------------------------------------
// Fallback fused attention (round-6 proven): 16 rows/block, 2 waves, fused q.
// ---------------------------------------------------------------------------
#define MT 16
#define CSTR 84
#define PSTR 65
#define BSTR 104
#define QSTR 72

__global__ __launch_bounds__(128) void attn_kernel_fb(
    const float* __restrict__ query, const float* __restrict__ Wq,
    const bf16* __restrict__ Kh, const bf16* __restrict__ VT,
    const bf16* __restrict__ peT, const float* __restrict__ spanv,
    bf16* __restrict__ ctx) {
  __shared__ __align__(16) float cont_lds[MT][CSTR];
  __shared__ __align__(16) float pos_lds[MT][PSTR];
  __shared__ __align__(16) bf16  P_lds[MT][BSTR];
  __shared__ __align__(16) bf16  q_lds[MT*QSTR];
  __shared__ float alpha_lds[MT];
  __shared__ float S_lds[MT];

  const int id = blockIdx.x;
  const int h  = id & 7;
  const int s_ = id >> 3;
  const int m0 = (s_ & 31) * MT;
  const int b  = s_ >> 5;
  const int hb = b * 8 + h;
  const int tid  = threadIdx.x;
  const int lane = tid & 63;
  const int w    = tid >> 6;
  const int col16 = lane & 15, quad = lane >> 4, kq = quad << 3;
  const int wr = quad << 2;

  for (int i = tid; i < MT * BSTR; i += 128)
    (&P_lds[0][0])[i] = __float2bfloat16(0.0f);

  bf16x8 qf0, qf1;
  {
    f32x4 qa0 = {0.f,0.f,0.f,0.f}, qa1 = qa0;
    const float* xq = query + (size_t)(b*SM + m0 + col16) * SH + kq;
    const float* w0 = Wq + (size_t)(h*HD + w*32 + col16) * SH + kq;
    const float* w1 = w0 + (size_t)16 * SH;
#pragma unroll
    for (int k0 = 0; k0 < SH; k0 += 32) {
      bf16x8 xa = ld8any(xq + k0);
      qa0 = mfma16(xa, ld8any(w0 + k0), qa0);
      qa1 = mfma16(xa, ld8any(w1 + k0), qa1);
    }
#pragma unroll
    for (int r = 0; r < 4; ++r) {
      q_lds[(wr + r)*QSTR + w*32 + col16]      = __float2bfloat16(qa0[r]);
      q_lds[(wr + r)*QSTR + w*32 + 16 + col16] = __float2bfloat16(qa1[r]);
    }
    __syncthreads();
    qf0 = ld8any(&q_lds[col16*QSTR + kq]);
    qf1 = ld8any(&q_lds[col16*QSTR + kq + 32]);
  }

  const bf16* kb = Kh + (size_t)(hb * SN) * HD + kq;
  const bf16* vb = VT + (size_t)(hb * HD) * SN;

  const int srow = tid >> 3, sj = tid & 7;
  float Mrun = -1.0e30f, Srun = 0.0f;
  const float span = spanv[h];
  const int dt0 = w * 16, dt1 = (w + 2) * 16;
  f32x4 o0 = {0.f,0.f,0.f,0.f}, o1 = o0;

  for (int ch = 0; ch < 16; ++ch) {
    const int l0 = ch << 6;
    const int nb_ = m0 + l0;

    f32x4 ca0 = {0.f,0.f,0.f,0.f}, ca1 = ca0, ca2 = ca0, pa0 = ca0, pa1 = ca0;
    {
      const bf16* kr0 = kb + (size_t)(nb_ + w*16 + col16) * HD;
      ca0 = mfma16(qf0, ld8any(kr0),           ca0);
      ca0 = mfma16(qf1, ld8any(kr0 + 32),      ca0);
      const bf16* kr1 = kr0 + 32 * HD;
      ca1 = mfma16(qf0, ld8any(kr1),           ca1);
      ca1 = mfma16(qf1, ld8any(kr1 + 32),      ca1);
      if (w == 0) {
        const bf16* kr2 = kr0 + 64 * HD;
        ca2 = mfma16(qf0, ld8any(kr2),         ca2);
        ca2 = mfma16(qf1, ld8any(kr2 + 32),    ca2);
      }
      const bf16* pr0 = peT + (size_t)(l0 + w*16 + col16) * HD + kq;
      pa0 = mfma16(qf0, ld8any(pr0),           pa0);
      pa0 = mfma16(qf1, ld8any(pr0 + 32),      pa0);
      const bf16* pr1 = pr0 + 32 * HD;
      pa1 = mfma16(qf0, ld8any(pr1),           pa1);
      pa1 = mfma16(qf1, ld8any(pr1 + 32),      pa1);
    }
#pragma unroll
    for (int r = 0; r < 4; ++r) {
      cont_lds[wr + r][w*16 + col16]      = ca0[r];
      cont_lds[wr + r][w*16 + 32 + col16] = ca1[r];
      if (w == 0) cont_lds[wr + r][64 + col16] = ca2[r];
      pos_lds[wr + r][w*16 + col16]       = pa0[r];
      pos_lds[wr + r][w*16 + 32 + col16]  = pa1[r];
    }
    __syncthreads();

    float sc[8];
    float mc = -1.0e30f;
    const float* crow = &cont_lds[srow][srow + sj*8];
    const float* prow = &pos_lds[srow][sj*8];
#pragma unroll
    for (int i = 0; i < 8; ++i) {
      float v = (crow[i] + prow[i]) * 0.125f;
      sc[i] = v;
      mc = fmaxf(mc, v);
    }
    mc = fmaxf(mc, __shfl_xor(mc, 1));
    mc = fmaxf(mc, __shfl_xor(mc, 2));
    mc = fmaxf(mc, __shfl_xor(mc, 4));
    const float Mnew = fmaxf(Mrun, mc);
    const float alpha = __expf(Mrun - Mnew);
    float ls = 0.0f;
    bf16* pwrow = &P_lds[srow][srow + sj*8];
#pragma unroll
    for (int i = 0; i < 8; ++i) {
      float p = __expf(sc[i] - Mnew);
      ls += p;
      const float tpl = (float)(l0 + sj*8 + i) - 1023.0f;
      float mv = (tpl + span * 1024.0f) * 0.03125f + 1.0f;
      mv = fminf(fmaxf(mv, 0.0f), 1.0f);
      pwrow[i] = __float2bfloat16(p * mv);
    }
    ls += __shfl_xor(ls, 1);
    ls += __shfl_xor(ls, 2);
    ls += __shfl_xor(ls, 4);
    Srun = Srun * alpha + ls;
    Mrun = Mnew;
    if (sj == 0) { alpha_lds[srow] = alpha; S_lds[srow] = Srun; }
    __syncthreads();

    float al[4];
#pragma unroll
    for (int r = 0; r < 4; ++r) al[r] = alpha_lds[wr + r];
#pragma unroll
    for (int r = 0; r < 4; ++r) { o0[r] *= al[r]; o1[r] *= al[r]; }
#pragma unroll
    for (int ks = 0; ks < 3; ++ks) {
      const bf16x8 ap = ld8any(&P_lds[col16][ks*32 + kq]);
      const bf16* v0 = vb + (size_t)(dt0 + col16) * SN + nb_ + ks*32 + kq;
      const bf16* v1 = vb + (size_t)(dt1 + col16) * SN + nb_ + ks*32 + kq;
      o0 = mfma16(ap, ld8any(v0), o0);
      o1 = mfma16(ap, ld8any(v1), o1);
    }
  }

  bf16* cr = ctx + (size_t)(b*SM + m0 + wr) * SH + h*HD + col16;
#pragma unroll
  for (int r = 0; r < 4; ++r) {
    const float inv = 1.0f / S_lds[wr + r];
    cr[(size_t)r * SH + dt0] = __float2bfloat16(o0[r] * inv);
    cr[(size_t)r * SH + dt1] = __float2bfloat16(o1[r] * inv);
  }
}

// ---------------------------------------------------------------------------
extern "C" void kernel_launch(void* const* d_in, const int* in_sizes, int n_in,
                              void* d_out, int out_size, void* d_ws, size_t ws_size,
                              hipStream_t stream) {
  const float* query  = (const float*)d_in[0];
  const float* key    = (const float*)d_in[1];
  const float* value  = (const float*)d_in[2];
  const float* key_pe = (const float*)d_in[3];
  const float* Wq     = (const float*)d_in[4];
  const float* Wk     = (const float*)d_in[5];
  const float* Wv     = (const float*)d_in[6];
  const float* Wo     = (const float*)d_in[7];
  const float* spanv  = (const float*)d_in[8];
  float* out = (float*)d_out;

  bf16* ws = (bf16*)d_ws;
  if (ws_size >= (size_t)48365568) {
    // Path C: bf16-converted pipeline, 48.4 MB ws.
    bf16* stg    = ws;                    // 6291456 el, reused key->value
    bf16* k_head = stg    + 6291456;
    bf16* vT     = k_head + 6291456;
    bf16* qp     = vT     + 6291456;
    bf16* ctx    = qp     + 2097152;
    bf16* peT    = ctx    + 2097152;
    bf16* Wb     = peT    + 65536;
    bf16* Wq_b = Wb, *Wk_b = Wb + 262144, *Wv_b = Wb + 524288, *Wo_b = Wb + 786432;

    conv_w4<<<dim3(128, 4), 256, 0, stream>>>(Wq, Wk, Wv, Wo, Wb);
    transpose_pe<<<256, 256, 0, stream>>>(key_pe, peT);

    conv_bf16<<<3072, 256, 0, stream>>>(key, stg);
    gemmbn64<1, bf16, bf16, bf16><<<768, 256, 0, stream>>>(stg, Wk_b, k_head);
    conv_bf16<<<3072, 256, 0, stream>>>(value, stg);
    gemmbn64<2, bf16, bf16, bf16><<<768, 256, 0, stream>>>(stg, Wv_b, vT);
    gemmbn64<0, float, bf16, bf16><<<256, 256, 0, stream>>>(query, Wq_b, qp);

    attn4<<<2048, 256, 0, stream>>>(qp, k_head, vT, peT, spanv, ctx);
    gemmbn64<0, bf16, bf16, float><<<256, 256, 0, stream>>>(ctx, Wo_b, out);
  } else {
    // Path B (fallback): fused-q attention, f32 GEMM reads, 29.5 MB ws.
    bf16* k_head = ws;
    bf16* vT     = k_head + 6291456;
    bf16* ctx    = vT     + 6291456;
    bf16* peT    = ctx    + 2097152;
    gemmbn64<1, float, float, bf16><<<768, 256, 0, stream>>>(key,   Wk, k_head);
    gemmbn64<2, float, float, bf16><<<768, 256, 0, stream>>>(value, Wv, vT);
    transpose_pe<<<256, 256, 0, stream>>>(key_pe, peT);
    attn_kernel_fb<<<2048, 128, 0, stream>>>(query, Wq, k_head, vT,
                                             peT, spanv, ctx);
    gemmbn64<0, bf16, float, float><<<256, 256, 0, stream>>>(ctx, Wo, out);
  }
}

// Round 2
// 334.969 us; speedup vs baseline: 1.1103x; 1.1103x over previous
//
#include <hip/hip_runtime.h>
#include <hip/hip_bf16.h>
#include <type_traits>

typedef __hip_bfloat16 bf16;
typedef short bf16x8 __attribute__((ext_vector_type(8)));
typedef float f32x4 __attribute__((ext_vector_type(4)));

#define NB 8      // batch
#define SM 512    // block size M
#define SL 1024   // attn span L
#define SH 512    // hidden
#define NH 8      // heads
#define HD 64     // head dim
#define SN 1536   // M + L (key length)

static __device__ __forceinline__ short bf_bits(float x) {
  union { bf16 b; short s; } u; u.b = __float2bfloat16(x); return u.s;
}
static __device__ __forceinline__ bf16x8 ld8any(const bf16* p) {
  return *reinterpret_cast<const bf16x8*>(p);
}
static __device__ __forceinline__ bf16x8 ld8any(const float* p) {
  float4 a = *reinterpret_cast<const float4*>(p);
  float4 b = *reinterpret_cast<const float4*>(p + 4);
  bf16x8 r;
  r[0] = bf_bits(a.x); r[1] = bf_bits(a.y); r[2] = bf_bits(a.z); r[3] = bf_bits(a.w);
  r[4] = bf_bits(b.x); r[5] = bf_bits(b.y); r[6] = bf_bits(b.z); r[7] = bf_bits(b.w);
  return r;
}
static __device__ __forceinline__ void st1(bf16* p, float v) { *p = __float2bfloat16(v); }
static __device__ __forceinline__ void st1(float* p, float v) { *p = v; }
static __device__ __forceinline__ f32x4 mfma16(bf16x8 a, bf16x8 b, f32x4 c) {
  return __builtin_amdgcn_mfma_f32_16x16x32_bf16(a, b, c, 0, 0, 0);
}

// ---------------------------------------------------------------------------
// f32 -> bf16 bulk conversion, 8 el/thread, fully coalesced.
// ---------------------------------------------------------------------------
__global__ __launch_bounds__(256) void conv_bf16(const float* __restrict__ src,
                                                 bf16* __restrict__ dst) {
  const int i = blockIdx.x * 256 + threadIdx.x;
  *reinterpret_cast<bf16x8*>(dst + (size_t)i * 8) = ld8any(src + (size_t)i * 8);
}

__global__ __launch_bounds__(256) void conv_w4(const float* __restrict__ w0,
                                               const float* __restrict__ w1,
                                               const float* __restrict__ w2,
                                               const float* __restrict__ w3,
                                               bf16* __restrict__ dst) {
  const float* srcs[4] = {w0, w1, w2, w3};
  const float* s = srcs[blockIdx.y];
  bf16* d = dst + (size_t)blockIdx.y * 262144;
  const int i = blockIdx.x * 256 + threadIdx.x;
  *reinterpret_cast<bf16x8*>(d + (size_t)i * 8) = ld8any(s + (size_t)i * 8);
}

// ---------------------------------------------------------------------------
// Y[R x 512] = X[R x 512] @ W^T. BM=128, BN=64 (64 = head dim -> MODE1/2
// head-aligned). 4 waves, wave tile 64x32. grid = (R/128)*8, XCD-swizzled:
// id = xcd + 8*(yblk + 8*xhi); xblk = xcd + 8*xhi.
// MODE 0: row-major.  MODE 1: k_head [((b*8+h)*1536+s)*64+d] (direct, h=yblk).
// MODE 2: vT [((b*8+h)*64+d)*1536+s] (LDS-staged transpose).
// ---------------------------------------------------------------------------
#define T2STR 136

template <int MODE, typename TX, typename TW, typename TY>
__global__ __launch_bounds__(256) void gemmbn64(const TX* __restrict__ X,
                                                const TW* __restrict__ W,
                                                TY* __restrict__ Y) {
  __shared__ __align__(16) bf16 tile[(MODE == 2) ? 64 * T2STR : 8];
  const int id   = blockIdx.x;
  const int s_   = id >> 3;
  const int xblk = (id & 7) + 8 * (s_ >> 3);
  const int yblk = s_ & 7;
  const int tid  = threadIdx.x;
  const int lane = tid & 63, w = tid >> 6;
  const int col16 = lane & 15, quad = lane >> 4, kq = quad << 3;
  const int wm = w >> 1, wn = w & 1;
  const int m0 = xblk * 128 + wm * 64;
  const int n0 = yblk * 64 + wn * 32;
  const TX* xr = X + (size_t)(m0 + col16) * SH + kq;
  const TW* wr = W + (size_t)(n0 + col16) * SH + kq;
  f32x4 acc[4][2];
#pragma unroll
  for (int i = 0; i < 4; ++i)
#pragma unroll
    for (int j = 0; j < 2; ++j) acc[i][j] = f32x4{0.f,0.f,0.f,0.f};
#pragma unroll
  for (int k0 = 0; k0 < SH; k0 += 32) {
    bf16x8 af[4], bfr[2];
#pragma unroll
    for (int t = 0; t < 4; ++t) af[t]  = ld8any(xr + (size_t)(t*16) * SH + k0);
#pragma unroll
    for (int t = 0; t < 2; ++t) bfr[t] = ld8any(wr + (size_t)(t*16) * SH + k0);
#pragma unroll
    for (int mt = 0; mt < 4; ++mt)
#pragma unroll
      for (int nt = 0; nt < 2; ++nt)
        acc[mt][nt] = mfma16(af[mt], bfr[nt], acc[mt][nt]);
  }

  if constexpr (MODE == 0) {
#pragma unroll
    for (int mt = 0; mt < 4; ++mt)
#pragma unroll
      for (int r = 0; r < 4; ++r) {
        const int row = m0 + mt*16 + quad*4 + r;
        TY* yr = Y + (size_t)row * SH + n0 + col16;
        st1(yr,      acc[mt][0][r]);
        st1(yr + 16, acc[mt][1][r]);
      }
  } else if constexpr (MODE == 1) {
#pragma unroll
    for (int mt = 0; mt < 4; ++mt)
#pragma unroll
      for (int r = 0; r < 4; ++r) {
        const int row = m0 + mt*16 + quad*4 + r;
        const int b = row / SN, sr = row - b * SN;
        bf16* yr = (bf16*)Y + (size_t)((b*NH + yblk)*SN + sr) * HD
                 + wn*32 + col16;
        yr[0]  = __float2bfloat16(acc[mt][0][r]);
        yr[16] = __float2bfloat16(acc[mt][1][r]);
      }
  } else {
    // stage transposed: tile[d][row_loc]
#pragma unroll
    for (int mt = 0; mt < 4; ++mt)
#pragma unroll
      for (int r = 0; r < 4; ++r) {
        const int row_loc = wm*64 + mt*16 + quad*4 + r;
#pragma unroll
        for (int nt = 0; nt < 2; ++nt) {
          const int d = wn*32 + nt*16 + col16;
          tile[d * T2STR + row_loc] = __float2bfloat16(acc[mt][nt][r]);
        }
      }
    __syncthreads();
    const int d  = tid >> 2;      // 0..63
    const int hq = tid & 3;       // 32-row quarter
    const bf16* src = tile + d * T2STR + hq * 32;
    const int row0 = xblk*128 + hq*32;
    const int b = row0 / SN, sr0 = row0 - b * SN;
    bf16* dst = (bf16*)Y + (size_t)((b*NH + yblk)*HD + d) * SN + sr0;
#pragma unroll
    for (int i = 0; i < 4; ++i)
      reinterpret_cast<uint4*>(dst)[i] = reinterpret_cast<const uint4*>(src)[i];
  }
}

// ---------------------------------------------------------------------------
// peT[l][d] = bf16(pe[d][l])
// ---------------------------------------------------------------------------
__global__ void transpose_pe(const float* __restrict__ pe, bf16* __restrict__ peT) {
  int idx = blockIdx.x * 256 + threadIdx.x;
  int l = idx >> 6, d = idx & 63;
  peT[idx] = __float2bfloat16(pe[d * SL + l]);
}

// ---------------------------------------------------------------------------
// 4-wave fused attention: 16 rows/unit, one unit per 256-thread block.
// grid 2048. 2 barriers/chunk.
// Phase1 split: w0 cont{0,16}, w1 cont{32,48}, w2 cont{64}+pos{0},
// w3 pos{16,32,48}. Phase2: 16 lanes/row, 4 cols each. Phase3: d-tile=w*16.
//
// v3 (latency pipeline, spill-free): all global reads register-prefetched:
//   - V fragments issued at chunk top, consumed in phase 3 (2 barriers later)
//   - K/peT fragments for chunk ch+1 issued right after phase-1 MFMAs of
//     chunk ch; in flight across both barriers (T14 issue-early pattern).
// __launch_bounds__(256,2) -> VGPR cap 256: v2's 52-reg budget spilled the
// cross-barrier fragments to scratch (WRITE_SIZE 4->22.5 MB); this gives the
// allocator room to keep them in registers.
// ---------------------------------------------------------------------------
#define CSTR4 84
#define PSTR4 65
#define BSTR4 104

#define LOADP1(L0P)                                                          \
  {                                                                          \
    const int nbp_ = m0 + (L0P);                                             \
    if (w < 2) {                                                             \
      const bf16* kr0 = kb + (size_t)(nbp_ + w*32 + col16) * HD;             \
      f0 = ld8any(kr0);            f1 = ld8any(kr0 + 32);                    \
      f2 = ld8any(kr0 + 16*HD);    f3 = ld8any(kr0 + 16*HD + 32);            \
    } else if (w == 2) {                                                     \
      const bf16* kr = kb + (size_t)(nbp_ + 64 + col16) * HD;                \
      f0 = ld8any(kr);             f1 = ld8any(kr + 32);                     \
      const bf16* pr = peT + (size_t)((L0P) + col16) * HD + kq;              \
      f2 = ld8any(pr);             f3 = ld8any(pr + 32);                     \
    } else {                                                                 \
      const bf16* pr1 = peT + (size_t)((L0P) + 16 + col16) * HD + kq;        \
      f0 = ld8any(pr1);            f1 = ld8any(pr1 + 32);                    \
      f2 = ld8any(pr1 + 16*HD);    f3 = ld8any(pr1 + 16*HD + 32);            \
      f4 = ld8any(pr1 + 32*HD);    f5 = ld8any(pr1 + 32*HD + 32);            \
    }                                                                        \
  }

__global__ __launch_bounds__(256, 2) void attn4(
    const bf16* __restrict__ qp, const bf16* __restrict__ Kh,
    const bf16* __restrict__ VT, const bf16* __restrict__ peT,
    const float* __restrict__ spanv, bf16* __restrict__ ctx) {
  __shared__ __align__(16) float cont_s[16][CSTR4];
  __shared__ __align__(16) float pos_s[16][PSTR4];
  __shared__ __align__(16) bf16  P_s[16][BSTR4];
  __shared__ float alpha_s[16];
  __shared__ float S_s[16];

  const int id = blockIdx.x;
  const int h  = id & 7;
  const int s_ = id >> 3;
  const int m0 = (s_ & 31) * 16;
  const int b  = s_ >> 5;
  const int hb = b * 8 + h;
  const int tid = threadIdx.x, lane = tid & 63, w = tid >> 6;
  const int col16 = lane & 15, quad = lane >> 4, kq = quad << 3;
  const int wr = quad << 2;

  // zero P band once (band positions are chunk-invariant; init visible after
  // the first phase-1 barrier, before any P_s read in phase 3)
  for (int i = tid; i < 16 * BSTR4; i += 256)
    (&P_s[0][0])[i] = __float2bfloat16(0.0f);

  const bf16* qb = qp + (size_t)(b*SM + m0 + col16) * SH + h*HD + kq;
  const bf16x8 qf0 = ld8any(qb), qf1 = ld8any(qb + 32);

  const bf16* kb = Kh + (size_t)(hb * SN) * HD + kq;
  const bf16* vb = VT + (size_t)(hb * HD) * SN;

  const int srow = tid >> 4, sj = tid & 15;  // softmax: 16 rows x 16 lanes
  float Mrun = -1.0e30f, Srun = 0.0f;
  const float span = spanv[h];
  const int dt = w * 16;
  f32x4 o = {0.f,0.f,0.f,0.f};

  // phase-1 operand registers (role-dependent; loaded one chunk ahead)
  bf16x8 f0, f1, f2, f3, f4, f5;

  LOADP1(0);  // prologue: chunk-0 operands

  for (int ch = 0; ch < 16; ++ch) {
    const int l0 = ch << 6;
    const int nb_ = m0 + l0;   // abs key base; max 496+960, +79 < 1536

    // ---- early V issue (consumed in phase 3, two barriers from now) ----
    bf16x8 vf0, vf1, vf2;
    {
      const bf16* v0 = vb + (size_t)(dt + col16) * SN + nb_ + kq;
      vf0 = ld8any(v0);
      vf1 = ld8any(v0 + 32);
      vf2 = ld8any(v0 + 64);
    }

    // ---- phase 1: MFMA on operands prefetched last iteration ----
    if (w < 2) {
      f32x4 c0 = {0.f,0.f,0.f,0.f}, c1 = c0;
      c0 = mfma16(qf0, f0, c0);
      c0 = mfma16(qf1, f1, c0);
      c1 = mfma16(qf0, f2, c1);
      c1 = mfma16(qf1, f3, c1);
#pragma unroll
      for (int r = 0; r < 4; ++r) {
        cont_s[wr + r][w*32 + col16]      = c0[r];
        cont_s[wr + r][w*32 + 16 + col16] = c1[r];
      }
    } else if (w == 2) {
      f32x4 c0 = {0.f,0.f,0.f,0.f}, p0 = c0;
      c0 = mfma16(qf0, f0, c0);
      c0 = mfma16(qf1, f1, c0);
      p0 = mfma16(qf0, f2, p0);
      p0 = mfma16(qf1, f3, p0);
#pragma unroll
      for (int r = 0; r < 4; ++r) {
        cont_s[wr + r][64 + col16] = c0[r];
        pos_s[wr + r][col16]       = p0[r];
      }
    } else {
      f32x4 p1 = {0.f,0.f,0.f,0.f}, p2 = p1, p3 = p1;
      p1 = mfma16(qf0, f0, p1);
      p1 = mfma16(qf1, f1, p1);
      p2 = mfma16(qf0, f2, p2);
      p2 = mfma16(qf1, f3, p2);
      p3 = mfma16(qf0, f4, p3);
      p3 = mfma16(qf1, f5, p3);
#pragma unroll
      for (int r = 0; r < 4; ++r) {
        pos_s[wr + r][16 + col16] = p1[r];
        pos_s[wr + r][32 + col16] = p2[r];
        pos_s[wr + r][48 + col16] = p3[r];
      }
    }

    // ---- prefetch next chunk's phase-1 operands; loads stay in flight
    // across both barriers (plain global->VGPR loads are not drained by
    // __syncthreads). ch==15: re-issue chunk 15 (dead values, in-bounds).
    LOADP1(ch < 15 ? (l0 + 64) : l0);

    __syncthreads();

    // ---- phase 2: combine + online softmax (4 cols/thread) ----
    float sc[4];
    float mc = -1.0e30f;
    const float* crow = &cont_s[srow][srow + sj*4];
    const float* prow = &pos_s[srow][sj*4];
#pragma unroll
    for (int i = 0; i < 4; ++i) {
      float v = (crow[i] + prow[i]) * 0.125f;
      sc[i] = v;
      mc = fmaxf(mc, v);
    }
    mc = fmaxf(mc, __shfl_xor(mc, 1));
    mc = fmaxf(mc, __shfl_xor(mc, 2));
    mc = fmaxf(mc, __shfl_xor(mc, 4));
    mc = fmaxf(mc, __shfl_xor(mc, 8));
    const float Mnew = fmaxf(Mrun, mc);
    const float alpha = __expf(Mrun - Mnew);
    float ls = 0.0f;
    bf16* pw = &P_s[srow][srow + sj*4];
#pragma unroll
    for (int i = 0; i < 4; ++i) {
      float p = __expf(sc[i] - Mnew);
      ls += p;
      const float tpl = (float)(l0 + sj*4 + i) - 1023.0f;
      float mv = (tpl + span * 1024.0f) * 0.03125f + 1.0f;
      mv = fminf(fmaxf(mv, 0.0f), 1.0f);
      pw[i] = __float2bfloat16(p * mv);
    }
    ls += __shfl_xor(ls, 1);
    ls += __shfl_xor(ls, 2);
    ls += __shfl_xor(ls, 4);
    ls += __shfl_xor(ls, 8);
    Srun = Srun * alpha + ls;
    Mrun = Mnew;
    if (sj == 0) { alpha_s[srow] = alpha; S_s[srow] = Srun; }
    __syncthreads();

    // ---- phase 3: rescale O, PV MFMA over 96-key band (V from regs) ----
    float al[4];
#pragma unroll
    for (int r = 0; r < 4; ++r) al[r] = alpha_s[wr + r];
#pragma unroll
    for (int r = 0; r < 4; ++r) o[r] *= al[r];
    {
      const bf16x8 ap0 = ld8any(&P_s[col16][kq]);
      o = mfma16(ap0, vf0, o);
      const bf16x8 ap1 = ld8any(&P_s[col16][32 + kq]);
      o = mfma16(ap1, vf1, o);
      const bf16x8 ap2 = ld8any(&P_s[col16][64 + kq]);
      o = mfma16(ap2, vf2, o);
    }
    // no barrier: next phase1 writes cont/pos only; P_s/alpha_s rewritten
    // only after the next phase1 barrier.
  }

  // ---- epilogue ----
#pragma unroll
  for (int r = 0; r < 4; ++r) {
    const float inv = 1.0f / S_s[wr + r];
    bf16* cr = ctx + (size_t)(b*SM + m0 + wr + r) * SH + h*HD + dt + col16;
    *cr = __float2bfloat16(o[r] * inv);
  }
}

// ---------------------------------------------------------------------------
// Fallback fused attention (round-6 proven): 16 rows/block, 2 waves, fused q.
// ---------------------------------------------------------------------------
#define MT 16
#define CSTR 84
#define PSTR 65
#define BSTR 104
#define QSTR 72

__global__ __launch_bounds__(128) void attn_kernel_fb(
    const float* __restrict__ query, const float* __restrict__ Wq,
    const bf16* __restrict__ Kh, const bf16* __restrict__ VT,
    const bf16* __restrict__ peT, const float* __restrict__ spanv,
    bf16* __restrict__ ctx) {
  __shared__ __align__(16) float cont_lds[MT][CSTR];
  __shared__ __align__(16) float pos_lds[MT][PSTR];
  __shared__ __align__(16) bf16  P_lds[MT][BSTR];
  __shared__ __align__(16) bf16  q_lds[MT*QSTR];
  __shared__ float alpha_lds[MT];
  __shared__ float S_lds[MT];

  const int id = blockIdx.x;
  const int h  = id & 7;
  const int s_ = id >> 3;
  const int m0 = (s_ & 31) * MT;
  const int b  = s_ >> 5;
  const int hb = b * 8 + h;
  const int tid  = threadIdx.x;
  const int lane = tid & 63;
  const int w    = tid >> 6;
  const int col16 = lane & 15, quad = lane >> 4, kq = quad << 3;
  const int wr = quad << 2;

  for (int i = tid; i < MT * BSTR; i += 128)
    (&P_lds[0][0])[i] = __float2bfloat16(0.0f);

  bf16x8 qf0, qf1;
  {
    f32x4 qa0 = {0.f,0.f,0.f,0.f}, qa1 = qa0;
    const float* xq = query + (size_t)(b*SM + m0 + col16) * SH + kq;
    const float* w0 = Wq + (size_t)(h*HD + w*32 + col16) * SH + kq;
    const float* w1 = w0 + (size_t)16 * SH;
#pragma unroll
    for (int k0 = 0; k0 < SH; k0 += 32) {
      bf16x8 xa = ld8any(xq + k0);
      qa0 = mfma16(xa, ld8any(w0 + k0), qa0);
      qa1 = mfma16(xa, ld8any(w1 + k0), qa1);
    }
#pragma unroll
    for (int r = 0; r < 4; ++r) {
      q_lds[(wr + r)*QSTR + w*32 + col16]      = __float2bfloat16(qa0[r]);
      q_lds[(wr + r)*QSTR + w*32 + 16 + col16] = __float2bfloat16(qa1[r]);
    }
    __syncthreads();
    qf0 = ld8any(&q_lds[col16*QSTR + kq]);
    qf1 = ld8any(&q_lds[col16*QSTR + kq + 32]);
  }

  const bf16* kb = Kh + (size_t)(hb * SN) * HD + kq;
  const bf16* vb = VT + (size_t)(hb * HD) * SN;

  const int srow = tid >> 3, sj = tid & 7;
  float Mrun = -1.0e30f, Srun = 0.0f;
  const float span = spanv[h];
  const int dt0 = w * 16, dt1 = (w + 2) * 16;
  f32x4 o0 = {0.f,0.f,0.f,0.f}, o1 = o0;

  for (int ch = 0; ch < 16; ++ch) {
    const int l0 = ch << 6;
    const int nb_ = m0 + l0;

    f32x4 ca0 = {0.f,0.f,0.f,0.f}, ca1 = ca0, ca2 = ca0, pa0 = ca0, pa1 = ca0;
    {
      const bf16* kr0 = kb + (size_t)(nb_ + w*16 + col16) * HD;
      ca0 = mfma16(qf0, ld8any(kr0),           ca0);
      ca0 = mfma16(qf1, ld8any(kr0 + 32),      ca0);
      const bf16* kr1 = kr0 + 32 * HD;
      ca1 = mfma16(qf0, ld8any(kr1),           ca1);
      ca1 = mfma16(qf1, ld8any(kr1 + 32),      ca1);
      if (w == 0) {
        const bf16* kr2 = kr0 + 64 * HD;
        ca2 = mfma16(qf0, ld8any(kr2),         ca2);
        ca2 = mfma16(qf1, ld8any(kr2 + 32),    ca2);
      }
      const bf16* pr0 = peT + (size_t)(l0 + w*16 + col16) * HD + kq;
      pa0 = mfma16(qf0, ld8any(pr0),           pa0);
      pa0 = mfma16(qf1, ld8any(pr0 + 32),      pa0);
      const bf16* pr1 = pr0 + 32 * HD;
      pa1 = mfma16(qf0, ld8any(pr1),           pa1);
      pa1 = mfma16(qf1, ld8any(pr1 + 32),      pa1);
    }
#pragma unroll
    for (int r = 0; r < 4; ++r) {
      cont_lds[wr + r][w*16 + col16]      = ca0[r];
      cont_lds[wr + r][w*16 + 32 + col16] = ca1[r];
      if (w == 0) cont_lds[wr + r][64 + col16] = ca2[r];
      pos_lds[wr + r][w*16 + col16]       = pa0[r];
      pos_lds[wr + r][w*16 + 32 + col16]  = pa1[r];
    }
    __syncthreads();

    float sc[8];
    float mc = -1.0e30f;
    const float* crow = &cont_lds[srow][srow + sj*8];
    const float* prow = &pos_lds[srow][sj*8];
#pragma unroll
    for (int i = 0; i < 8; ++i) {
      float v = (crow[i] + prow[i]) * 0.125f;
      sc[i] = v;
      mc = fmaxf(mc, v);
    }
    mc = fmaxf(mc, __shfl_xor(mc, 1));
    mc = fmaxf(mc, __shfl_xor(mc, 2));
    mc = fmaxf(mc, __shfl_xor(mc, 4));
    const float Mnew = fmaxf(Mrun, mc);
    const float alpha = __expf(Mrun - Mnew);
    float ls = 0.0f;
    bf16* pwrow = &P_lds[srow][srow + sj*8];
#pragma unroll
    for (int i = 0; i < 8; ++i) {
      float p = __expf(sc[i] - Mnew);
      ls += p;
      const float tpl = (float)(l0 + sj*8 + i) - 1023.0f;
      float mv = (tpl + span * 1024.0f) * 0.03125f + 1.0f;
      mv = fminf(fmaxf(mv, 0.0f), 1.0f);
      pwrow[i] = __float2bfloat16(p * mv);
    }
    ls += __shfl_xor(ls, 1);
    ls += __shfl_xor(ls, 2);
    ls += __shfl_xor(ls, 4);
    Srun = Srun * alpha + ls;
    Mrun = Mnew;
    if (sj == 0) { alpha_lds[srow] = alpha; S_lds[srow] = Srun; }
    __syncthreads();

    float al[4];
#pragma unroll
    for (int r = 0; r < 4; ++r) al[r] = alpha_lds[wr + r];
#pragma unroll
    for (int r = 0; r < 4; ++r) { o0[r] *= al[r]; o1[r] *= al[r]; }
#pragma unroll
    for (int ks = 0; ks < 3; ++ks) {
      const bf16x8 ap = ld8any(&P_lds[col16][ks*32 + kq]);
      const bf16* v0 = vb + (size_t)(dt0 + col16) * SN + nb_ + ks*32 + kq;
      const bf16* v1 = vb + (size_t)(dt1 + col16) * SN + nb_ + ks*32 + kq;
      o0 = mfma16(ap, ld8any(v0), o0);
      o1 = mfma16(ap, ld8any(v1), o1);
    }
  }

  bf16* cr = ctx + (size_t)(b*SM + m0 + wr) * SH + h*HD + col16;
#pragma unroll
  for (int r = 0; r < 4; ++r) {
    const float inv = 1.0f / S_lds[wr + r];
    cr[(size_t)r * SH + dt0] = __float2bfloat16(o0[r] * inv);
    cr[(size_t)r * SH + dt1] = __float2bfloat16(o1[r] * inv);
  }
}

// ---------------------------------------------------------------------------
extern "C" void kernel_launch(void* const* d_in, const int* in_sizes, int n_in,
                              void* d_out, int out_size, void* d_ws, size_t ws_size,
                              hipStream_t stream) {
  const float* query  = (const float*)d_in[0];
  const float* key    = (const float*)d_in[1];
  const float* value  = (const float*)d_in[2];
  const float* key_pe = (const float*)d_in[3];
  const float* Wq     = (const float*)d_in[4];
  const float* Wk     = (const float*)d_in[5];
  const float* Wv     = (const float*)d_in[6];
  const float* Wo     = (const float*)d_in[7];
  const float* spanv  = (const float*)d_in[8];
  float* out = (float*)d_out;

  bf16* ws = (bf16*)d_ws;
  if (ws_size >= (size_t)48365568) {
    // Path C: bf16-converted pipeline, 48.4 MB ws.
    bf16* stg    = ws;                    // 6291456 el, reused key->value
    bf16* k_head = stg    + 6291456;
    bf16* vT     = k_head + 6291456;
    bf16* qp     = vT     + 6291456;
    bf16* ctx    = qp     + 2097152;
    bf16* peT    = ctx    + 2097152;
    bf16* Wb     = peT    + 65536;
    bf16* Wq_b = Wb, *Wk_b = Wb + 262144, *Wv_b = Wb + 524288, *Wo_b = Wb + 786432;

    conv_w4<<<dim3(128, 4), 256, 0, stream>>>(Wq, Wk, Wv, Wo, Wb);
    transpose_pe<<<256, 256, 0, stream>>>(key_pe, peT);

    conv_bf16<<<3072, 256, 0, stream>>>(key, stg);
    gemmbn64<1, bf16, bf16, bf16><<<768, 256, 0, stream>>>(stg, Wk_b, k_head);
    conv_bf16<<<3072, 256, 0, stream>>>(value, stg);
    gemmbn64<2, bf16, bf16, bf16><<<768, 256, 0, stream>>>(stg, Wv_b, vT);
    gemmbn64<0, float, bf16, bf16><<<256, 256, 0, stream>>>(query, Wq_b, qp);

    attn4<<<2048, 256, 0, stream>>>(qp, k_head, vT, peT, spanv, ctx);
    gemmbn64<0, bf16, bf16, float><<<256, 256, 0, stream>>>(ctx, Wo_b, out);
  } else {
    // Path B (fallback): fused-q attention, f32 GEMM reads, 29.5 MB ws.
    bf16* k_head = ws;
    bf16* vT     = k_head + 6291456;
    bf16* ctx    = vT     + 6291456;
    bf16* peT    = ctx    + 2097152;
    gemmbn64<1, float, float, bf16><<<768, 256, 0, stream>>>(key,   Wk, k_head);
    gemmbn64<2, float, float, bf16><<<768, 256, 0, stream>>>(value, Wv, vT);
    transpose_pe<<<256, 256, 0, stream>>>(key_pe, peT);
    attn_kernel_fb<<<2048, 128, 0, stream>>>(query, Wq, k_head, vT,
                                             peT, spanv, ctx);
    gemmbn64<0, bf16, float, float><<<256, 256, 0, stream>>>(ctx, Wo, out);
  }
}

// Round 3
// 332.862 us; speedup vs baseline: 1.1173x; 1.0063x over previous
//
#include <hip/hip_runtime.h>
#include <hip/hip_bf16.h>
#include <type_traits>

typedef __hip_bfloat16 bf16;
typedef short bf16x8 __attribute__((ext_vector_type(8)));
typedef float f32x4 __attribute__((ext_vector_type(4)));
typedef short short4_ __attribute__((ext_vector_type(4)));

#define NB 8      // batch
#define SM 512    // block size M
#define SL 1024   // attn span L
#define SH 512    // hidden
#define NH 8      // heads
#define HD 64     // head dim
#define SN 1536   // M + L (key length)

static __device__ __forceinline__ short bf_bits(float x) {
  union { bf16 b; short s; } u; u.b = __float2bfloat16(x); return u.s;
}
static __device__ __forceinline__ bf16x8 ld8any(const bf16* p) {
  return *reinterpret_cast<const bf16x8*>(p);
}
static __device__ __forceinline__ bf16x8 ld8any(const float* p) {
  float4 a = *reinterpret_cast<const float4*>(p);
  float4 b = *reinterpret_cast<const float4*>(p + 4);
  bf16x8 r;
  r[0] = bf_bits(a.x); r[1] = bf_bits(a.y); r[2] = bf_bits(a.z); r[3] = bf_bits(a.w);
  r[4] = bf_bits(b.x); r[5] = bf_bits(b.y); r[6] = bf_bits(b.z); r[7] = bf_bits(b.w);
  return r;
}
static __device__ __forceinline__ void st1(bf16* p, float v) { *p = __float2bfloat16(v); }
static __device__ __forceinline__ void st1(float* p, float v) { *p = v; }
static __device__ __forceinline__ f32x4 mfma16(bf16x8 a, bf16x8 b, f32x4 c) {
  return __builtin_amdgcn_mfma_f32_16x16x32_bf16(a, b, c, 0, 0, 0);
}

// ---------------------------------------------------------------------------
// f32 -> bf16 bulk conversion, 8 el/thread, fully coalesced.
// ---------------------------------------------------------------------------
__global__ __launch_bounds__(256) void conv_bf16(const float* __restrict__ src,
                                                 bf16* __restrict__ dst) {
  const int i = blockIdx.x * 256 + threadIdx.x;
  *reinterpret_cast<bf16x8*>(dst + (size_t)i * 8) = ld8any(src + (size_t)i * 8);
}

__global__ __launch_bounds__(256) void conv_w4(const float* __restrict__ w0,
                                               const float* __restrict__ w1,
                                               const float* __restrict__ w2,
                                               const float* __restrict__ w3,
                                               bf16* __restrict__ dst) {
  const float* srcs[4] = {w0, w1, w2, w3};
  const float* s = srcs[blockIdx.y];
  bf16* d = dst + (size_t)blockIdx.y * 262144;
  const int i = blockIdx.x * 256 + threadIdx.x;
  *reinterpret_cast<bf16x8*>(d + (size_t)i * 8) = ld8any(s + (size_t)i * 8);
}

// ---------------------------------------------------------------------------
// Y[R x 512] = X[R x 512] @ W^T. BM=128, BN=64. 4 waves, wave tile 64x32.
// grid = (R/128)*8, XCD-swizzled. MODE 0: row-major. MODE 1: k_head. MODE 2: vT.
// ---------------------------------------------------------------------------
#define T2STR 136

template <int MODE, typename TX, typename TW, typename TY>
__global__ __launch_bounds__(256) void gemmbn64(const TX* __restrict__ X,
                                                const TW* __restrict__ W,
                                                TY* __restrict__ Y) {
  __shared__ __align__(16) bf16 tile[(MODE == 2) ? 64 * T2STR : 8];
  const int id   = blockIdx.x;
  const int s_   = id >> 3;
  const int xblk = (id & 7) + 8 * (s_ >> 3);
  const int yblk = s_ & 7;
  const int tid  = threadIdx.x;
  const int lane = tid & 63, w = tid >> 6;
  const int col16 = lane & 15, quad = lane >> 4, kq = quad << 3;
  const int wm = w >> 1, wn = w & 1;
  const int m0 = xblk * 128 + wm * 64;
  const int n0 = yblk * 64 + wn * 32;
  const TX* xr = X + (size_t)(m0 + col16) * SH + kq;
  const TW* wr = W + (size_t)(n0 + col16) * SH + kq;
  f32x4 acc[4][2];
#pragma unroll
  for (int i = 0; i < 4; ++i)
#pragma unroll
    for (int j = 0; j < 2; ++j) acc[i][j] = f32x4{0.f,0.f,0.f,0.f};
#pragma unroll
  for (int k0 = 0; k0 < SH; k0 += 32) {
    bf16x8 af[4], bfr[2];
#pragma unroll
    for (int t = 0; t < 4; ++t) af[t]  = ld8any(xr + (size_t)(t*16) * SH + k0);
#pragma unroll
    for (int t = 0; t < 2; ++t) bfr[t] = ld8any(wr + (size_t)(t*16) * SH + k0);
#pragma unroll
    for (int mt = 0; mt < 4; ++mt)
#pragma unroll
      for (int nt = 0; nt < 2; ++nt)
        acc[mt][nt] = mfma16(af[mt], bfr[nt], acc[mt][nt]);
  }

  if constexpr (MODE == 0) {
#pragma unroll
    for (int mt = 0; mt < 4; ++mt)
#pragma unroll
      for (int r = 0; r < 4; ++r) {
        const int row = m0 + mt*16 + quad*4 + r;
        TY* yr = Y + (size_t)row * SH + n0 + col16;
        st1(yr,      acc[mt][0][r]);
        st1(yr + 16, acc[mt][1][r]);
      }
  } else if constexpr (MODE == 1) {
#pragma unroll
    for (int mt = 0; mt < 4; ++mt)
#pragma unroll
      for (int r = 0; r < 4; ++r) {
        const int row = m0 + mt*16 + quad*4 + r;
        const int b = row / SN, sr = row - b * SN;
        bf16* yr = (bf16*)Y + (size_t)((b*NH + yblk)*SN + sr) * HD
                 + wn*32 + col16;
        yr[0]  = __float2bfloat16(acc[mt][0][r]);
        yr[16] = __float2bfloat16(acc[mt][1][r]);
      }
  } else {
    // stage transposed: tile[d][row_loc]
#pragma unroll
    for (int mt = 0; mt < 4; ++mt)
#pragma unroll
      for (int r = 0; r < 4; ++r) {
        const int row_loc = wm*64 + mt*16 + quad*4 + r;
#pragma unroll
        for (int nt = 0; nt < 2; ++nt) {
          const int d = wn*32 + nt*16 + col16;
          tile[d * T2STR + row_loc] = __float2bfloat16(acc[mt][nt][r]);
        }
      }
    __syncthreads();
    const int d  = tid >> 2;      // 0..63
    const int hq = tid & 3;       // 32-row quarter
    const bf16* src = tile + d * T2STR + hq * 32;
    const int row0 = xblk*128 + hq*32;
    const int b = row0 / SN, sr0 = row0 - b * SN;
    bf16* dst = (bf16*)Y + (size_t)((b*NH + yblk)*HD + d) * SN + sr0;
#pragma unroll
    for (int i = 0; i < 4; ++i)
      reinterpret_cast<uint4*>(dst)[i] = reinterpret_cast<const uint4*>(src)[i];
  }
}

// ---------------------------------------------------------------------------
// peT[l][d] = bf16(pe[d][l])
// ---------------------------------------------------------------------------
__global__ void transpose_pe(const float* __restrict__ pe, bf16* __restrict__ peT) {
  int idx = blockIdx.x * 256 + threadIdx.x;
  int l = idx >> 6, d = idx & 63;
  peT[idx] = __float2bfloat16(pe[d * SL + l]);
}

// ---------------------------------------------------------------------------
// Barrier-free wave-private fused attention (v4).
// One 64-lane wave fully owns 16 query rows; grid 2048 x 64 threads.
// Operand-swapped MFMAs keep lane&15 == query-row in EVERY phase:
//   QK^T:  mfma(K, Q)  -> cont scores in REGISTERS (no LDS), D col = q-row.
//   pos:   mfma(pe, Q) -> LDS round-trip only for the unskew diagonal.
//   PV:    mfma(V, P)  -> output col = q-row, so alpha/S are lane-local.
// No __syncthreads anywhere in the loop; LDS deps are within-wave (lgkmcnt).
// K/pe prefetched one chunk ahead; V prefetched one chunk ahead (T14).
// ---------------------------------------------------------------------------
#define PSTR1 69    // pos stride (f32): scalar writes, read addr 68*row+16t+q4 -> b128-aligned
#define BSTR1 104   // P stride (bf16): b64 writes, b128 reads aligned (mod 8 == 0)

__global__ __launch_bounds__(64, 2) void attn1w(
    const bf16* __restrict__ qp, const bf16* __restrict__ Kh,
    const bf16* __restrict__ VT, const bf16* __restrict__ peT,
    const float* __restrict__ spanv, bf16* __restrict__ ctx) {
  __shared__ __align__(16) float pos_s[16 * PSTR1];
  __shared__ __align__(16) bf16  P_s[16 * BSTR1];

  const int id = blockIdx.x;
  const int h  = id & 7;
  const int s_ = id >> 3;
  const int m0 = (s_ & 31) * 16;
  const int b  = s_ >> 5;
  const int hb = b * 8 + h;
  const int lane  = threadIdx.x;
  const int col16 = lane & 15, quad = lane >> 4, kq = quad << 3;
  const int q4 = quad << 2;

  // zero P band once (cols 0..79 rewritten every chunk incl. masked zeros;
  // cols 80..103 stay zero, read by the ks=2 PV fragment up to col 95)
  for (int i = lane; i < 16 * BSTR1; i += 64)
    P_s[i] = __float2bfloat16(0.0f);

  const bf16* qb = qp + (size_t)(b*SM + m0 + col16) * SH + h*HD + kq;
  const bf16x8 qf0 = ld8any(qb), qf1 = ld8any(qb + 32);

  const bf16* kb = Kh + (size_t)(hb * SN) * HD + kq;   // + key*HD
  const bf16* vb = VT + (size_t)(hb * HD) * SN;        // + d*SN + key
  const bf16* pb = peT + kq;                           // + l*HD

  float Mrun = -1.0e30f, Srun = 0.0f;
  const float span1024 = spanv[h] * 1024.0f;
  f32x4 o[4];
#pragma unroll
  for (int dt = 0; dt < 4; ++dt) o[dt] = f32x4{0.f,0.f,0.f,0.f};

  // prefetched operand fragments (single-buffered; WAR ordering via reg deps)
  bf16x8 kf[5][2], pf[4][2], vf[4][3];

  // ---- prologue: chunk-0 operands ----
#pragma unroll
  for (int t = 0; t < 5; ++t) {
    const bf16* kr = kb + (size_t)(m0 + 16*t + col16) * HD;
    kf[t][0] = ld8any(kr); kf[t][1] = ld8any(kr + 32);
  }
#pragma unroll
  for (int t = 0; t < 4; ++t) {
    const bf16* pr = pb + (size_t)(16*t + col16) * HD;
    pf[t][0] = ld8any(pr); pf[t][1] = ld8any(pr + 32);
  }
#pragma unroll
  for (int dt = 0; dt < 4; ++dt) {
    const bf16* v0 = vb + (size_t)(16*dt + col16) * SN + m0 + kq;
#pragma unroll
    for (int ks = 0; ks < 3; ++ks) vf[dt][ks] = ld8any(v0 + ks*32);
  }

  const int posw = col16 * PSTR1 + q4;        // write base (scalar f32)
  const int posr = col16 * (PSTR1 - 1) + q4;  // read base (b128-aligned)
  const int pww  = col16 * BSTR1 + q4;        // P write base (b64-aligned)
  const int pwr  = col16 * BSTR1 + kq;        // P read base (b128-aligned)

  for (int ch = 0; ch < 16; ++ch) {
    const int l0 = ch << 6;
    const int nb_ = m0 + l0;

    // ---- pos MFMAs (swapped: A=pe rows, D rows = l, cols = q-row) ----
    f32x4 pacc[4];
#pragma unroll
    for (int t = 0; t < 4; ++t) {
      f32x4 a = {0.f,0.f,0.f,0.f};
      a = mfma16(pf[t][0], qf0, a);
      a = mfma16(pf[t][1], qf1, a);
      pacc[t] = a;
    }
    // scalar writes: pos_s[qrow][l], qrow = col16, l = 16t + q4 + r
#pragma unroll
    for (int t = 0; t < 4; ++t)
#pragma unroll
      for (int r = 0; r < 4; ++r)
        pos_s[posw + 16*t + r] = pacc[t][r];

    // ---- cont MFMAs (swapped: A=K rows, D rows = band pos, cols = q-row) ----
    f32x4 cacc[5];
#pragma unroll
    for (int t = 0; t < 5; ++t) {
      f32x4 a = {0.f,0.f,0.f,0.f};
      a = mfma16(kf[t][0], qf0, a);
      a = mfma16(kf[t][1], qf1, a);
      cacc[t] = a;
    }

    // ---- issue next chunk's K/pe (kf/pf regs now dead; in flight across
    //      the softmax below) ----
    {
      const int l0n = (ch < 15) ? l0 + 64 : l0;
      const int nbn = m0 + l0n;
#pragma unroll
      for (int t = 0; t < 5; ++t) {
        const bf16* kr = kb + (size_t)(nbn + 16*t + col16) * HD;
        kf[t][0] = ld8any(kr); kf[t][1] = ld8any(kr + 32);
      }
#pragma unroll
      for (int t = 0; t < 4; ++t) {
        const bf16* pr = pb + (size_t)(l0n + 16*t + col16) * HD;
        pf[t][0] = ld8any(pr); pf[t][1] = ld8any(pr + 32);
      }
    }

    // ---- per-lane softmax over this row's 64-key window ----
    // lane's cont value (t,r): band pos bp = 16t+q4+r, l = bp - col16.
    float sc[5][4];
    float mc = -1.0e30f;
#pragma unroll
    for (int t = 0; t < 5; ++t) {
      const f32x4 pv4 = *reinterpret_cast<const f32x4*>(&pos_s[posr + 16*t]);
#pragma unroll
      for (int r = 0; r < 4; ++r) {
        const int l = 16*t + q4 + r - col16;
        float v = (cacc[t][r] + pv4[r]) * 0.125f;
        v = ((unsigned)l < 64u) ? v : -1.0e30f;
        sc[t][r] = v;
        mc = fmaxf(mc, v);
      }
    }
    mc = fmaxf(mc, __shfl_xor(mc, 16));
    mc = fmaxf(mc, __shfl_xor(mc, 32));
    const float Mnew = fmaxf(Mrun, mc);
    const float alpha = __expf(Mrun - Mnew);
    float ls = 0.0f;
#pragma unroll
    for (int t = 0; t < 5; ++t) {
      short4_ pk;
#pragma unroll
      for (int r = 0; r < 4; ++r) {
        const float p = __expf(sc[t][r] - Mnew);   // 0 for masked slots
        ls += p;
        const float lg = (float)(l0 + 16*t + q4 + r - col16);
        float mv = (lg - 1023.0f + span1024) * 0.03125f + 1.0f;
        mv = fminf(fmaxf(mv, 0.0f), 1.0f);
        pk[r] = bf_bits(p * mv);
      }
      *reinterpret_cast<short4_*>(&P_s[pww + 16*t]) = pk;
    }
    ls += __shfl_xor(ls, 16);
    ls += __shfl_xor(ls, 32);
    Srun = Srun * alpha + ls;
    Mrun = Mnew;

    // ---- PV (swapped: A=V^T rows=d, B=P cols=q-row) ----
#pragma unroll
    for (int dt = 0; dt < 4; ++dt)
#pragma unroll
      for (int r = 0; r < 4; ++r) o[dt][r] *= alpha;
#pragma unroll
    for (int ks = 0; ks < 3; ++ks) {
      const bf16x8 ap = ld8any(&P_s[pwr + ks*32]);
#pragma unroll
      for (int dt = 0; dt < 4; ++dt)
        o[dt] = mfma16(vf[dt][ks], ap, o[dt]);
    }

    // ---- issue next chunk's V (vf regs now dead) ----
    {
      const int nbn = m0 + ((ch < 15) ? l0 + 64 : l0);
#pragma unroll
      for (int dt = 0; dt < 4; ++dt) {
        const bf16* v0 = vb + (size_t)(16*dt + col16) * SN + nbn + kq;
#pragma unroll
        for (int ks = 0; ks < 3; ++ks) vf[dt][ks] = ld8any(v0 + ks*32);
      }
    }
  }

  // ---- epilogue: lane-local normalize, packed b64 stores ----
  const float inv = 1.0f / Srun;
  bf16* cr = ctx + (size_t)(b*SM + m0 + col16) * SH + h*HD + q4;
#pragma unroll
  for (int dt = 0; dt < 4; ++dt) {
    short4_ pk;
#pragma unroll
    for (int r = 0; r < 4; ++r) pk[r] = bf_bits(o[dt][r] * inv);
    *reinterpret_cast<short4_*>(cr + 16*dt) = pk;
  }
}

// ---------------------------------------------------------------------------
// Fallback fused attention (round-6 proven): 16 rows/block, 2 waves, fused q.
// ---------------------------------------------------------------------------
#define MT 16
#define CSTR 84
#define PSTR 65
#define BSTR 104
#define QSTR 72

__global__ __launch_bounds__(128) void attn_kernel_fb(
    const float* __restrict__ query, const float* __restrict__ Wq,
    const bf16* __restrict__ Kh, const bf16* __restrict__ VT,
    const bf16* __restrict__ peT, const float* __restrict__ spanv,
    bf16* __restrict__ ctx) {
  __shared__ __align__(16) float cont_lds[MT][CSTR];
  __shared__ __align__(16) float pos_lds[MT][PSTR];
  __shared__ __align__(16) bf16  P_lds[MT][BSTR];
  __shared__ __align__(16) bf16  q_lds[MT*QSTR];
  __shared__ float alpha_lds[MT];
  __shared__ float S_lds[MT];

  const int id = blockIdx.x;
  const int h  = id & 7;
  const int s_ = id >> 3;
  const int m0 = (s_ & 31) * MT;
  const int b  = s_ >> 5;
  const int hb = b * 8 + h;
  const int tid  = threadIdx.x;
  const int lane = tid & 63;
  const int w    = tid >> 6;
  const int col16 = lane & 15, quad = lane >> 4, kq = quad << 3;
  const int wr = quad << 2;

  for (int i = tid; i < MT * BSTR; i += 128)
    (&P_lds[0][0])[i] = __float2bfloat16(0.0f);

  bf16x8 qf0, qf1;
  {
    f32x4 qa0 = {0.f,0.f,0.f,0.f}, qa1 = qa0;
    const float* xq = query + (size_t)(b*SM + m0 + col16) * SH + kq;
    const float* w0 = Wq + (size_t)(h*HD + w*32 + col16) * SH + kq;
    const float* w1 = w0 + (size_t)16 * SH;
#pragma unroll
    for (int k0 = 0; k0 < SH; k0 += 32) {
      bf16x8 xa = ld8any(xq + k0);
      qa0 = mfma16(xa, ld8any(w0 + k0), qa0);
      qa1 = mfma16(xa, ld8any(w1 + k0), qa1);
    }
#pragma unroll
    for (int r = 0; r < 4; ++r) {
      q_lds[(wr + r)*QSTR + w*32 + col16]      = __float2bfloat16(qa0[r]);
      q_lds[(wr + r)*QSTR + w*32 + 16 + col16] = __float2bfloat16(qa1[r]);
    }
    __syncthreads();
    qf0 = ld8any(&q_lds[col16*QSTR + kq]);
    qf1 = ld8any(&q_lds[col16*QSTR + kq + 32]);
  }

  const bf16* kb = Kh + (size_t)(hb * SN) * HD + kq;
  const bf16* vb = VT + (size_t)(hb * HD) * SN;

  const int srow = tid >> 3, sj = tid & 7;
  float Mrun = -1.0e30f, Srun = 0.0f;
  const float span = spanv[h];
  const int dt0 = w * 16, dt1 = (w + 2) * 16;
  f32x4 o0 = {0.f,0.f,0.f,0.f}, o1 = o0;

  for (int ch = 0; ch < 16; ++ch) {
    const int l0 = ch << 6;
    const int nb_ = m0 + l0;

    f32x4 ca0 = {0.f,0.f,0.f,0.f}, ca1 = ca0, ca2 = ca0, pa0 = ca0, pa1 = ca0;
    {
      const bf16* kr0 = kb + (size_t)(nb_ + w*16 + col16) * HD;
      ca0 = mfma16(qf0, ld8any(kr0),           ca0);
      ca0 = mfma16(qf1, ld8any(kr0 + 32),      ca0);
      const bf16* kr1 = kr0 + 32 * HD;
      ca1 = mfma16(qf0, ld8any(kr1),           ca1);
      ca1 = mfma16(qf1, ld8any(kr1 + 32),      ca1);
      if (w == 0) {
        const bf16* kr2 = kr0 + 64 * HD;
        ca2 = mfma16(qf0, ld8any(kr2),         ca2);
        ca2 = mfma16(qf1, ld8any(kr2 + 32),    ca2);
      }
      const bf16* pr0 = peT + (size_t)(l0 + w*16 + col16) * HD + kq;
      pa0 = mfma16(qf0, ld8any(pr0),           pa0);
      pa0 = mfma16(qf1, ld8any(pr0 + 32),      pa0);
      const bf16* pr1 = pr0 + 32 * HD;
      pa1 = mfma16(qf0, ld8any(pr1),           pa1);
      pa1 = mfma16(qf1, ld8any(pr1 + 32),      pa1);
    }
#pragma unroll
    for (int r = 0; r < 4; ++r) {
      cont_lds[wr + r][w*16 + col16]      = ca0[r];
      cont_lds[wr + r][w*16 + 32 + col16] = ca1[r];
      if (w == 0) cont_lds[wr + r][64 + col16] = ca2[r];
      pos_lds[wr + r][w*16 + col16]       = pa0[r];
      pos_lds[wr + r][w*16 + 32 + col16]  = pa1[r];
    }
    __syncthreads();

    float sc[8];
    float mc = -1.0e30f;
    const float* crow = &cont_lds[srow][srow + sj*8];
    const float* prow = &pos_lds[srow][sj*8];
#pragma unroll
    for (int i = 0; i < 8; ++i) {
      float v = (crow[i] + prow[i]) * 0.125f;
      sc[i] = v;
      mc = fmaxf(mc, v);
    }
    mc = fmaxf(mc, __shfl_xor(mc, 1));
    mc = fmaxf(mc, __shfl_xor(mc, 2));
    mc = fmaxf(mc, __shfl_xor(mc, 4));
    const float Mnew = fmaxf(Mrun, mc);
    const float alpha = __expf(Mrun - Mnew);
    float ls = 0.0f;
    bf16* pwrow = &P_lds[srow][srow + sj*8];
#pragma unroll
    for (int i = 0; i < 8; ++i) {
      float p = __expf(sc[i] - Mnew);
      ls += p;
      const float tpl = (float)(l0 + sj*8 + i) - 1023.0f;
      float mv = (tpl + span * 1024.0f) * 0.03125f + 1.0f;
      mv = fminf(fmaxf(mv, 0.0f), 1.0f);
      pwrow[i] = __float2bfloat16(p * mv);
    }
    ls += __shfl_xor(ls, 1);
    ls += __shfl_xor(ls, 2);
    ls += __shfl_xor(ls, 4);
    Srun = Srun * alpha + ls;
    Mrun = Mnew;
    if (sj == 0) { alpha_lds[srow] = alpha; S_lds[srow] = Srun; }
    __syncthreads();

    float al[4];
#pragma unroll
    for (int r = 0; r < 4; ++r) al[r] = alpha_lds[wr + r];
#pragma unroll
    for (int r = 0; r < 4; ++r) { o0[r] *= al[r]; o1[r] *= al[r]; }
#pragma unroll
    for (int ks = 0; ks < 3; ++ks) {
      const bf16x8 ap = ld8any(&P_lds[col16][ks*32 + kq]);
      const bf16* v0 = vb + (size_t)(dt0 + col16) * SN + nb_ + ks*32 + kq;
      const bf16* v1 = vb + (size_t)(dt1 + col16) * SN + nb_ + ks*32 + kq;
      o0 = mfma16(ap, ld8any(v0), o0);
      o1 = mfma16(ap, ld8any(v1), o1);
    }
  }

  bf16* cr = ctx + (size_t)(b*SM + m0 + wr) * SH + h*HD + col16;
#pragma unroll
  for (int r = 0; r < 4; ++r) {
    const float inv = 1.0f / S_lds[wr + r];
    cr[(size_t)r * SH + dt0] = __float2bfloat16(o0[r] * inv);
    cr[(size_t)r * SH + dt1] = __float2bfloat16(o1[r] * inv);
  }
}

// ---------------------------------------------------------------------------
extern "C" void kernel_launch(void* const* d_in, const int* in_sizes, int n_in,
                              void* d_out, int out_size, void* d_ws, size_t ws_size,
                              hipStream_t stream) {
  const float* query  = (const float*)d_in[0];
  const float* key    = (const float*)d_in[1];
  const float* value  = (const float*)d_in[2];
  const float* key_pe = (const float*)d_in[3];
  const float* Wq     = (const float*)d_in[4];
  const float* Wk     = (const float*)d_in[5];
  const float* Wv     = (const float*)d_in[6];
  const float* Wo     = (const float*)d_in[7];
  const float* spanv  = (const float*)d_in[8];
  float* out = (float*)d_out;

  bf16* ws = (bf16*)d_ws;
  if (ws_size >= (size_t)48365568) {
    // Path C: bf16-converted pipeline, 48.4 MB ws.
    bf16* stg    = ws;                    // 6291456 el, reused key->value
    bf16* k_head = stg    + 6291456;
    bf16* vT     = k_head + 6291456;
    bf16* qp     = vT     + 6291456;
    bf16* ctx    = qp     + 2097152;
    bf16* peT    = ctx    + 2097152;
    bf16* Wb     = peT    + 65536;
    bf16* Wq_b = Wb, *Wk_b = Wb + 262144, *Wv_b = Wb + 524288, *Wo_b = Wb + 786432;

    conv_w4<<<dim3(128, 4), 256, 0, stream>>>(Wq, Wk, Wv, Wo, Wb);
    transpose_pe<<<256, 256, 0, stream>>>(key_pe, peT);

    conv_bf16<<<3072, 256, 0, stream>>>(key, stg);
    gemmbn64<1, bf16, bf16, bf16><<<768, 256, 0, stream>>>(stg, Wk_b, k_head);
    conv_bf16<<<3072, 256, 0, stream>>>(value, stg);
    gemmbn64<2, bf16, bf16, bf16><<<768, 256, 0, stream>>>(stg, Wv_b, vT);
    gemmbn64<0, float, bf16, bf16><<<256, 256, 0, stream>>>(query, Wq_b, qp);

    attn1w<<<2048, 64, 0, stream>>>(qp, k_head, vT, peT, spanv, ctx);
    gemmbn64<0, bf16, bf16, float><<<256, 256, 0, stream>>>(ctx, Wo_b, out);
  } else {
    // Path B (fallback): fused-q attention, f32 GEMM reads, 29.5 MB ws.
    bf16* k_head = ws;
    bf16* vT     = k_head + 6291456;
    bf16* ctx    = vT     + 6291456;
    bf16* peT    = ctx    + 2097152;
    gemmbn64<1, float, float, bf16><<<768, 256, 0, stream>>>(key,   Wk, k_head);
    gemmbn64<2, float, float, bf16><<<768, 256, 0, stream>>>(value, Wv, vT);
    transpose_pe<<<256, 256, 0, stream>>>(key_pe, peT);
    attn_kernel_fb<<<2048, 128, 0, stream>>>(query, Wq, k_head, vT,
                                             peT, spanv, ctx);
    gemmbn64<0, bf16, float, float><<<256, 256, 0, stream>>>(ctx, Wo, out);
  }
}

// Round 4
// 330.144 us; speedup vs baseline: 1.1265x; 1.0082x over previous
//
#include <hip/hip_runtime.h>
#include <hip/hip_bf16.h>
#include <type_traits>

typedef __hip_bfloat16 bf16;
typedef short bf16x8 __attribute__((ext_vector_type(8)));
typedef float f32x4 __attribute__((ext_vector_type(4)));
typedef short short4_ __attribute__((ext_vector_type(4)));

#define NB 8      // batch
#define SM 512    // block size M
#define SL 1024   // attn span L
#define SH 512    // hidden
#define NH 8      // heads
#define HD 64     // head dim
#define SN 1536   // M + L (key length)

static __device__ __forceinline__ short bf_bits(float x) {
  union { bf16 b; short s; } u; u.b = __float2bfloat16(x); return u.s;
}
static __device__ __forceinline__ bf16x8 ld8any(const bf16* p) {
  return *reinterpret_cast<const bf16x8*>(p);
}
static __device__ __forceinline__ bf16x8 ld8any(const float* p) {
  float4 a = *reinterpret_cast<const float4*>(p);
  float4 b = *reinterpret_cast<const float4*>(p + 4);
  bf16x8 r;
  r[0] = bf_bits(a.x); r[1] = bf_bits(a.y); r[2] = bf_bits(a.z); r[3] = bf_bits(a.w);
  r[4] = bf_bits(b.x); r[5] = bf_bits(b.y); r[6] = bf_bits(b.z); r[7] = bf_bits(b.w);
  return r;
}
static __device__ __forceinline__ void st1(bf16* p, float v) { *p = __float2bfloat16(v); }
static __device__ __forceinline__ void st1(float* p, float v) { *p = v; }
static __device__ __forceinline__ f32x4 mfma16(bf16x8 a, bf16x8 b, f32x4 c) {
  return __builtin_amdgcn_mfma_f32_16x16x32_bf16(a, b, c, 0, 0, 0);
}

// ---------------------------------------------------------------------------
// f32 -> bf16 bulk conversion, 8 el/thread, fully coalesced.
// ---------------------------------------------------------------------------
__global__ __launch_bounds__(256) void conv_bf16(const float* __restrict__ src,
                                                 bf16* __restrict__ dst) {
  const int i = blockIdx.x * 256 + threadIdx.x;
  *reinterpret_cast<bf16x8*>(dst + (size_t)i * 8) = ld8any(src + (size_t)i * 8);
}

__global__ __launch_bounds__(256) void conv_w4(const float* __restrict__ w0,
                                               const float* __restrict__ w1,
                                               const float* __restrict__ w2,
                                               const float* __restrict__ w3,
                                               bf16* __restrict__ dst) {
  const float* srcs[4] = {w0, w1, w2, w3};
  const float* s = srcs[blockIdx.y];
  bf16* d = dst + (size_t)blockIdx.y * 262144;
  const int i = blockIdx.x * 256 + threadIdx.x;
  *reinterpret_cast<bf16x8*>(d + (size_t)i * 8) = ld8any(s + (size_t)i * 8);
}

// ---------------------------------------------------------------------------
// Y[R x 512] = X[R x 512] @ W^T. BM=128, BN=64. 4 waves, wave tile 64x32.
// grid = (R/128)*8, XCD-swizzled. MODE 0: row-major. MODE 1: k_head. MODE 2: vT.
// ---------------------------------------------------------------------------
#define T2STR 136

template <int MODE, typename TX, typename TW, typename TY>
__global__ __launch_bounds__(256) void gemmbn64(const TX* __restrict__ X,
                                                const TW* __restrict__ W,
                                                TY* __restrict__ Y) {
  __shared__ __align__(16) bf16 tile[(MODE == 2) ? 64 * T2STR : 8];
  const int id   = blockIdx.x;
  const int s_   = id >> 3;
  const int xblk = (id & 7) + 8 * (s_ >> 3);
  const int yblk = s_ & 7;
  const int tid  = threadIdx.x;
  const int lane = tid & 63, w = tid >> 6;
  const int col16 = lane & 15, quad = lane >> 4, kq = quad << 3;
  const int wm = w >> 1, wn = w & 1;
  const int m0 = xblk * 128 + wm * 64;
  const int n0 = yblk * 64 + wn * 32;
  const TX* xr = X + (size_t)(m0 + col16) * SH + kq;
  const TW* wr = W + (size_t)(n0 + col16) * SH + kq;
  f32x4 acc[4][2];
#pragma unroll
  for (int i = 0; i < 4; ++i)
#pragma unroll
    for (int j = 0; j < 2; ++j) acc[i][j] = f32x4{0.f,0.f,0.f,0.f};
#pragma unroll
  for (int k0 = 0; k0 < SH; k0 += 32) {
    bf16x8 af[4], bfr[2];
#pragma unroll
    for (int t = 0; t < 4; ++t) af[t]  = ld8any(xr + (size_t)(t*16) * SH + k0);
#pragma unroll
    for (int t = 0; t < 2; ++t) bfr[t] = ld8any(wr + (size_t)(t*16) * SH + k0);
#pragma unroll
    for (int mt = 0; mt < 4; ++mt)
#pragma unroll
      for (int nt = 0; nt < 2; ++nt)
        acc[mt][nt] = mfma16(af[mt], bfr[nt], acc[mt][nt]);
  }

  if constexpr (MODE == 0) {
#pragma unroll
    for (int mt = 0; mt < 4; ++mt)
#pragma unroll
      for (int r = 0; r < 4; ++r) {
        const int row = m0 + mt*16 + quad*4 + r;
        TY* yr = Y + (size_t)row * SH + n0 + col16;
        st1(yr,      acc[mt][0][r]);
        st1(yr + 16, acc[mt][1][r]);
      }
  } else if constexpr (MODE == 1) {
#pragma unroll
    for (int mt = 0; mt < 4; ++mt)
#pragma unroll
      for (int r = 0; r < 4; ++r) {
        const int row = m0 + mt*16 + quad*4 + r;
        const int b = row / SN, sr = row - b * SN;
        bf16* yr = (bf16*)Y + (size_t)((b*NH + yblk)*SN + sr) * HD
                 + wn*32 + col16;
        yr[0]  = __float2bfloat16(acc[mt][0][r]);
        yr[16] = __float2bfloat16(acc[mt][1][r]);
      }
  } else {
    // stage transposed: tile[d][row_loc]
#pragma unroll
    for (int mt = 0; mt < 4; ++mt)
#pragma unroll
      for (int r = 0; r < 4; ++r) {
        const int row_loc = wm*64 + mt*16 + quad*4 + r;
#pragma unroll
        for (int nt = 0; nt < 2; ++nt) {
          const int d = wn*32 + nt*16 + col16;
          tile[d * T2STR + row_loc] = __float2bfloat16(acc[mt][nt][r]);
        }
      }
    __syncthreads();
    const int d  = tid >> 2;      // 0..63
    const int hq = tid & 3;       // 32-row quarter
    const bf16* src = tile + d * T2STR + hq * 32;
    const int row0 = xblk*128 + hq*32;
    const int b = row0 / SN, sr0 = row0 - b * SN;
    bf16* dst = (bf16*)Y + (size_t)((b*NH + yblk)*HD + d) * SN + sr0;
#pragma unroll
    for (int i = 0; i < 4; ++i)
      reinterpret_cast<uint4*>(dst)[i] = reinterpret_cast<const uint4*>(src)[i];
  }
}

// ---------------------------------------------------------------------------
// peT[l][d] = bf16(pe[d][l])
// ---------------------------------------------------------------------------
__global__ void transpose_pe(const float* __restrict__ pe, bf16* __restrict__ peT) {
  int idx = blockIdx.x * 256 + threadIdx.x;
  int l = idx >> 6, d = idx & 63;
  peT[idx] = __float2bfloat16(pe[d * SL + l]);
}

// ---------------------------------------------------------------------------
// 4-wave L1-sharing fused attention (v5).
// Each 64-lane wave fully owns 16 query rows (m0 offset w*16) with the proven
// barrier-free wave-private structure (swapped MFMAs, lane&15 == q-row in all
// phases, private LDS slices, K/pe/V register prefetch). The 4 waves of a
// block cover 64 consecutive rows, so their K/V bands overlap 75-80% and pe
// reads are IDENTICAL -> the CU-shared 32KB L1 dedups the L2 traffic (~2.7x).
// One raw s_barrier per chunk keeps waves temporally aligned for L1 reuse;
// no data crosses waves, so no waitcnt drain is needed.
// grid 512 x 256. h = id&7 keeps the per-XCD head-residency in L2.
// ---------------------------------------------------------------------------
#define PSTR1 69    // pos stride (f32): scalar writes, b128-aligned reads
#define BSTR1 104   // P stride (bf16): b64 writes, b128 reads aligned

__global__ __launch_bounds__(256, 2) void attn4w(
    const bf16* __restrict__ qp, const bf16* __restrict__ Kh,
    const bf16* __restrict__ VT, const bf16* __restrict__ peT,
    const float* __restrict__ spanv, bf16* __restrict__ ctx) {
  __shared__ __align__(16) float pos_all[4][16 * PSTR1];
  __shared__ __align__(16) bf16  P_all[4][16 * BSTR1];

  const int id = blockIdx.x;
  const int h  = id & 7;
  const int s_ = id >> 3;       // 0..63
  const int b  = s_ >> 3;
  const int mg = s_ & 7;
  const int tid = threadIdx.x;
  const int lane = tid & 63, w = tid >> 6;
  const int m0 = mg * 64 + w * 16;
  const int hb = b * 8 + h;
  const int col16 = lane & 15, quad = lane >> 4, kq = quad << 3;
  const int q4 = quad << 2;

  float* pos_s = &pos_all[w][0];
  bf16*  P_s   = &P_all[w][0];

  // zero own P band once (cols 80..103 stay zero; read by ks=2 PV fragment)
  for (int i = lane; i < 16 * BSTR1; i += 64)
    P_s[i] = __float2bfloat16(0.0f);

  const bf16* qb = qp + (size_t)(b*SM + m0 + col16) * SH + h*HD + kq;
  const bf16x8 qf0 = ld8any(qb), qf1 = ld8any(qb + 32);

  const bf16* kb = Kh + (size_t)(hb * SN) * HD + kq;   // + key*HD
  const bf16* vb = VT + (size_t)(hb * HD) * SN;        // + d*SN + key
  const bf16* pb = peT + kq;                           // + l*HD

  float Mrun = -1.0e30f, Srun = 0.0f;
  const float span1024 = spanv[h] * 1024.0f;
  f32x4 o[4];
#pragma unroll
  for (int dt = 0; dt < 4; ++dt) o[dt] = f32x4{0.f,0.f,0.f,0.f};

  // prefetched operand fragments (single-buffered; WAR ordering via reg deps)
  bf16x8 kf[5][2], pf[4][2], vf[4][3];

  // ---- prologue: chunk-0 operands ----
#pragma unroll
  for (int t = 0; t < 5; ++t) {
    const bf16* kr = kb + (size_t)(m0 + 16*t + col16) * HD;
    kf[t][0] = ld8any(kr); kf[t][1] = ld8any(kr + 32);
  }
#pragma unroll
  for (int t = 0; t < 4; ++t) {
    const bf16* pr = pb + (size_t)(16*t + col16) * HD;
    pf[t][0] = ld8any(pr); pf[t][1] = ld8any(pr + 32);
  }
#pragma unroll
  for (int dt = 0; dt < 4; ++dt) {
    const bf16* v0 = vb + (size_t)(16*dt + col16) * SN + m0 + kq;
#pragma unroll
    for (int ks = 0; ks < 3; ++ks) vf[dt][ks] = ld8any(v0 + ks*32);
  }

  const int posw = col16 * PSTR1 + q4;        // write base (scalar f32)
  const int posr = col16 * (PSTR1 - 1) + q4;  // read base (b128-aligned)
  const int pww  = col16 * BSTR1 + q4;        // P write base (b64-aligned)
  const int pwr  = col16 * BSTR1 + kq;        // P read base (b128-aligned)

  for (int ch = 0; ch < 16; ++ch) {
    const int l0 = ch << 6;
    const int nb_ = m0 + l0;

    // keep the 4 waves temporally aligned so overlapping K/V/pe lines hit L1.
    // No cross-wave data -> raw s_barrier (no waitcnt drain) is safe.
    __builtin_amdgcn_s_barrier();

    // ---- pos MFMAs (swapped: A=pe rows, D rows = l, cols = q-row) ----
    f32x4 pacc[4];
#pragma unroll
    for (int t = 0; t < 4; ++t) {
      f32x4 a = {0.f,0.f,0.f,0.f};
      a = mfma16(pf[t][0], qf0, a);
      a = mfma16(pf[t][1], qf1, a);
      pacc[t] = a;
    }
    // scalar writes: pos_s[qrow][l], qrow = col16, l = 16t + q4 + r
#pragma unroll
    for (int t = 0; t < 4; ++t)
#pragma unroll
      for (int r = 0; r < 4; ++r)
        pos_s[posw + 16*t + r] = pacc[t][r];

    // ---- cont MFMAs (swapped: A=K rows, D rows = band pos, cols = q-row) ----
    f32x4 cacc[5];
#pragma unroll
    for (int t = 0; t < 5; ++t) {
      f32x4 a = {0.f,0.f,0.f,0.f};
      a = mfma16(kf[t][0], qf0, a);
      a = mfma16(kf[t][1], qf1, a);
      cacc[t] = a;
    }

    // ---- issue next chunk's K/pe (kf/pf regs now dead; in flight across
    //      the softmax below) ----
    {
      const int l0n = (ch < 15) ? l0 + 64 : l0;
      const int nbn = m0 + l0n;
#pragma unroll
      for (int t = 0; t < 5; ++t) {
        const bf16* kr = kb + (size_t)(nbn + 16*t + col16) * HD;
        kf[t][0] = ld8any(kr); kf[t][1] = ld8any(kr + 32);
      }
#pragma unroll
      for (int t = 0; t < 4; ++t) {
        const bf16* pr = pb + (size_t)(l0n + 16*t + col16) * HD;
        pf[t][0] = ld8any(pr); pf[t][1] = ld8any(pr + 32);
      }
    }

    // ---- per-lane softmax over this row's 64-key window ----
    // lane's cont value (t,r): band pos bp = 16t+q4+r, l = bp - col16.
    float sc[5][4];
    float mc = -1.0e30f;
#pragma unroll
    for (int t = 0; t < 5; ++t) {
      const f32x4 pv4 = *reinterpret_cast<const f32x4*>(&pos_s[posr + 16*t]);
#pragma unroll
      for (int r = 0; r < 4; ++r) {
        const int l = 16*t + q4 + r - col16;
        float v = (cacc[t][r] + pv4[r]) * 0.125f;
        v = ((unsigned)l < 64u) ? v : -1.0e30f;
        sc[t][r] = v;
        mc = fmaxf(mc, v);
      }
    }
    mc = fmaxf(mc, __shfl_xor(mc, 16));
    mc = fmaxf(mc, __shfl_xor(mc, 32));
    const float Mnew = fmaxf(Mrun, mc);
    const float alpha = __expf(Mrun - Mnew);
    float ls = 0.0f;
#pragma unroll
    for (int t = 0; t < 5; ++t) {
      short4_ pk;
#pragma unroll
      for (int r = 0; r < 4; ++r) {
        const float p = __expf(sc[t][r] - Mnew);   // 0 for masked slots
        ls += p;
        const float lg = (float)(l0 + 16*t + q4 + r - col16);
        float mv = (lg - 1023.0f + span1024) * 0.03125f + 1.0f;
        mv = fminf(fmaxf(mv, 0.0f), 1.0f);
        pk[r] = bf_bits(p * mv);
      }
      *reinterpret_cast<short4_*>(&P_s[pww + 16*t]) = pk;
    }
    ls += __shfl_xor(ls, 16);
    ls += __shfl_xor(ls, 32);
    Srun = Srun * alpha + ls;
    Mrun = Mnew;

    // ---- PV (swapped: A=V^T rows=d, B=P cols=q-row) ----
#pragma unroll
    for (int dt = 0; dt < 4; ++dt)
#pragma unroll
      for (int r = 0; r < 4; ++r) o[dt][r] *= alpha;
#pragma unroll
    for (int ks = 0; ks < 3; ++ks) {
      const bf16x8 ap = ld8any(&P_s[pwr + ks*32]);
#pragma unroll
      for (int dt = 0; dt < 4; ++dt)
        o[dt] = mfma16(vf[dt][ks], ap, o[dt]);
    }

    // ---- issue next chunk's V (vf regs now dead) ----
    {
      const int nbn = m0 + ((ch < 15) ? l0 + 64 : l0);
#pragma unroll
      for (int dt = 0; dt < 4; ++dt) {
        const bf16* v0 = vb + (size_t)(16*dt + col16) * SN + nbn + kq;
#pragma unroll
        for (int ks = 0; ks < 3; ++ks) vf[dt][ks] = ld8any(v0 + ks*32);
      }
    }
  }

  // ---- epilogue: lane-local normalize, packed b64 stores ----
  const float inv = 1.0f / Srun;
  bf16* cr = ctx + (size_t)(b*SM + m0 + col16) * SH + h*HD + q4;
#pragma unroll
  for (int dt = 0; dt < 4; ++dt) {
    short4_ pk;
#pragma unroll
    for (int r = 0; r < 4; ++r) pk[r] = bf_bits(o[dt][r] * inv);
    *reinterpret_cast<short4_*>(cr + 16*dt) = pk;
  }
}

// ---------------------------------------------------------------------------
// Fallback fused attention (round-6 proven): 16 rows/block, 2 waves, fused q.
// ---------------------------------------------------------------------------
#define MT 16
#define CSTR 84
#define PSTR 65
#define BSTR 104
#define QSTR 72

__global__ __launch_bounds__(128) void attn_kernel_fb(
    const float* __restrict__ query, const float* __restrict__ Wq,
    const bf16* __restrict__ Kh, const bf16* __restrict__ VT,
    const bf16* __restrict__ peT, const float* __restrict__ spanv,
    bf16* __restrict__ ctx) {
  __shared__ __align__(16) float cont_lds[MT][CSTR];
  __shared__ __align__(16) float pos_lds[MT][PSTR];
  __shared__ __align__(16) bf16  P_lds[MT][BSTR];
  __shared__ __align__(16) bf16  q_lds[MT*QSTR];
  __shared__ float alpha_lds[MT];
  __shared__ float S_lds[MT];

  const int id = blockIdx.x;
  const int h  = id & 7;
  const int s_ = id >> 3;
  const int m0 = (s_ & 31) * MT;
  const int b  = s_ >> 5;
  const int hb = b * 8 + h;
  const int tid  = threadIdx.x;
  const int lane = tid & 63;
  const int w    = tid >> 6;
  const int col16 = lane & 15, quad = lane >> 4, kq = quad << 3;
  const int wr = quad << 2;

  for (int i = tid; i < MT * BSTR; i += 128)
    (&P_lds[0][0])[i] = __float2bfloat16(0.0f);

  bf16x8 qf0, qf1;
  {
    f32x4 qa0 = {0.f,0.f,0.f,0.f}, qa1 = qa0;
    const float* xq = query + (size_t)(b*SM + m0 + col16) * SH + kq;
    const float* w0 = Wq + (size_t)(h*HD + w*32 + col16) * SH + kq;
    const float* w1 = w0 + (size_t)16 * SH;
#pragma unroll
    for (int k0 = 0; k0 < SH; k0 += 32) {
      bf16x8 xa = ld8any(xq + k0);
      qa0 = mfma16(xa, ld8any(w0 + k0), qa0);
      qa1 = mfma16(xa, ld8any(w1 + k0), qa1);
    }
#pragma unroll
    for (int r = 0; r < 4; ++r) {
      q_lds[(wr + r)*QSTR + w*32 + col16]      = __float2bfloat16(qa0[r]);
      q_lds[(wr + r)*QSTR + w*32 + 16 + col16] = __float2bfloat16(qa1[r]);
    }
    __syncthreads();
    qf0 = ld8any(&q_lds[col16*QSTR + kq]);
    qf1 = ld8any(&q_lds[col16*QSTR + kq + 32]);
  }

  const bf16* kb = Kh + (size_t)(hb * SN) * HD + kq;
  const bf16* vb = VT + (size_t)(hb * HD) * SN;

  const int srow = tid >> 3, sj = tid & 7;
  float Mrun = -1.0e30f, Srun = 0.0f;
  const float span = spanv[h];
  const int dt0 = w * 16, dt1 = (w + 2) * 16;
  f32x4 o0 = {0.f,0.f,0.f,0.f}, o1 = o0;

  for (int ch = 0; ch < 16; ++ch) {
    const int l0 = ch << 6;
    const int nb_ = m0 + l0;

    f32x4 ca0 = {0.f,0.f,0.f,0.f}, ca1 = ca0, ca2 = ca0, pa0 = ca0, pa1 = ca0;
    {
      const bf16* kr0 = kb + (size_t)(nb_ + w*16 + col16) * HD;
      ca0 = mfma16(qf0, ld8any(kr0),           ca0);
      ca0 = mfma16(qf1, ld8any(kr0 + 32),      ca0);
      const bf16* kr1 = kr0 + 32 * HD;
      ca1 = mfma16(qf0, ld8any(kr1),           ca1);
      ca1 = mfma16(qf1, ld8any(kr1 + 32),      ca1);
      if (w == 0) {
        const bf16* kr2 = kr0 + 64 * HD;
        ca2 = mfma16(qf0, ld8any(kr2),         ca2);
        ca2 = mfma16(qf1, ld8any(kr2 + 32),    ca2);
      }
      const bf16* pr0 = peT + (size_t)(l0 + w*16 + col16) * HD + kq;
      pa0 = mfma16(qf0, ld8any(pr0),           pa0);
      pa0 = mfma16(qf1, ld8any(pr0 + 32),      pa0);
      const bf16* pr1 = pr0 + 32 * HD;
      pa1 = mfma16(qf0, ld8any(pr1),           pa1);
      pa1 = mfma16(qf1, ld8any(pr1 + 32),      pa1);
    }
#pragma unroll
    for (int r = 0; r < 4; ++r) {
      cont_lds[wr + r][w*16 + col16]      = ca0[r];
      cont_lds[wr + r][w*16 + 32 + col16] = ca1[r];
      if (w == 0) cont_lds[wr + r][64 + col16] = ca2[r];
      pos_lds[wr + r][w*16 + col16]       = pa0[r];
      pos_lds[wr + r][w*16 + 32 + col16]  = pa1[r];
    }
    __syncthreads();

    float sc[8];
    float mc = -1.0e30f;
    const float* crow = &cont_lds[srow][srow + sj*8];
    const float* prow = &pos_lds[srow][sj*8];
#pragma unroll
    for (int i = 0; i < 8; ++i) {
      float v = (crow[i] + prow[i]) * 0.125f;
      sc[i] = v;
      mc = fmaxf(mc, v);
    }
    mc = fmaxf(mc, __shfl_xor(mc, 1));
    mc = fmaxf(mc, __shfl_xor(mc, 2));
    mc = fmaxf(mc, __shfl_xor(mc, 4));
    const float Mnew = fmaxf(Mrun, mc);
    const float alpha = __expf(Mrun - Mnew);
    float ls = 0.0f;
    bf16* pwrow = &P_lds[srow][srow + sj*8];
#pragma unroll
    for (int i = 0; i < 8; ++i) {
      float p = __expf(sc[i] - Mnew);
      ls += p;
      const float tpl = (float)(l0 + sj*8 + i) - 1023.0f;
      float mv = (tpl + span * 1024.0f) * 0.03125f + 1.0f;
      mv = fminf(fmaxf(mv, 0.0f), 1.0f);
      pwrow[i] = __float2bfloat16(p * mv);
    }
    ls += __shfl_xor(ls, 1);
    ls += __shfl_xor(ls, 2);
    ls += __shfl_xor(ls, 4);
    Srun = Srun * alpha + ls;
    Mrun = Mnew;
    if (sj == 0) { alpha_lds[srow] = alpha; S_lds[srow] = Srun; }
    __syncthreads();

    float al[4];
#pragma unroll
    for (int r = 0; r < 4; ++r) al[r] = alpha_lds[wr + r];
#pragma unroll
    for (int r = 0; r < 4; ++r) { o0[r] *= al[r]; o1[r] *= al[r]; }
#pragma unroll
    for (int ks = 0; ks < 3; ++ks) {
      const bf16x8 ap = ld8any(&P_lds[col16][ks*32 + kq]);
      const bf16* v0 = vb + (size_t)(dt0 + col16) * SN + nb_ + ks*32 + kq;
      const bf16* v1 = vb + (size_t)(dt1 + col16) * SN + nb_ + ks*32 + kq;
      o0 = mfma16(ap, ld8any(v0), o0);
      o1 = mfma16(ap, ld8any(v1), o1);
    }
  }

  bf16* cr = ctx + (size_t)(b*SM + m0 + wr) * SH + h*HD + col16;
#pragma unroll
  for (int r = 0; r < 4; ++r) {
    const float inv = 1.0f / S_lds[wr + r];
    cr[(size_t)r * SH + dt0] = __float2bfloat16(o0[r] * inv);
    cr[(size_t)r * SH + dt1] = __float2bfloat16(o1[r] * inv);
  }
}

// ---------------------------------------------------------------------------
extern "C" void kernel_launch(void* const* d_in, const int* in_sizes, int n_in,
                              void* d_out, int out_size, void* d_ws, size_t ws_size,
                              hipStream_t stream) {
  const float* query  = (const float*)d_in[0];
  const float* key    = (const float*)d_in[1];
  const float* value  = (const float*)d_in[2];
  const float* key_pe = (const float*)d_in[3];
  const float* Wq     = (const float*)d_in[4];
  const float* Wk     = (const float*)d_in[5];
  const float* Wv     = (const float*)d_in[6];
  const float* Wo     = (const float*)d_in[7];
  const float* spanv  = (const float*)d_in[8];
  float* out = (float*)d_out;

  bf16* ws = (bf16*)d_ws;
  if (ws_size >= (size_t)48365568) {
    // Path C: bf16-converted pipeline, 48.4 MB ws.
    bf16* stg    = ws;                    // 6291456 el, reused key->value
    bf16* k_head = stg    + 6291456;
    bf16* vT     = k_head + 6291456;
    bf16* qp     = vT     + 6291456;
    bf16* ctx    = qp     + 2097152;
    bf16* peT    = ctx    + 2097152;
    bf16* Wb     = peT    + 65536;
    bf16* Wq_b = Wb, *Wk_b = Wb + 262144, *Wv_b = Wb + 524288, *Wo_b = Wb + 786432;

    conv_w4<<<dim3(128, 4), 256, 0, stream>>>(Wq, Wk, Wv, Wo, Wb);
    transpose_pe<<<256, 256, 0, stream>>>(key_pe, peT);

    conv_bf16<<<3072, 256, 0, stream>>>(key, stg);
    gemmbn64<1, bf16, bf16, bf16><<<768, 256, 0, stream>>>(stg, Wk_b, k_head);
    conv_bf16<<<3072, 256, 0, stream>>>(value, stg);
    gemmbn64<2, bf16, bf16, bf16><<<768, 256, 0, stream>>>(stg, Wv_b, vT);
    gemmbn64<0, float, bf16, bf16><<<256, 256, 0, stream>>>(query, Wq_b, qp);

    attn4w<<<512, 256, 0, stream>>>(qp, k_head, vT, peT, spanv, ctx);
    gemmbn64<0, bf16, bf16, float><<<256, 256, 0, stream>>>(ctx, Wo_b, out);
  } else {
    // Path B (fallback): fused-q attention, f32 GEMM reads, 29.5 MB ws.
    bf16* k_head = ws;
    bf16* vT     = k_head + 6291456;
    bf16* ctx    = vT     + 6291456;
    bf16* peT    = ctx    + 2097152;
    gemmbn64<1, float, float, bf16><<<768, 256, 0, stream>>>(key,   Wk, k_head);
    gemmbn64<2, float, float, bf16><<<768, 256, 0, stream>>>(value, Wv, vT);
    transpose_pe<<<256, 256, 0, stream>>>(key_pe, peT);
    attn_kernel_fb<<<2048, 128, 0, stream>>>(query, Wq, k_head, vT,
                                             peT, spanv, ctx);
    gemmbn64<0, bf16, float, float><<<256, 256, 0, stream>>>(ctx, Wo, out);
  }
}

// Round 5
// 259.495 us; speedup vs baseline: 1.4332x; 1.2723x over previous
//
#include <hip/hip_runtime.h>
#include <hip/hip_bf16.h>
#include <type_traits>

typedef __hip_bfloat16 bf16;
typedef short bf16x8 __attribute__((ext_vector_type(8)));
typedef float f32x4 __attribute__((ext_vector_type(4)));
typedef short short4_ __attribute__((ext_vector_type(4)));

#define NB 8      // batch
#define SM 512    // block size M
#define SL 1024   // attn span L
#define SH 512    // hidden
#define NH 8      // heads
#define HD 64     // head dim
#define SN 1536   // M + L (key length)

static __device__ __forceinline__ short bf_bits(float x) {
  union { bf16 b; short s; } u; u.b = __float2bfloat16(x); return u.s;
}
static __device__ __forceinline__ bf16x8 ld8any(const bf16* p) {
  return *reinterpret_cast<const bf16x8*>(p);
}
static __device__ __forceinline__ bf16x8 ld8any(const float* p) {
  float4 a = *reinterpret_cast<const float4*>(p);
  float4 b = *reinterpret_cast<const float4*>(p + 4);
  bf16x8 r;
  r[0] = bf_bits(a.x); r[1] = bf_bits(a.y); r[2] = bf_bits(a.z); r[3] = bf_bits(a.w);
  r[4] = bf_bits(b.x); r[5] = bf_bits(b.y); r[6] = bf_bits(b.z); r[7] = bf_bits(b.w);
  return r;
}
static __device__ __forceinline__ void st1(bf16* p, float v) { *p = __float2bfloat16(v); }
static __device__ __forceinline__ void st1(float* p, float v) { *p = v; }
static __device__ __forceinline__ f32x4 mfma16(bf16x8 a, bf16x8 b, f32x4 c) {
  return __builtin_amdgcn_mfma_f32_16x16x32_bf16(a, b, c, 0, 0, 0);
}

// ---------------------------------------------------------------------------
// Fragment-linear layouts (all sized so one wave ld8any = base + lane*16B,
// fully coalesced, contents identical to the old strided gathers):
//  kF : [hb][kt 0..95][h 0..1][512]  elem = (dq*16 + kl)*8 + de
//       holds K[hb][key=kt*16+kl][d=h*32+dq*8+de]
//  vF : [hb][dt 0..3][kt 0..95][256] elem = kr8*128 + dl*8 + ke
//       holds V^T[hb][d=dt*16+dl][key=kt*16+kr8*8+ke]
//  peF: [lt 0..63][h 0..1][512]      elem = (dq*16 + ll)*8 + de
//       holds pe[d=h*32+dq*8+de][l=lt*16+ll]
// ---------------------------------------------------------------------------

// ---------------------------------------------------------------------------
// f32 -> bf16 bulk conversion, 8 el/thread, fully coalesced.
// ---------------------------------------------------------------------------
__global__ __launch_bounds__(256) void conv_bf16(const float* __restrict__ src,
                                                 bf16* __restrict__ dst) {
  const int i = blockIdx.x * 256 + threadIdx.x;
  *reinterpret_cast<bf16x8*>(dst + (size_t)i * 8) = ld8any(src + (size_t)i * 8);
}

__global__ __launch_bounds__(256) void conv_w4(const float* __restrict__ w0,
                                               const float* __restrict__ w1,
                                               const float* __restrict__ w2,
                                               const float* __restrict__ w3,
                                               bf16* __restrict__ dst) {
  const float* srcs[4] = {w0, w1, w2, w3};
  const float* s = srcs[blockIdx.y];
  bf16* d = dst + (size_t)blockIdx.y * 262144;
  const int i = blockIdx.x * 256 + threadIdx.x;
  *reinterpret_cast<bf16x8*>(d + (size_t)i * 8) = ld8any(s + (size_t)i * 8);
}

// ---------------------------------------------------------------------------
// Y[R x 512] = X[R x 512] @ W^T. BM=128, BN=64. 4 waves, wave tile 64x32.
// grid = (R/128)*8, XCD-swizzled. MODE 0: row-major. MODE 1: k_head.
// MODE 2: vT (LDS-staged transpose). FRAG=1 -> fragment-linear layouts above.
// ---------------------------------------------------------------------------
#define T2STR 136

template <int MODE, int FRAG, typename TX, typename TW, typename TY>
__global__ __launch_bounds__(256) void gemmbn64(const TX* __restrict__ X,
                                                const TW* __restrict__ W,
                                                TY* __restrict__ Y) {
  __shared__ __align__(16) bf16 tile[(MODE == 2) ? 64 * T2STR : 8];
  const int id   = blockIdx.x;
  const int s_   = id >> 3;
  const int xblk = (id & 7) + 8 * (s_ >> 3);
  const int yblk = s_ & 7;
  const int tid  = threadIdx.x;
  const int lane = tid & 63, w = tid >> 6;
  const int col16 = lane & 15, quad = lane >> 4, kq = quad << 3;
  const int wm = w >> 1, wn = w & 1;
  const int m0 = xblk * 128 + wm * 64;
  const int n0 = yblk * 64 + wn * 32;
  const TX* xr = X + (size_t)(m0 + col16) * SH + kq;
  const TW* wr = W + (size_t)(n0 + col16) * SH + kq;
  f32x4 acc[4][2];
#pragma unroll
  for (int i = 0; i < 4; ++i)
#pragma unroll
    for (int j = 0; j < 2; ++j) acc[i][j] = f32x4{0.f,0.f,0.f,0.f};
#pragma unroll
  for (int k0 = 0; k0 < SH; k0 += 32) {
    bf16x8 af[4], bfr[2];
#pragma unroll
    for (int t = 0; t < 4; ++t) af[t]  = ld8any(xr + (size_t)(t*16) * SH + k0);
#pragma unroll
    for (int t = 0; t < 2; ++t) bfr[t] = ld8any(wr + (size_t)(t*16) * SH + k0);
#pragma unroll
    for (int mt = 0; mt < 4; ++mt)
#pragma unroll
      for (int nt = 0; nt < 2; ++nt)
        acc[mt][nt] = mfma16(af[mt], bfr[nt], acc[mt][nt]);
  }

  if constexpr (MODE == 0) {
#pragma unroll
    for (int mt = 0; mt < 4; ++mt)
#pragma unroll
      for (int r = 0; r < 4; ++r) {
        const int row = m0 + mt*16 + quad*4 + r;
        TY* yr = Y + (size_t)row * SH + n0 + col16;
        st1(yr,      acc[mt][0][r]);
        st1(yr + 16, acc[mt][1][r]);
      }
  } else if constexpr (MODE == 1 && FRAG == 0) {
#pragma unroll
    for (int mt = 0; mt < 4; ++mt)
#pragma unroll
      for (int r = 0; r < 4; ++r) {
        const int row = m0 + mt*16 + quad*4 + r;
        const int b = row / SN, sr = row - b * SN;
        bf16* yr = (bf16*)Y + (size_t)((b*NH + yblk)*SN + sr) * HD
                 + wn*32 + col16;
        yr[0]  = __float2bfloat16(acc[mt][0][r]);
        yr[16] = __float2bfloat16(acc[mt][1][r]);
      }
  } else if constexpr (MODE == 1 && FRAG == 1) {
    // fragment-linear K: base + 256 for the +16 d column (dq += 2)
    const int dq = col16 >> 3, de = col16 & 7;
#pragma unroll
    for (int mt = 0; mt < 4; ++mt)
#pragma unroll
      for (int r = 0; r < 4; ++r) {
        const int row = m0 + mt*16 + quad*4 + r;
        const int b = row / SN, sr = row - b * SN;
        bf16* yr = (bf16*)Y
            + ((((size_t)(b*NH + yblk)*96 + (sr>>4))*2 + wn)*512)
            + (size_t)((sr&15)*8 + dq*128 + de);
        yr[0]   = __float2bfloat16(acc[mt][0][r]);
        yr[256] = __float2bfloat16(acc[mt][1][r]);
      }
  } else {
    // stage transposed: tile[d][row_loc]
#pragma unroll
    for (int mt = 0; mt < 4; ++mt)
#pragma unroll
      for (int r = 0; r < 4; ++r) {
        const int row_loc = wm*64 + mt*16 + quad*4 + r;
#pragma unroll
        for (int nt = 0; nt < 2; ++nt) {
          const int d = wn*32 + nt*16 + col16;
          tile[d * T2STR + row_loc] = __float2bfloat16(acc[mt][nt][r]);
        }
      }
    __syncthreads();
    const int d  = tid >> 2;      // 0..63
    const int hq = tid & 3;       // 32-row quarter
    const bf16* src = tile + d * T2STR + hq * 32;
    const int row0 = xblk*128 + hq*32;
    const int b = row0 / SN, sr0 = row0 - b * SN;
    if constexpr (FRAG == 0) {
      bf16* dst = (bf16*)Y + (size_t)((b*NH + yblk)*HD + d) * SN + sr0;
#pragma unroll
      for (int i = 0; i < 4; ++i)
        reinterpret_cast<uint4*>(dst)[i] = reinterpret_cast<const uint4*>(src)[i];
    } else {
      // fragment-linear V
      const int hb2 = b*NH + yblk;
      bf16* dstF = (bf16*)Y + (((size_t)hb2*4 + (d>>4))*96)*256 + (size_t)(d&15)*8;
#pragma unroll
      for (int i = 0; i < 4; ++i) {
        const int key = sr0 + i*8;
        const size_t off = (size_t)(key>>4)*256 + (size_t)((key>>3)&1)*128;
        *reinterpret_cast<uint4*>(dstF + off) = reinterpret_cast<const uint4*>(src)[i];
      }
    }
  }
}

// ---------------------------------------------------------------------------
// transpose_pe: FRAG=0 -> peT[l][d]; FRAG=1 -> fragment-linear peF
// ---------------------------------------------------------------------------
template <int FRAG>
__global__ void transpose_pe(const float* __restrict__ pe, bf16* __restrict__ peT) {
  int idx = blockIdx.x * 256 + threadIdx.x;
  int l = idx >> 6, d = idx & 63;
  if constexpr (FRAG == 0) {
    peT[idx] = __float2bfloat16(pe[d * SL + l]);
  } else {
    peT[(size_t)((l>>4)*2 + (d>>5))*512
        + (size_t)((((d>>3)&3)*16 + (l&15))*8 + (d&7))]
      = __float2bfloat16(pe[d * SL + l]);
  }
}

// ---------------------------------------------------------------------------
// Barrier-free wave-private fused attention (v6, fragment-linear loads).
// One 64-lane wave owns 16 query rows; grid 2048 x 64 threads.
// Operand-swapped MFMAs keep lane&15 == query-row in EVERY phase.
// All operand loads are now FULLY COALESCED 1KB bursts (base + lane*16B) from
// the fragment-linear buffers; address math is one shared lane*8 offset, so
// the prefetched fragments fit in registers and sched_barrier(0) pins the
// issue point (compiler previously sank the prefetch -> serialized latency).
// ---------------------------------------------------------------------------
#define PSTR1 69    // pos stride (f32): scalar writes, b128-aligned reads
#define BSTR1 104   // P stride (bf16): b64 writes, b128 reads aligned

__global__ __launch_bounds__(64, 2) void attn1w(
    const bf16* __restrict__ qp, const bf16* __restrict__ Kh,
    const bf16* __restrict__ VT, const bf16* __restrict__ peT,
    const float* __restrict__ spanv, bf16* __restrict__ ctx) {
  __shared__ __align__(16) float pos_s[16 * PSTR1];
  __shared__ __align__(16) bf16  P_s[16 * BSTR1];

  const int id = blockIdx.x;
  const int h  = id & 7;
  const int s_ = id >> 3;
  const int m0 = (s_ & 31) * 16;
  const int b  = s_ >> 5;
  const int hb = b * 8 + h;
  const int lane  = threadIdx.x;
  const int col16 = lane & 15, quad = lane >> 4, kq = quad << 3;
  const int q4 = quad << 2;
  const int lane8 = lane * 8;

  // zero P band once (cols 80..103 stay zero; read by ks=2 PV fragment)
  for (int i = lane; i < 16 * BSTR1; i += 64)
    P_s[i] = __float2bfloat16(0.0f);

  const bf16* qb = qp + (size_t)(b*SM + m0 + col16) * SH + h*HD + kq;
  const bf16x8 qf0 = ld8any(qb), qf1 = ld8any(qb + 32);

  const bf16* kbF = Kh + (size_t)hb * 98304 + lane8;   // 96 tiles * 1024
  const bf16* vbF = VT + (size_t)hb * 98304 + lane8;   // 4 dt * 96 kt * 256
  const bf16* pbF = peT + lane8;

  float Mrun = -1.0e30f, Srun = 0.0f;
  const float span1024 = spanv[h] * 1024.0f;
  f32x4 o[4];
#pragma unroll
  for (int dt = 0; dt < 4; ++dt) o[dt] = f32x4{0.f,0.f,0.f,0.f};

  // prefetched operand fragments (single-buffered; WAR ordering via reg deps)
  bf16x8 kf[5][2], pf[4][2], vf[4][3];

  // ---- prologue: chunk-0 operands ----
  {
    const int tk0 = m0 >> 4;
#pragma unroll
    for (int t = 0; t < 5; ++t) {
      const bf16* kr = kbF + (size_t)(tk0 + t) * 1024;
      kf[t][0] = ld8any(kr); kf[t][1] = ld8any(kr + 512);
    }
#pragma unroll
    for (int t = 0; t < 4; ++t) {
      const bf16* pr = pbF + (size_t)t * 1024;
      pf[t][0] = ld8any(pr); pf[t][1] = ld8any(pr + 512);
    }
#pragma unroll
    for (int dt = 0; dt < 4; ++dt) {
      const bf16* v0 = vbF + (size_t)dt * 24576 + (size_t)tk0 * 256;
#pragma unroll
      for (int ks = 0; ks < 3; ++ks) vf[dt][ks] = ld8any(v0 + ks*512);
    }
    __builtin_amdgcn_sched_barrier(0);
  }

  const int posw = col16 * PSTR1 + q4;        // write base (scalar f32)
  const int posr = col16 * (PSTR1 - 1) + q4;  // read base (b128-aligned)
  const int pww  = col16 * BSTR1 + q4;        // P write base (b64-aligned)
  const int pwr  = col16 * BSTR1 + kq;        // P read base (b128-aligned)

  for (int ch = 0; ch < 16; ++ch) {
    const int l0 = ch << 6;

    // ---- pos MFMAs (swapped: A=pe rows, D rows = l, cols = q-row) ----
    f32x4 pacc[4];
#pragma unroll
    for (int t = 0; t < 4; ++t) {
      f32x4 a = {0.f,0.f,0.f,0.f};
      a = mfma16(pf[t][0], qf0, a);
      a = mfma16(pf[t][1], qf1, a);
      pacc[t] = a;
    }
    // scalar writes: pos_s[qrow][l], qrow = col16, l = 16t + q4 + r
#pragma unroll
    for (int t = 0; t < 4; ++t)
#pragma unroll
      for (int r = 0; r < 4; ++r)
        pos_s[posw + 16*t + r] = pacc[t][r];

    // ---- cont MFMAs (swapped: A=K rows, D rows = band pos, cols = q-row) ----
    f32x4 cacc[5];
#pragma unroll
    for (int t = 0; t < 5; ++t) {
      f32x4 a = {0.f,0.f,0.f,0.f};
      a = mfma16(kf[t][0], qf0, a);
      a = mfma16(kf[t][1], qf1, a);
      cacc[t] = a;
    }

    // ---- issue next chunk's K/pe (kf/pf regs now dead); pinned early so
    //      they stay in flight across the softmax below ----
    {
      const int l0n = (ch < 15) ? l0 + 64 : l0;
      const int tkn = (m0 + l0n) >> 4;
      const int tpn = l0n >> 4;
#pragma unroll
      for (int t = 0; t < 5; ++t) {
        const bf16* kr = kbF + (size_t)(tkn + t) * 1024;
        kf[t][0] = ld8any(kr); kf[t][1] = ld8any(kr + 512);
      }
#pragma unroll
      for (int t = 0; t < 4; ++t) {
        const bf16* pr = pbF + (size_t)(tpn + t) * 1024;
        pf[t][0] = ld8any(pr); pf[t][1] = ld8any(pr + 512);
      }
      __builtin_amdgcn_sched_barrier(0);
    }

    // ---- per-lane softmax over this row's 64-key window ----
    // lane's cont value (t,r): band pos bp = 16t+q4+r, l = bp - col16.
    float sc[5][4];
    float mc = -1.0e30f;
#pragma unroll
    for (int t = 0; t < 5; ++t) {
      const f32x4 pv4 = *reinterpret_cast<const f32x4*>(&pos_s[posr + 16*t]);
#pragma unroll
      for (int r = 0; r < 4; ++r) {
        const int l = 16*t + q4 + r - col16;
        float v = (cacc[t][r] + pv4[r]) * 0.125f;
        v = ((unsigned)l < 64u) ? v : -1.0e30f;
        sc[t][r] = v;
        mc = fmaxf(mc, v);
      }
    }
    mc = fmaxf(mc, __shfl_xor(mc, 16));
    mc = fmaxf(mc, __shfl_xor(mc, 32));
    const float Mnew = fmaxf(Mrun, mc);
    const float alpha = __expf(Mrun - Mnew);
    float ls = 0.0f;
#pragma unroll
    for (int t = 0; t < 5; ++t) {
      short4_ pk;
#pragma unroll
      for (int r = 0; r < 4; ++r) {
        const float p = __expf(sc[t][r] - Mnew);   // 0 for masked slots
        ls += p;
        const float lg = (float)(l0 + 16*t + q4 + r - col16);
        float mv = (lg - 1023.0f + span1024) * 0.03125f + 1.0f;
        mv = fminf(fmaxf(mv, 0.0f), 1.0f);
        pk[r] = bf_bits(p * mv);
      }
      *reinterpret_cast<short4_*>(&P_s[pww + 16*t]) = pk;
    }
    ls += __shfl_xor(ls, 16);
    ls += __shfl_xor(ls, 32);
    Srun = Srun * alpha + ls;
    Mrun = Mnew;

    // ---- PV (swapped: A=V^T rows=d, B=P cols=q-row) ----
#pragma unroll
    for (int dt = 0; dt < 4; ++dt)
#pragma unroll
      for (int r = 0; r < 4; ++r) o[dt][r] *= alpha;
#pragma unroll
    for (int ks = 0; ks < 3; ++ks) {
      const bf16x8 ap = ld8any(&P_s[pwr + ks*32]);
#pragma unroll
      for (int dt = 0; dt < 4; ++dt)
        o[dt] = mfma16(vf[dt][ks], ap, o[dt]);
    }

    // ---- issue next chunk's V (vf regs now dead); pinned early ----
    {
      const int tkn = (m0 + ((ch < 15) ? l0 + 64 : l0)) >> 4;
#pragma unroll
      for (int dt = 0; dt < 4; ++dt) {
        const bf16* v0 = vbF + (size_t)dt * 24576 + (size_t)tkn * 256;
#pragma unroll
        for (int ks = 0; ks < 3; ++ks) vf[dt][ks] = ld8any(v0 + ks*512);
      }
      __builtin_amdgcn_sched_barrier(0);
    }
  }

  // ---- epilogue: lane-local normalize, packed b64 stores ----
  const float inv = 1.0f / Srun;
  bf16* cr = ctx + (size_t)(b*SM + m0 + col16) * SH + h*HD + q4;
#pragma unroll
  for (int dt = 0; dt < 4; ++dt) {
    short4_ pk;
#pragma unroll
    for (int r = 0; r < 4; ++r) pk[r] = bf_bits(o[dt][r] * inv);
    *reinterpret_cast<short4_*>(cr + 16*dt) = pk;
  }
}

// ---------------------------------------------------------------------------
// Fallback fused attention (round-6 proven): 16 rows/block, 2 waves, fused q.
// Uses the OLD (non-fragment) layouts.
// ---------------------------------------------------------------------------
#define MT 16
#define CSTR 84
#define PSTR 65
#define BSTR 104
#define QSTR 72

__global__ __launch_bounds__(128) void attn_kernel_fb(
    const float* __restrict__ query, const float* __restrict__ Wq,
    const bf16* __restrict__ Kh, const bf16* __restrict__ VT,
    const bf16* __restrict__ peT, const float* __restrict__ spanv,
    bf16* __restrict__ ctx) {
  __shared__ __align__(16) float cont_lds[MT][CSTR];
  __shared__ __align__(16) float pos_lds[MT][PSTR];
  __shared__ __align__(16) bf16  P_lds[MT][BSTR];
  __shared__ __align__(16) bf16  q_lds[MT*QSTR];
  __shared__ float alpha_lds[MT];
  __shared__ float S_lds[MT];

  const int id = blockIdx.x;
  const int h  = id & 7;
  const int s_ = id >> 3;
  const int m0 = (s_ & 31) * MT;
  const int b  = s_ >> 5;
  const int hb = b * 8 + h;
  const int tid  = threadIdx.x;
  const int lane = tid & 63;
  const int w    = tid >> 6;
  const int col16 = lane & 15, quad = lane >> 4, kq = quad << 3;
  const int wr = quad << 2;

  for (int i = tid; i < MT * BSTR; i += 128)
    (&P_lds[0][0])[i] = __float2bfloat16(0.0f);

  bf16x8 qf0, qf1;
  {
    f32x4 qa0 = {0.f,0.f,0.f,0.f}, qa1 = qa0;
    const float* xq = query + (size_t)(b*SM + m0 + col16) * SH + kq;
    const float* w0 = Wq + (size_t)(h*HD + w*32 + col16) * SH + kq;
    const float* w1 = w0 + (size_t)16 * SH;
#pragma unroll
    for (int k0 = 0; k0 < SH; k0 += 32) {
      bf16x8 xa = ld8any(xq + k0);
      qa0 = mfma16(xa, ld8any(w0 + k0), qa0);
      qa1 = mfma16(xa, ld8any(w1 + k0), qa1);
    }
#pragma unroll
    for (int r = 0; r < 4; ++r) {
      q_lds[(wr + r)*QSTR + w*32 + col16]      = __float2bfloat16(qa0[r]);
      q_lds[(wr + r)*QSTR + w*32 + 16 + col16] = __float2bfloat16(qa1[r]);
    }
    __syncthreads();
    qf0 = ld8any(&q_lds[col16*QSTR + kq]);
    qf1 = ld8any(&q_lds[col16*QSTR + kq + 32]);
  }

  const bf16* kb = Kh + (size_t)(hb * SN) * HD + kq;
  const bf16* vb = VT + (size_t)(hb * HD) * SN;

  const int srow = tid >> 3, sj = tid & 7;
  float Mrun = -1.0e30f, Srun = 0.0f;
  const float span = spanv[h];
  const int dt0 = w * 16, dt1 = (w + 2) * 16;
  f32x4 o0 = {0.f,0.f,0.f,0.f}, o1 = o0;

  for (int ch = 0; ch < 16; ++ch) {
    const int l0 = ch << 6;
    const int nb_ = m0 + l0;

    f32x4 ca0 = {0.f,0.f,0.f,0.f}, ca1 = ca0, ca2 = ca0, pa0 = ca0, pa1 = ca0;
    {
      const bf16* kr0 = kb + (size_t)(nb_ + w*16 + col16) * HD;
      ca0 = mfma16(qf0, ld8any(kr0),           ca0);
      ca0 = mfma16(qf1, ld8any(kr0 + 32),      ca0);
      const bf16* kr1 = kr0 + 32 * HD;
      ca1 = mfma16(qf0, ld8any(kr1),           ca1);
      ca1 = mfma16(qf1, ld8any(kr1 + 32),      ca1);
      if (w == 0) {
        const bf16* kr2 = kr0 + 64 * HD;
        ca2 = mfma16(qf0, ld8any(kr2),         ca2);
        ca2 = mfma16(qf1, ld8any(kr2 + 32),    ca2);
      }
      const bf16* pr0 = peT + (size_t)(l0 + w*16 + col16) * HD + kq;
      pa0 = mfma16(qf0, ld8any(pr0),           pa0);
      pa0 = mfma16(qf1, ld8any(pr0 + 32),      pa0);
      const bf16* pr1 = pr0 + 32 * HD;
      pa1 = mfma16(qf0, ld8any(pr1),           pa1);
      pa1 = mfma16(qf1, ld8any(pr1 + 32),      pa1);
    }
#pragma unroll
    for (int r = 0; r < 4; ++r) {
      cont_lds[wr + r][w*16 + col16]      = ca0[r];
      cont_lds[wr + r][w*16 + 32 + col16] = ca1[r];
      if (w == 0) cont_lds[wr + r][64 + col16] = ca2[r];
      pos_lds[wr + r][w*16 + col16]       = pa0[r];
      pos_lds[wr + r][w*16 + 32 + col16]  = pa1[r];
    }
    __syncthreads();

    float sc[8];
    float mc = -1.0e30f;
    const float* crow = &cont_lds[srow][srow + sj*8];
    const float* prow = &pos_lds[srow][sj*8];
#pragma unroll
    for (int i = 0; i < 8; ++i) {
      float v = (crow[i] + prow[i]) * 0.125f;
      sc[i] = v;
      mc = fmaxf(mc, v);
    }
    mc = fmaxf(mc, __shfl_xor(mc, 1));
    mc = fmaxf(mc, __shfl_xor(mc, 2));
    mc = fmaxf(mc, __shfl_xor(mc, 4));
    const float Mnew = fmaxf(Mrun, mc);
    const float alpha = __expf(Mrun - Mnew);
    float ls = 0.0f;
    bf16* pwrow = &P_lds[srow][srow + sj*8];
#pragma unroll
    for (int i = 0; i < 8; ++i) {
      float p = __expf(sc[i] - Mnew);
      ls += p;
      const float tpl = (float)(l0 + sj*8 + i) - 1023.0f;
      float mv = (tpl + span * 1024.0f) * 0.03125f + 1.0f;
      mv = fminf(fmaxf(mv, 0.0f), 1.0f);
      pwrow[i] = __float2bfloat16(p * mv);
    }
    ls += __shfl_xor(ls, 1);
    ls += __shfl_xor(ls, 2);
    ls += __shfl_xor(ls, 4);
    Srun = Srun * alpha + ls;
    Mrun = Mnew;
    if (sj == 0) { alpha_lds[srow] = alpha; S_lds[srow] = Srun; }
    __syncthreads();

    float al[4];
#pragma unroll
    for (int r = 0; r < 4; ++r) al[r] = alpha_lds[wr + r];
#pragma unroll
    for (int r = 0; r < 4; ++r) { o0[r] *= al[r]; o1[r] *= al[r]; }
#pragma unroll
    for (int ks = 0; ks < 3; ++ks) {
      const bf16x8 ap = ld8any(&P_lds[col16][ks*32 + kq]);
      const bf16* v0 = vb + (size_t)(dt0 + col16) * SN + nb_ + ks*32 + kq;
      const bf16* v1 = vb + (size_t)(dt1 + col16) * SN + nb_ + ks*32 + kq;
      o0 = mfma16(ap, ld8any(v0), o0);
      o1 = mfma16(ap, ld8any(v1), o1);
    }
  }

  bf16* cr = ctx + (size_t)(b*SM + m0 + wr) * SH + h*HD + col16;
#pragma unroll
  for (int r = 0; r < 4; ++r) {
    const float inv = 1.0f / S_lds[wr + r];
    cr[(size_t)r * SH + dt0] = __float2bfloat16(o0[r] * inv);
    cr[(size_t)r * SH + dt1] = __float2bfloat16(o1[r] * inv);
  }
}

// ---------------------------------------------------------------------------
extern "C" void kernel_launch(void* const* d_in, const int* in_sizes, int n_in,
                              void* d_out, int out_size, void* d_ws, size_t ws_size,
                              hipStream_t stream) {
  const float* query  = (const float*)d_in[0];
  const float* key    = (const float*)d_in[1];
  const float* value  = (const float*)d_in[2];
  const float* key_pe = (const float*)d_in[3];
  const float* Wq     = (const float*)d_in[4];
  const float* Wk     = (const float*)d_in[5];
  const float* Wv     = (const float*)d_in[6];
  const float* Wo     = (const float*)d_in[7];
  const float* spanv  = (const float*)d_in[8];
  float* out = (float*)d_out;

  bf16* ws = (bf16*)d_ws;
  if (ws_size >= (size_t)48365568) {
    // Path C: bf16-converted pipeline, 48.4 MB ws, fragment-linear K/V/pe.
    bf16* stg    = ws;                    // 6291456 el, reused key->value
    bf16* k_head = stg    + 6291456;      // kF: 64*96*2*512 = 6291456
    bf16* vT     = k_head + 6291456;      // vF: 64*4*96*256 = 6291456
    bf16* qp     = vT     + 6291456;
    bf16* ctx    = qp     + 2097152;
    bf16* peT    = ctx    + 2097152;      // peF: 64*2*512 = 65536
    bf16* Wb     = peT    + 65536;
    bf16* Wq_b = Wb, *Wk_b = Wb + 262144, *Wv_b = Wb + 524288, *Wo_b = Wb + 786432;

    conv_w4<<<dim3(128, 4), 256, 0, stream>>>(Wq, Wk, Wv, Wo, Wb);
    transpose_pe<1><<<256, 256, 0, stream>>>(key_pe, peT);

    conv_bf16<<<3072, 256, 0, stream>>>(key, stg);
    gemmbn64<1, 1, bf16, bf16, bf16><<<768, 256, 0, stream>>>(stg, Wk_b, k_head);
    conv_bf16<<<3072, 256, 0, stream>>>(value, stg);
    gemmbn64<2, 1, bf16, bf16, bf16><<<768, 256, 0, stream>>>(stg, Wv_b, vT);
    gemmbn64<0, 0, float, bf16, bf16><<<256, 256, 0, stream>>>(query, Wq_b, qp);

    attn1w<<<2048, 64, 0, stream>>>(qp, k_head, vT, peT, spanv, ctx);
    gemmbn64<0, 0, bf16, bf16, float><<<256, 256, 0, stream>>>(ctx, Wo_b, out);
  } else {
    // Path B (fallback): fused-q attention, f32 GEMM reads, 29.5 MB ws.
    bf16* k_head = ws;
    bf16* vT     = k_head + 6291456;
    bf16* ctx    = vT     + 6291456;
    bf16* peT    = ctx    + 2097152;
    gemmbn64<1, 0, float, float, bf16><<<768, 256, 0, stream>>>(key,   Wk, k_head);
    gemmbn64<2, 0, float, float, bf16><<<768, 256, 0, stream>>>(value, Wv, vT);
    transpose_pe<0><<<256, 256, 0, stream>>>(key_pe, peT);
    attn_kernel_fb<<<2048, 128, 0, stream>>>(query, Wq, k_head, vT,
                                             peT, spanv, ctx);
    gemmbn64<0, 0, bf16, float, float><<<256, 256, 0, stream>>>(ctx, Wo, out);
  }
}

// Round 6
// 217.289 us; speedup vs baseline: 1.7116x; 1.1942x over previous
//
#include <hip/hip_runtime.h>
#include <hip/hip_bf16.h>
#include <type_traits>

typedef __hip_bfloat16 bf16;
typedef short bf16x8 __attribute__((ext_vector_type(8)));
typedef float f32x4 __attribute__((ext_vector_type(4)));
typedef short short4_ __attribute__((ext_vector_type(4)));

#define NB 8      // batch
#define SM 512    // block size M
#define SL 1024   // attn span L
#define SH 512    // hidden
#define NH 8      // heads
#define HD 64     // head dim
#define SN 1536   // M + L (key length)

static __device__ __forceinline__ short bf_bits(float x) {
  union { bf16 b; short s; } u; u.b = __float2bfloat16(x); return u.s;
}
static __device__ __forceinline__ bf16x8 ld8any(const bf16* p) {
  return *reinterpret_cast<const bf16x8*>(p);
}
static __device__ __forceinline__ bf16x8 ld8any(const float* p) {
  float4 a = *reinterpret_cast<const float4*>(p);
  float4 b = *reinterpret_cast<const float4*>(p + 4);
  bf16x8 r;
  r[0] = bf_bits(a.x); r[1] = bf_bits(a.y); r[2] = bf_bits(a.z); r[3] = bf_bits(a.w);
  r[4] = bf_bits(b.x); r[5] = bf_bits(b.y); r[6] = bf_bits(b.z); r[7] = bf_bits(b.w);
  return r;
}
static __device__ __forceinline__ void st1(bf16* p, float v) { *p = __float2bfloat16(v); }
static __device__ __forceinline__ void st1(float* p, float v) { *p = v; }
static __device__ __forceinline__ f32x4 mfma16(bf16x8 a, bf16x8 b, f32x4 c) {
  return __builtin_amdgcn_mfma_f32_16x16x32_bf16(a, b, c, 0, 0, 0);
}

// ---------------------------------------------------------------------------
// Universal fragment-linear layout for an [R x C] matrix (C multiple of 32):
//   FRAGIDX(row,col) = (row>>4)*(16*C) + (col>>5)*512
//                    + ((col>>3)&3)*128 + (row&15)*8 + (col&7)
// One wave MFMA fragment (16 rows x 32 cols) = 1KB contiguous, lane*16B.
// Used for: X/W of all GEMMs (C=512), kF (C=64 per key-row grp), vF, qpF, ctxF.
// ---------------------------------------------------------------------------

// f32/bf16 row-major -> bf16 fragment-linear (C=512), 8 el/thread.
template <typename T>
__global__ __launch_bounds__(256) void conv_frag(const T* __restrict__ src,
                                                 bf16* __restrict__ dst) {
  const int i = blockIdx.x * 256 + threadIdx.x;
  const size_t flat = (size_t)i * 8;
  const int row = (int)(flat >> 9), k = (int)(flat & 511);
  const size_t a = (size_t)(row >> 4) * 8192 + (size_t)(k >> 5) * 512
                 + (size_t)(((k >> 3) & 3) * 128 + (row & 15) * 8);
  *reinterpret_cast<bf16x8*>(dst + a) = ld8any(src + flat);
}

// 4 weight matrices [512x512] -> fragment-linear.
__global__ __launch_bounds__(256) void conv_w4f(const float* __restrict__ w0,
                                                const float* __restrict__ w1,
                                                const float* __restrict__ w2,
                                                const float* __restrict__ w3,
                                                bf16* __restrict__ dst) {
  const float* srcs[4] = {w0, w1, w2, w3};
  const float* s = srcs[blockIdx.y];
  bf16* d = dst + (size_t)blockIdx.y * 262144;
  const int i = blockIdx.x * 256 + threadIdx.x;
  const size_t flat = (size_t)i * 8;
  const int row = (int)(flat >> 9), k = (int)(flat & 511);
  const size_t a = (size_t)(row >> 4) * 8192 + (size_t)(k >> 5) * 512
                 + (size_t)(((k >> 3) & 3) * 128 + (row & 15) * 8);
  *reinterpret_cast<bf16x8*>(d + a) = ld8any(s + flat);
}

// ---------------------------------------------------------------------------
// gemmF: Y[R x 512] = X @ W^T with X, W in fragment-linear layout (coalesced
// 1KB fragment loads). BM=128, BN=64, 4 waves, wave tile 64x32, XCD swizzle.
// MODE 0: row-major TY out. MODE 1: kF out. MODE 2: vF out (LDS transpose).
// MODE 3: qp fragment-linear out (= attn's q-read layout).
// ---------------------------------------------------------------------------
#define T2STR 136

template <int MODE, typename TY>
__global__ __launch_bounds__(256) void gemmF(const bf16* __restrict__ XF,
                                             const bf16* __restrict__ WF,
                                             TY* __restrict__ Y) {
  __shared__ __align__(16) bf16 tile[(MODE == 2) ? 64 * T2STR : 8];
  const int id   = blockIdx.x;
  const int s_   = id >> 3;
  const int xblk = (id & 7) + 8 * (s_ >> 3);
  const int yblk = s_ & 7;
  const int tid  = threadIdx.x;
  const int lane = tid & 63, w = tid >> 6;
  const int col16 = lane & 15, quad = lane >> 4;
  const int lane8 = lane * 8;
  const int wm = w >> 1, wn = w & 1;
  const int m0 = xblk * 128 + wm * 64;
  const int n0 = yblk * 64 + wn * 32;
  const bf16* xr = XF + (size_t)(m0 >> 4) * 8192 + lane8;
  const bf16* wr = WF + (size_t)(n0 >> 4) * 8192 + lane8;
  f32x4 acc[4][2];
#pragma unroll
  for (int i = 0; i < 4; ++i)
#pragma unroll
    for (int j = 0; j < 2; ++j) acc[i][j] = f32x4{0.f,0.f,0.f,0.f};
#pragma unroll
  for (int kt = 0; kt < 16; ++kt) {
    bf16x8 af[4], bfr[2];
#pragma unroll
    for (int t = 0; t < 4; ++t) af[t]  = ld8any(xr + (size_t)t * 8192 + kt * 512);
#pragma unroll
    for (int t = 0; t < 2; ++t) bfr[t] = ld8any(wr + (size_t)t * 8192 + kt * 512);
#pragma unroll
    for (int mt = 0; mt < 4; ++mt)
#pragma unroll
      for (int nt = 0; nt < 2; ++nt)
        acc[mt][nt] = mfma16(af[mt], bfr[nt], acc[mt][nt]);
  }

  if constexpr (MODE == 0) {
#pragma unroll
    for (int mt = 0; mt < 4; ++mt)
#pragma unroll
      for (int r = 0; r < 4; ++r) {
        const int row = m0 + mt*16 + quad*4 + r;
        TY* yr = Y + (size_t)row * SH + n0 + col16;
        st1(yr,      acc[mt][0][r]);
        st1(yr + 16, acc[mt][1][r]);
      }
  } else if constexpr (MODE == 1) {
    // kF: per hb, per 16-key tile: [2 d-halves][512]; in-half lane-linear.
    const int dq = col16 >> 3, de = col16 & 7;
#pragma unroll
    for (int mt = 0; mt < 4; ++mt)
#pragma unroll
      for (int r = 0; r < 4; ++r) {
        const int row = m0 + mt*16 + quad*4 + r;
        const int b = row / SN, sr = row - b * SN;
        bf16* yr = (bf16*)Y
            + ((((size_t)(b*NH + yblk)*96 + (sr>>4))*2 + wn)*512)
            + (size_t)((sr&15)*8 + dq*128 + de);
        yr[0]   = __float2bfloat16(acc[mt][0][r]);
        yr[256] = __float2bfloat16(acc[mt][1][r]);
      }
  } else if constexpr (MODE == 3) {
    // qp fragment-linear (FRAGIDX with C=512): row = m0+mt*16+quad*4+r,
    // col = n0+col16 (+16). (col>>5)=yblk*2+wn, ((col>>3)&3)=col16>>3 (+2).
    const int dq2 = col16 >> 3, de = col16 & 7;
#pragma unroll
    for (int mt = 0; mt < 4; ++mt)
#pragma unroll
      for (int r = 0; r < 4; ++r) {
        bf16* yr = (bf16*)Y + (size_t)((m0>>4) + mt) * 8192
                 + (size_t)(yblk*2 + wn) * 512
                 + (size_t)(dq2*128 + (quad*4 + r)*8 + de);
        yr[0]   = __float2bfloat16(acc[mt][0][r]);
        yr[256] = __float2bfloat16(acc[mt][1][r]);
      }
  } else {
    // vF via LDS transpose: tile[d][row_loc]
#pragma unroll
    for (int mt = 0; mt < 4; ++mt)
#pragma unroll
      for (int r = 0; r < 4; ++r) {
        const int row_loc = wm*64 + mt*16 + quad*4 + r;
#pragma unroll
        for (int nt = 0; nt < 2; ++nt) {
          const int d = wn*32 + nt*16 + col16;
          tile[d * T2STR + row_loc] = __float2bfloat16(acc[mt][nt][r]);
        }
      }
    __syncthreads();
    const int d  = tid >> 2;      // 0..63
    const int hq = tid & 3;       // 32-row quarter
    const bf16* src = tile + d * T2STR + hq * 32;
    const int row0 = xblk*128 + hq*32;
    const int b = row0 / SN, sr0 = row0 - b * SN;
    const int hb2 = b*NH + yblk;
    bf16* dstF = (bf16*)Y + (((size_t)hb2*4 + (d>>4))*96)*256 + (size_t)(d&15)*8;
#pragma unroll
    for (int i = 0; i < 4; ++i) {
      const int key = sr0 + i*8;
      const size_t off = (size_t)(key>>4)*256 + (size_t)((key>>3)&1)*128;
      *reinterpret_cast<uint4*>(dstF + off) = reinterpret_cast<const uint4*>(src)[i];
    }
  }
}

// ---------------------------------------------------------------------------
// transpose_pe: FRAG=0 -> peT[l][d]; FRAG=1 -> fragment-linear peF
// ---------------------------------------------------------------------------
template <int FRAG>
__global__ void transpose_pe(const float* __restrict__ pe, bf16* __restrict__ peT) {
  int idx = blockIdx.x * 256 + threadIdx.x;
  int l = idx >> 6, d = idx & 63;
  if constexpr (FRAG == 0) {
    peT[idx] = __float2bfloat16(pe[d * SL + l]);
  } else {
    peT[(size_t)((l>>4)*2 + (d>>5))*512
        + (size_t)((((d>>3)&3)*16 + (l&15))*8 + (d&7))]
      = __float2bfloat16(pe[d * SL + l]);
  }
}

// ---------------------------------------------------------------------------
// Barrier-free wave-private fused attention (v6, fragment-linear loads).
// One 64-lane wave owns 16 query rows; grid 2048 x 64 threads.
// Operand-swapped MFMAs keep lane&15 == query-row in EVERY phase.
// All operand loads are FULLY COALESCED 1KB bursts (base + lane*16B);
// sched_barrier(0) pins the prefetch issue points.
// v7: q read from fragment-linear qp; epilogue writes fragment-linear ctx
// so the Wo GEMM also gets coalesced X reads.
// ---------------------------------------------------------------------------
#define PSTR1 69    // pos stride (f32): scalar writes, b128-aligned reads
#define BSTR1 104   // P stride (bf16): b64 writes, b128 reads aligned

__global__ __launch_bounds__(64, 2) void attn1w(
    const bf16* __restrict__ qp, const bf16* __restrict__ Kh,
    const bf16* __restrict__ VT, const bf16* __restrict__ peT,
    const float* __restrict__ spanv, bf16* __restrict__ ctx) {
  __shared__ __align__(16) float pos_s[16 * PSTR1];
  __shared__ __align__(16) bf16  P_s[16 * BSTR1];

  const int id = blockIdx.x;
  const int h  = id & 7;
  const int s_ = id >> 3;
  const int m0 = (s_ & 31) * 16;
  const int b  = s_ >> 5;
  const int hb = b * 8 + h;
  const int lane  = threadIdx.x;
  const int col16 = lane & 15, quad = lane >> 4, kq = quad << 3;
  const int q4 = quad << 2;
  const int lane8 = lane * 8;

  // zero P band once (cols 80..103 stay zero; read by ks=2 PV fragment)
  for (int i = lane; i < 16 * BSTR1; i += 64)
    P_s[i] = __float2bfloat16(0.0f);

  // q from fragment-linear qp: rt*8192 + h*1024 + lane*8 (and +512)
  const bf16* qb = qp + (size_t)((b*SM + m0) >> 4) * 8192 + h*1024 + lane8;
  const bf16x8 qf0 = ld8any(qb), qf1 = ld8any(qb + 512);

  const bf16* kbF = Kh + (size_t)hb * 98304 + lane8;   // 96 tiles * 1024
  const bf16* vbF = VT + (size_t)hb * 98304 + lane8;   // 4 dt * 96 kt * 256
  const bf16* pbF = peT + lane8;

  float Mrun = -1.0e30f, Srun = 0.0f;
  const float span1024 = spanv[h] * 1024.0f;
  f32x4 o[4];
#pragma unroll
  for (int dt = 0; dt < 4; ++dt) o[dt] = f32x4{0.f,0.f,0.f,0.f};

  // prefetched operand fragments (single-buffered; WAR ordering via reg deps)
  bf16x8 kf[5][2], pf[4][2], vf[4][3];

  // ---- prologue: chunk-0 operands ----
  {
    const int tk0 = m0 >> 4;
#pragma unroll
    for (int t = 0; t < 5; ++t) {
      const bf16* kr = kbF + (size_t)(tk0 + t) * 1024;
      kf[t][0] = ld8any(kr); kf[t][1] = ld8any(kr + 512);
    }
#pragma unroll
    for (int t = 0; t < 4; ++t) {
      const bf16* pr = pbF + (size_t)t * 1024;
      pf[t][0] = ld8any(pr); pf[t][1] = ld8any(pr + 512);
    }
#pragma unroll
    for (int dt = 0; dt < 4; ++dt) {
      const bf16* v0 = vbF + (size_t)dt * 24576 + (size_t)tk0 * 256;
#pragma unroll
      for (int ks = 0; ks < 3; ++ks) vf[dt][ks] = ld8any(v0 + ks*512);
    }
    __builtin_amdgcn_sched_barrier(0);
  }

  const int posw = col16 * PSTR1 + q4;        // write base (scalar f32)
  const int posr = col16 * (PSTR1 - 1) + q4;  // read base (b128-aligned)
  const int pww  = col16 * BSTR1 + q4;        // P write base (b64-aligned)
  const int pwr  = col16 * BSTR1 + kq;        // P read base (b128-aligned)

  for (int ch = 0; ch < 16; ++ch) {
    const int l0 = ch << 6;

    // ---- pos MFMAs (swapped: A=pe rows, D rows = l, cols = q-row) ----
    f32x4 pacc[4];
#pragma unroll
    for (int t = 0; t < 4; ++t) {
      f32x4 a = {0.f,0.f,0.f,0.f};
      a = mfma16(pf[t][0], qf0, a);
      a = mfma16(pf[t][1], qf1, a);
      pacc[t] = a;
    }
    // scalar writes: pos_s[qrow][l], qrow = col16, l = 16t + q4 + r
#pragma unroll
    for (int t = 0; t < 4; ++t)
#pragma unroll
      for (int r = 0; r < 4; ++r)
        pos_s[posw + 16*t + r] = pacc[t][r];

    // ---- cont MFMAs (swapped: A=K rows, D rows = band pos, cols = q-row) ----
    f32x4 cacc[5];
#pragma unroll
    for (int t = 0; t < 5; ++t) {
      f32x4 a = {0.f,0.f,0.f,0.f};
      a = mfma16(kf[t][0], qf0, a);
      a = mfma16(kf[t][1], qf1, a);
      cacc[t] = a;
    }

    // ---- issue next chunk's K/pe (kf/pf regs now dead); pinned early so
    //      they stay in flight across the softmax below ----
    {
      const int l0n = (ch < 15) ? l0 + 64 : l0;
      const int tkn = (m0 + l0n) >> 4;
      const int tpn = l0n >> 4;
#pragma unroll
      for (int t = 0; t < 5; ++t) {
        const bf16* kr = kbF + (size_t)(tkn + t) * 1024;
        kf[t][0] = ld8any(kr); kf[t][1] = ld8any(kr + 512);
      }
#pragma unroll
      for (int t = 0; t < 4; ++t) {
        const bf16* pr = pbF + (size_t)(tpn + t) * 1024;
        pf[t][0] = ld8any(pr); pf[t][1] = ld8any(pr + 512);
      }
      __builtin_amdgcn_sched_barrier(0);
    }

    // ---- per-lane softmax over this row's 64-key window ----
    // lane's cont value (t,r): band pos bp = 16t+q4+r, l = bp - col16.
    float sc[5][4];
    float mc = -1.0e30f;
#pragma unroll
    for (int t = 0; t < 5; ++t) {
      const f32x4 pv4 = *reinterpret_cast<const f32x4*>(&pos_s[posr + 16*t]);
#pragma unroll
      for (int r = 0; r < 4; ++r) {
        const int l = 16*t + q4 + r - col16;
        float v = (cacc[t][r] + pv4[r]) * 0.125f;
        v = ((unsigned)l < 64u) ? v : -1.0e30f;
        sc[t][r] = v;
        mc = fmaxf(mc, v);
      }
    }
    mc = fmaxf(mc, __shfl_xor(mc, 16));
    mc = fmaxf(mc, __shfl_xor(mc, 32));
    const float Mnew = fmaxf(Mrun, mc);
    const float alpha = __expf(Mrun - Mnew);
    float ls = 0.0f;
#pragma unroll
    for (int t = 0; t < 5; ++t) {
      short4_ pk;
#pragma unroll
      for (int r = 0; r < 4; ++r) {
        const float p = __expf(sc[t][r] - Mnew);   // 0 for masked slots
        ls += p;
        const float lg = (float)(l0 + 16*t + q4 + r - col16);
        float mv = (lg - 1023.0f + span1024) * 0.03125f + 1.0f;
        mv = fminf(fmaxf(mv, 0.0f), 1.0f);
        pk[r] = bf_bits(p * mv);
      }
      *reinterpret_cast<short4_*>(&P_s[pww + 16*t]) = pk;
    }
    ls += __shfl_xor(ls, 16);
    ls += __shfl_xor(ls, 32);
    Srun = Srun * alpha + ls;
    Mrun = Mnew;

    // ---- PV (swapped: A=V^T rows=d, B=P cols=q-row) ----
#pragma unroll
    for (int dt = 0; dt < 4; ++dt)
#pragma unroll
      for (int r = 0; r < 4; ++r) o[dt][r] *= alpha;
#pragma unroll
    for (int ks = 0; ks < 3; ++ks) {
      const bf16x8 ap = ld8any(&P_s[pwr + ks*32]);
#pragma unroll
      for (int dt = 0; dt < 4; ++dt)
        o[dt] = mfma16(vf[dt][ks], ap, o[dt]);
    }

    // ---- issue next chunk's V (vf regs now dead); pinned early ----
    {
      const int tkn = (m0 + ((ch < 15) ? l0 + 64 : l0)) >> 4;
#pragma unroll
      for (int dt = 0; dt < 4; ++dt) {
        const bf16* v0 = vbF + (size_t)dt * 24576 + (size_t)tkn * 256;
#pragma unroll
        for (int ks = 0; ks < 3; ++ks) vf[dt][ks] = ld8any(v0 + ks*512);
      }
      __builtin_amdgcn_sched_barrier(0);
    }
  }

  // ---- epilogue: lane-local normalize, fragment-linear ctx stores ----
  // row = b*SM+m0+col16 (row&15 = col16), col = h*64 + dt*16 + q4 + r:
  // FRAGIDX = rt*8192 + (h*2+(dt>>1))*512 + ((dt&1)*2+(quad>>1))*128
  //         + col16*8 + (quad&1)*4 + r
  const float inv = 1.0f / Srun;
  bf16* crb = ctx + (size_t)((b*SM + m0) >> 4) * 8192
            + (size_t)(h*1024 + (quad>>1)*128 + col16*8 + (quad&1)*4);
#pragma unroll
  for (int dt = 0; dt < 4; ++dt) {
    short4_ pk;
#pragma unroll
    for (int r = 0; r < 4; ++r) pk[r] = bf_bits(o[dt][r] * inv);
    *reinterpret_cast<short4_*>(crb + (size_t)(dt>>1)*512 + (dt&1)*256) = pk;
  }
}

// ---------------------------------------------------------------------------
// Fallback path kernels (round-6 proven, old row-major layouts).
// ---------------------------------------------------------------------------
template <int MODE, typename TX, typename TW, typename TY>
__global__ __launch_bounds__(256) void gemmbn64(const TX* __restrict__ X,
                                                const TW* __restrict__ W,
                                                TY* __restrict__ Y) {
  __shared__ __align__(16) bf16 tile[(MODE == 2) ? 64 * T2STR : 8];
  const int id   = blockIdx.x;
  const int s_   = id >> 3;
  const int xblk = (id & 7) + 8 * (s_ >> 3);
  const int yblk = s_ & 7;
  const int tid  = threadIdx.x;
  const int lane = tid & 63, w = tid >> 6;
  const int col16 = lane & 15, quad = lane >> 4, kq = quad << 3;
  const int wm = w >> 1, wn = w & 1;
  const int m0 = xblk * 128 + wm * 64;
  const int n0 = yblk * 64 + wn * 32;
  const TX* xr = X + (size_t)(m0 + col16) * SH + kq;
  const TW* wr = W + (size_t)(n0 + col16) * SH + kq;
  f32x4 acc[4][2];
#pragma unroll
  for (int i = 0; i < 4; ++i)
#pragma unroll
    for (int j = 0; j < 2; ++j) acc[i][j] = f32x4{0.f,0.f,0.f,0.f};
#pragma unroll
  for (int k0 = 0; k0 < SH; k0 += 32) {
    bf16x8 af[4], bfr[2];
#pragma unroll
    for (int t = 0; t < 4; ++t) af[t]  = ld8any(xr + (size_t)(t*16) * SH + k0);
#pragma unroll
    for (int t = 0; t < 2; ++t) bfr[t] = ld8any(wr + (size_t)(t*16) * SH + k0);
#pragma unroll
    for (int mt = 0; mt < 4; ++mt)
#pragma unroll
      for (int nt = 0; nt < 2; ++nt)
        acc[mt][nt] = mfma16(af[mt], bfr[nt], acc[mt][nt]);
  }

  if constexpr (MODE == 0) {
#pragma unroll
    for (int mt = 0; mt < 4; ++mt)
#pragma unroll
      for (int r = 0; r < 4; ++r) {
        const int row = m0 + mt*16 + quad*4 + r;
        TY* yr = Y + (size_t)row * SH + n0 + col16;
        st1(yr,      acc[mt][0][r]);
        st1(yr + 16, acc[mt][1][r]);
      }
  } else if constexpr (MODE == 1) {
#pragma unroll
    for (int mt = 0; mt < 4; ++mt)
#pragma unroll
      for (int r = 0; r < 4; ++r) {
        const int row = m0 + mt*16 + quad*4 + r;
        const int b = row / SN, sr = row - b * SN;
        bf16* yr = (bf16*)Y + (size_t)((b*NH + yblk)*SN + sr) * HD
                 + wn*32 + col16;
        yr[0]  = __float2bfloat16(acc[mt][0][r]);
        yr[16] = __float2bfloat16(acc[mt][1][r]);
      }
  } else {
#pragma unroll
    for (int mt = 0; mt < 4; ++mt)
#pragma unroll
      for (int r = 0; r < 4; ++r) {
        const int row_loc = wm*64 + mt*16 + quad*4 + r;
#pragma unroll
        for (int nt = 0; nt < 2; ++nt) {
          const int d = wn*32 + nt*16 + col16;
          tile[d * T2STR + row_loc] = __float2bfloat16(acc[mt][nt][r]);
        }
      }
    __syncthreads();
    const int d  = tid >> 2;
    const int hq = tid & 3;
    const bf16* src = tile + d * T2STR + hq * 32;
    const int row0 = xblk*128 + hq*32;
    const int b = row0 / SN, sr0 = row0 - b * SN;
    bf16* dst = (bf16*)Y + (size_t)((b*NH + yblk)*HD + d) * SN + sr0;
#pragma unroll
    for (int i = 0; i < 4; ++i)
      reinterpret_cast<uint4*>(dst)[i] = reinterpret_cast<const uint4*>(src)[i];
  }
}

#define MT 16
#define CSTR 84
#define PSTR 65
#define BSTR 104
#define QSTR 72

__global__ __launch_bounds__(128) void attn_kernel_fb(
    const float* __restrict__ query, const float* __restrict__ Wq,
    const bf16* __restrict__ Kh, const bf16* __restrict__ VT,
    const bf16* __restrict__ peT, const float* __restrict__ spanv,
    bf16* __restrict__ ctx) {
  __shared__ __align__(16) float cont_lds[MT][CSTR];
  __shared__ __align__(16) float pos_lds[MT][PSTR];
  __shared__ __align__(16) bf16  P_lds[MT][BSTR];
  __shared__ __align__(16) bf16  q_lds[MT*QSTR];
  __shared__ float alpha_lds[MT];
  __shared__ float S_lds[MT];

  const int id = blockIdx.x;
  const int h  = id & 7;
  const int s_ = id >> 3;
  const int m0 = (s_ & 31) * MT;
  const int b  = s_ >> 5;
  const int hb = b * 8 + h;
  const int tid  = threadIdx.x;
  const int lane = tid & 63;
  const int w    = tid >> 6;
  const int col16 = lane & 15, quad = lane >> 4, kq = quad << 3;
  const int wr = quad << 2;

  for (int i = tid; i < MT * BSTR; i += 128)
    (&P_lds[0][0])[i] = __float2bfloat16(0.0f);

  bf16x8 qf0, qf1;
  {
    f32x4 qa0 = {0.f,0.f,0.f,0.f}, qa1 = qa0;
    const float* xq = query + (size_t)(b*SM + m0 + col16) * SH + kq;
    const float* w0 = Wq + (size_t)(h*HD + w*32 + col16) * SH + kq;
    const float* w1 = w0 + (size_t)16 * SH;
#pragma unroll
    for (int k0 = 0; k0 < SH; k0 += 32) {
      bf16x8 xa = ld8any(xq + k0);
      qa0 = mfma16(xa, ld8any(w0 + k0), qa0);
      qa1 = mfma16(xa, ld8any(w1 + k0), qa1);
    }
#pragma unroll
    for (int r = 0; r < 4; ++r) {
      q_lds[(wr + r)*QSTR + w*32 + col16]      = __float2bfloat16(qa0[r]);
      q_lds[(wr + r)*QSTR + w*32 + 16 + col16] = __float2bfloat16(qa1[r]);
    }
    __syncthreads();
    qf0 = ld8any(&q_lds[col16*QSTR + kq]);
    qf1 = ld8any(&q_lds[col16*QSTR + kq + 32]);
  }

  const bf16* kb = Kh + (size_t)(hb * SN) * HD + kq;
  const bf16* vb = VT + (size_t)(hb * HD) * SN;

  const int srow = tid >> 3, sj = tid & 7;
  float Mrun = -1.0e30f, Srun = 0.0f;
  const float span = spanv[h];
  const int dt0 = w * 16, dt1 = (w + 2) * 16;
  f32x4 o0 = {0.f,0.f,0.f,0.f}, o1 = o0;

  for (int ch = 0; ch < 16; ++ch) {
    const int l0 = ch << 6;
    const int nb_ = m0 + l0;

    f32x4 ca0 = {0.f,0.f,0.f,0.f}, ca1 = ca0, ca2 = ca0, pa0 = ca0, pa1 = ca0;
    {
      const bf16* kr0 = kb + (size_t)(nb_ + w*16 + col16) * HD;
      ca0 = mfma16(qf0, ld8any(kr0),           ca0);
      ca0 = mfma16(qf1, ld8any(kr0 + 32),      ca0);
      const bf16* kr1 = kr0 + 32 * HD;
      ca1 = mfma16(qf0, ld8any(kr1),           ca1);
      ca1 = mfma16(qf1, ld8any(kr1 + 32),      ca1);
      if (w == 0) {
        const bf16* kr2 = kr0 + 64 * HD;
        ca2 = mfma16(qf0, ld8any(kr2),         ca2);
        ca2 = mfma16(qf1, ld8any(kr2 + 32),    ca2);
      }
      const bf16* pr0 = peT + (size_t)(l0 + w*16 + col16) * HD + kq;
      pa0 = mfma16(qf0, ld8any(pr0),           pa0);
      pa0 = mfma16(qf1, ld8any(pr0 + 32),      pa0);
      const bf16* pr1 = pr0 + 32 * HD;
      pa1 = mfma16(qf0, ld8any(pr1),           pa1);
      pa1 = mfma16(qf1, ld8any(pr1 + 32),      pa1);
    }
#pragma unroll
    for (int r = 0; r < 4; ++r) {
      cont_lds[wr + r][w*16 + col16]      = ca0[r];
      cont_lds[wr + r][w*16 + 32 + col16] = ca1[r];
      if (w == 0) cont_lds[wr + r][64 + col16] = ca2[r];
      pos_lds[wr + r][w*16 + col16]       = pa0[r];
      pos_lds[wr + r][w*16 + 32 + col16]  = pa1[r];
    }
    __syncthreads();

    float sc[8];
    float mc = -1.0e30f;
    const float* crow = &cont_lds[srow][srow + sj*8];
    const float* prow = &pos_lds[srow][sj*8];
#pragma unroll
    for (int i = 0; i < 8; ++i) {
      float v = (crow[i] + prow[i]) * 0.125f;
      sc[i] = v;
      mc = fmaxf(mc, v);
    }
    mc = fmaxf(mc, __shfl_xor(mc, 1));
    mc = fmaxf(mc, __shfl_xor(mc, 2));
    mc = fmaxf(mc, __shfl_xor(mc, 4));
    const float Mnew = fmaxf(Mrun, mc);
    const float alpha = __expf(Mrun - Mnew);
    float ls = 0.0f;
    bf16* pwrow = &P_lds[srow][srow + sj*8];
#pragma unroll
    for (int i = 0; i < 8; ++i) {
      float p = __expf(sc[i] - Mnew);
      ls += p;
      const float tpl = (float)(l0 + sj*8 + i) - 1023.0f;
      float mv = (tpl + span * 1024.0f) * 0.03125f + 1.0f;
      mv = fminf(fmaxf(mv, 0.0f), 1.0f);
      pwrow[i] = __float2bfloat16(p * mv);
    }
    ls += __shfl_xor(ls, 1);
    ls += __shfl_xor(ls, 2);
    ls += __shfl_xor(ls, 4);
    Srun = Srun * alpha + ls;
    Mrun = Mnew;
    if (sj == 0) { alpha_lds[srow] = alpha; S_lds[srow] = Srun; }
    __syncthreads();

    float al[4];
#pragma unroll
    for (int r = 0; r < 4; ++r) al[r] = alpha_lds[wr + r];
#pragma unroll
    for (int r = 0; r < 4; ++r) { o0[r] *= al[r]; o1[r] *= al[r]; }
#pragma unroll
    for (int ks = 0; ks < 3; ++ks) {
      const bf16x8 ap = ld8any(&P_lds[col16][ks*32 + kq]);
      const bf16* v0 = vb + (size_t)(dt0 + col16) * SN + nb_ + ks*32 + kq;
      const bf16* v1 = vb + (size_t)(dt1 + col16) * SN + nb_ + ks*32 + kq;
      o0 = mfma16(ap, ld8any(v0), o0);
      o1 = mfma16(ap, ld8any(v1), o1);
    }
  }

  bf16* cr = ctx + (size_t)(b*SM + m0 + wr) * SH + h*HD + col16;
#pragma unroll
  for (int r = 0; r < 4; ++r) {
    const float inv = 1.0f / S_lds[wr + r];
    cr[(size_t)r * SH + dt0] = __float2bfloat16(o0[r] * inv);
    cr[(size_t)r * SH + dt1] = __float2bfloat16(o1[r] * inv);
  }
}

// ---------------------------------------------------------------------------
extern "C" void kernel_launch(void* const* d_in, const int* in_sizes, int n_in,
                              void* d_out, int out_size, void* d_ws, size_t ws_size,
                              hipStream_t stream) {
  const float* query  = (const float*)d_in[0];
  const float* key    = (const float*)d_in[1];
  const float* value  = (const float*)d_in[2];
  const float* key_pe = (const float*)d_in[3];
  const float* Wq     = (const float*)d_in[4];
  const float* Wk     = (const float*)d_in[5];
  const float* Wv     = (const float*)d_in[6];
  const float* Wo     = (const float*)d_in[7];
  const float* spanv  = (const float*)d_in[8];
  float* out = (float*)d_out;

  bf16* ws = (bf16*)d_ws;
  if (ws_size >= (size_t)48365568) {
    // Path C: fully fragment-linear pipeline, 48.4 MB ws.
    bf16* stg    = ws;                    // 6291456 el: keyF -> valueF -> qF
    bf16* k_head = stg    + 6291456;      // kF
    bf16* vT     = k_head + 6291456;      // vF
    bf16* qp     = vT     + 6291456;      // qpF (fragment-linear)
    bf16* ctx    = qp     + 2097152;      // ctxF (fragment-linear)
    bf16* peT    = ctx    + 2097152;      // peF
    bf16* Wb     = peT    + 65536;        // fragment-linear weights
    bf16* Wq_b = Wb, *Wk_b = Wb + 262144, *Wv_b = Wb + 524288, *Wo_b = Wb + 786432;

    conv_w4f<<<dim3(128, 4), 256, 0, stream>>>(Wq, Wk, Wv, Wo, Wb);
    transpose_pe<1><<<256, 256, 0, stream>>>(key_pe, peT);

    conv_frag<float><<<3072, 256, 0, stream>>>(key, stg);
    gemmF<1, bf16><<<768, 256, 0, stream>>>(stg, Wk_b, k_head);
    conv_frag<float><<<3072, 256, 0, stream>>>(value, stg);
    gemmF<2, bf16><<<768, 256, 0, stream>>>(stg, Wv_b, vT);
    conv_frag<float><<<1024, 256, 0, stream>>>(query, stg);   // qF (reuses stg)
    gemmF<3, bf16><<<256, 256, 0, stream>>>(stg, Wq_b, qp);

    attn1w<<<2048, 64, 0, stream>>>(qp, k_head, vT, peT, spanv, ctx);
    gemmF<0, float><<<256, 256, 0, stream>>>(ctx, Wo_b, out);
  } else {
    // Path B (fallback): fused-q attention, f32 GEMM reads, 29.5 MB ws.
    bf16* k_head = ws;
    bf16* vT     = k_head + 6291456;
    bf16* ctx    = vT     + 6291456;
    bf16* peT    = ctx    + 2097152;
    gemmbn64<1, float, float, bf16><<<768, 256, 0, stream>>>(key,   Wk, k_head);
    gemmbn64<2, float, float, bf16><<<768, 256, 0, stream>>>(value, Wv, vT);
    transpose_pe<0><<<256, 256, 0, stream>>>(key_pe, peT);
    attn_kernel_fb<<<2048, 128, 0, stream>>>(query, Wq, k_head, vT,
                                             peT, spanv, ctx);
    gemmbn64<0, bf16, float, float><<<256, 256, 0, stream>>>(ctx, Wo, out);
  }
}

// Round 7
// 203.333 us; speedup vs baseline: 1.8291x; 1.0686x over previous
//
#include <hip/hip_runtime.h>
#include <hip/hip_bf16.h>
#include <type_traits>

typedef __hip_bfloat16 bf16;
typedef short bf16x8 __attribute__((ext_vector_type(8)));
typedef float f32x4 __attribute__((ext_vector_type(4)));
typedef short short4_ __attribute__((ext_vector_type(4)));

#define NB 8      // batch
#define SM 512    // block size M
#define SL 1024   // attn span L
#define SH 512    // hidden
#define NH 8      // heads
#define HD 64     // head dim
#define SN 1536   // M + L (key length)

static __device__ __forceinline__ short bf_bits(float x) {
  union { bf16 b; short s; } u; u.b = __float2bfloat16(x); return u.s;
}
static __device__ __forceinline__ bf16x8 ld8any(const bf16* p) {
  return *reinterpret_cast<const bf16x8*>(p);
}
static __device__ __forceinline__ bf16x8 ld8any(const float* p) {
  float4 a = *reinterpret_cast<const float4*>(p);
  float4 b = *reinterpret_cast<const float4*>(p + 4);
  bf16x8 r;
  r[0] = bf_bits(a.x); r[1] = bf_bits(a.y); r[2] = bf_bits(a.z); r[3] = bf_bits(a.w);
  r[4] = bf_bits(b.x); r[5] = bf_bits(b.y); r[6] = bf_bits(b.z); r[7] = bf_bits(b.w);
  return r;
}
static __device__ __forceinline__ void st1(bf16* p, float v) { *p = __float2bfloat16(v); }
static __device__ __forceinline__ void st1(float* p, float v) { *p = v; }
static __device__ __forceinline__ f32x4 mfma16(bf16x8 a, bf16x8 b, f32x4 c) {
  return __builtin_amdgcn_mfma_f32_16x16x32_bf16(a, b, c, 0, 0, 0);
}

// ---------------------------------------------------------------------------
// Universal fragment-linear layout for an [R x C] matrix (C multiple of 32):
//   FRAGIDX(row,col) = (row>>4)*(16*C) + (col>>5)*512
//                    + ((col>>3)&3)*128 + (row&15)*8 + (col&7)
// One wave MFMA fragment (16 rows x 32 cols) = 1KB contiguous, lane*16B.
// ---------------------------------------------------------------------------

// f32 row-major -> bf16 fragment-linear (C=512), 8 el/thread.
template <typename T>
__global__ __launch_bounds__(256) void conv_frag(const T* __restrict__ src,
                                                 bf16* __restrict__ dst) {
  const int i = blockIdx.x * 256 + threadIdx.x;
  const size_t flat = (size_t)i * 8;
  const int row = (int)(flat >> 9), k = (int)(flat & 511);
  const size_t a = (size_t)(row >> 4) * 8192 + (size_t)(k >> 5) * 512
                 + (size_t)(((k >> 3) & 3) * 128 + (row & 15) * 8);
  *reinterpret_cast<bf16x8*>(dst + a) = ld8any(src + flat);
}

// 4 weight matrices [512x512] -> fragment-linear.
__global__ __launch_bounds__(256) void conv_w4f(const float* __restrict__ w0,
                                                const float* __restrict__ w1,
                                                const float* __restrict__ w2,
                                                const float* __restrict__ w3,
                                                bf16* __restrict__ dst) {
  const float* srcs[4] = {w0, w1, w2, w3};
  const float* s = srcs[blockIdx.y];
  bf16* d = dst + (size_t)blockIdx.y * 262144;
  const int i = blockIdx.x * 256 + threadIdx.x;
  const size_t flat = (size_t)i * 8;
  const int row = (int)(flat >> 9), k = (int)(flat & 511);
  const size_t a = (size_t)(row >> 4) * 8192 + (size_t)(k >> 5) * 512
                 + (size_t)(((k >> 3) & 3) * 128 + (row & 15) * 8);
  *reinterpret_cast<bf16x8*>(d + a) = ld8any(s + flat);
}

// ---------------------------------------------------------------------------
// gemmF: Y[R x 512] = X @ W^T with X, W fragment-linear (coalesced 1KB
// fragment loads). BM=128, BN=64, 4 waves, wave tile 64x32, XCD swizzle.
// v8: explicit double-buffered K-loop, sched_barrier-pinned load issue
// (round-4 lesson: hipcc sinks loads to uses otherwise).
// MODE 0: row-major TY out. MODE 1: kF. MODE 2: vF (LDS transpose). MODE 3: qpF.
// ---------------------------------------------------------------------------
#define T2STR 136

#define GLOADF(AF, BF, KT)                                                   \
  {                                                                          \
    AF[0] = ld8any(xr +         (size_t)(KT) * 512);                         \
    AF[1] = ld8any(xr + 8192  + (size_t)(KT) * 512);                         \
    AF[2] = ld8any(xr + 16384 + (size_t)(KT) * 512);                         \
    AF[3] = ld8any(xr + 24576 + (size_t)(KT) * 512);                         \
    BF[0] = ld8any(wr +         (size_t)(KT) * 512);                         \
    BF[1] = ld8any(wr + 8192  + (size_t)(KT) * 512);                         \
  }

template <int MODE, typename TY>
__global__ __launch_bounds__(256) void gemmF(const bf16* __restrict__ XF,
                                             const bf16* __restrict__ WF,
                                             TY* __restrict__ Y) {
  __shared__ __align__(16) bf16 tile[(MODE == 2) ? 64 * T2STR : 8];
  const int id   = blockIdx.x;
  const int s_   = id >> 3;
  const int xblk = (id & 7) + 8 * (s_ >> 3);
  const int yblk = s_ & 7;
  const int tid  = threadIdx.x;
  const int lane = tid & 63, w = tid >> 6;
  const int col16 = lane & 15, quad = lane >> 4;
  const int lane8 = lane * 8;
  const int wm = w >> 1, wn = w & 1;
  const int m0 = xblk * 128 + wm * 64;
  const int n0 = yblk * 64 + wn * 32;
  const bf16* xr = XF + (size_t)(m0 >> 4) * 8192 + lane8;
  const bf16* wr = WF + (size_t)(n0 >> 4) * 8192 + lane8;
  f32x4 acc[4][2];
#pragma unroll
  for (int i = 0; i < 4; ++i)
#pragma unroll
    for (int j = 0; j < 2; ++j) acc[i][j] = f32x4{0.f,0.f,0.f,0.f};

  bf16x8 afA[4], bfA[2], afB[4], bfB[2];
  GLOADF(afA, bfA, 0);
  __builtin_amdgcn_sched_barrier(0);
#pragma unroll
  for (int kt = 0; kt < 16; kt += 2) {
    GLOADF(afB, bfB, kt + 1);
    __builtin_amdgcn_sched_barrier(0);
#pragma unroll
    for (int mt = 0; mt < 4; ++mt)
#pragma unroll
      for (int nt = 0; nt < 2; ++nt)
        acc[mt][nt] = mfma16(afA[mt], bfA[nt], acc[mt][nt]);
    const int ktn = (kt + 2 < 16) ? kt + 2 : kt;  // last: dead reload
    GLOADF(afA, bfA, ktn);
    __builtin_amdgcn_sched_barrier(0);
#pragma unroll
    for (int mt = 0; mt < 4; ++mt)
#pragma unroll
      for (int nt = 0; nt < 2; ++nt)
        acc[mt][nt] = mfma16(afB[mt], bfB[nt], acc[mt][nt]);
  }

  if constexpr (MODE == 0) {
#pragma unroll
    for (int mt = 0; mt < 4; ++mt)
#pragma unroll
      for (int r = 0; r < 4; ++r) {
        const int row = m0 + mt*16 + quad*4 + r;
        TY* yr = Y + (size_t)row * SH + n0 + col16;
        st1(yr,      acc[mt][0][r]);
        st1(yr + 16, acc[mt][1][r]);
      }
  } else if constexpr (MODE == 1) {
    const int dq = col16 >> 3, de = col16 & 7;
#pragma unroll
    for (int mt = 0; mt < 4; ++mt)
#pragma unroll
      for (int r = 0; r < 4; ++r) {
        const int row = m0 + mt*16 + quad*4 + r;
        const int b = row / SN, sr = row - b * SN;
        bf16* yr = (bf16*)Y
            + ((((size_t)(b*NH + yblk)*96 + (sr>>4))*2 + wn)*512)
            + (size_t)((sr&15)*8 + dq*128 + de);
        yr[0]   = __float2bfloat16(acc[mt][0][r]);
        yr[256] = __float2bfloat16(acc[mt][1][r]);
      }
  } else if constexpr (MODE == 3) {
    const int dq2 = col16 >> 3, de = col16 & 7;
#pragma unroll
    for (int mt = 0; mt < 4; ++mt)
#pragma unroll
      for (int r = 0; r < 4; ++r) {
        bf16* yr = (bf16*)Y + (size_t)((m0>>4) + mt) * 8192
                 + (size_t)(yblk*2 + wn) * 512
                 + (size_t)(dq2*128 + (quad*4 + r)*8 + de);
        yr[0]   = __float2bfloat16(acc[mt][0][r]);
        yr[256] = __float2bfloat16(acc[mt][1][r]);
      }
  } else {
    // vF via LDS transpose: tile[d][row_loc]
#pragma unroll
    for (int mt = 0; mt < 4; ++mt)
#pragma unroll
      for (int r = 0; r < 4; ++r) {
        const int row_loc = wm*64 + mt*16 + quad*4 + r;
#pragma unroll
        for (int nt = 0; nt < 2; ++nt) {
          const int d = wn*32 + nt*16 + col16;
          tile[d * T2STR + row_loc] = __float2bfloat16(acc[mt][nt][r]);
        }
      }
    __syncthreads();
    const int d  = tid >> 2;      // 0..63
    const int hq = tid & 3;       // 32-row quarter
    const bf16* src = tile + d * T2STR + hq * 32;
    const int row0 = xblk*128 + hq*32;
    const int b = row0 / SN, sr0 = row0 - b * SN;
    const int hb2 = b*NH + yblk;
    bf16* dstF = (bf16*)Y + (((size_t)hb2*4 + (d>>4))*96)*256 + (size_t)(d&15)*8;
#pragma unroll
    for (int i = 0; i < 4; ++i) {
      const int key = sr0 + i*8;
      const size_t off = (size_t)(key>>4)*256 + (size_t)((key>>3)&1)*128;
      *reinterpret_cast<uint4*>(dstF + off) = reinterpret_cast<const uint4*>(src)[i];
    }
  }
}

// ---------------------------------------------------------------------------
// transpose_pe: FRAG=0 -> peT[l][d]; FRAG=1 -> fragment-linear peF
// ---------------------------------------------------------------------------
template <int FRAG>
__global__ void transpose_pe(const float* __restrict__ pe, bf16* __restrict__ peT) {
  int idx = blockIdx.x * 256 + threadIdx.x;
  int l = idx >> 6, d = idx & 63;
  if constexpr (FRAG == 0) {
    peT[idx] = __float2bfloat16(pe[d * SL + l]);
  } else {
    peT[(size_t)((l>>4)*2 + (d>>5))*512
        + (size_t)((((d>>3)&3)*16 + (l&15))*8 + (d&7))]
      = __float2bfloat16(pe[d * SL + l]);
  }
}

// ---------------------------------------------------------------------------
// 2-wave split-chunk fused attention (v8).
// Block = 128 threads; wave w handles chunks [w*8, w*8+8) of the 16-chunk
// key range with the proven barrier-free wave-private body (swapped MFMAs,
// lane&15 == q-row everywhere, private LDS slices, fragment-linear coalesced
// loads, sched_barrier-pinned register prefetch). One __syncthreads() at the
// end merges the two online-softmax partials (lane-local math).
// Grid 2048 x 128 -> 16 waves/CU (2x round-6 TLP), serial chain halved.
// ---------------------------------------------------------------------------
#define PSTR1 69    // pos stride (f32): scalar writes, b128-aligned reads
#define BSTR1 104   // P stride (bf16): b64 writes, b128 reads aligned

__global__ __launch_bounds__(128, 2) void attn2w(
    const bf16* __restrict__ qp, const bf16* __restrict__ Kh,
    const bf16* __restrict__ VT, const bf16* __restrict__ peT,
    const float* __restrict__ spanv, bf16* __restrict__ ctx) {
  __shared__ __align__(16) float pos_all[2][16 * PSTR1];
  __shared__ __align__(16) bf16  P_all[2][16 * BSTR1];
  __shared__ __align__(16) float mrg[64 * 18];   // wave1 partial: 16 o + M + S

  const int id = blockIdx.x;
  const int h  = id & 7;
  const int s_ = id >> 3;
  const int m0 = (s_ & 31) * 16;
  const int b  = s_ >> 5;
  const int hb = b * 8 + h;
  const int tid = threadIdx.x;
  const int lane = tid & 63, w = tid >> 6;
  const int col16 = lane & 15, quad = lane >> 4, kq = quad << 3;
  const int q4 = quad << 2;
  const int lane8 = lane * 8;

  float* pos_s = &pos_all[w][0];
  bf16*  P_s   = &P_all[w][0];

  // zero own P band (cols 80..103 stay zero; read by ks=2 PV fragment)
  for (int i = lane; i < 16 * BSTR1; i += 64)
    P_s[i] = __float2bfloat16(0.0f);

  // q from fragment-linear qp: rt*8192 + h*1024 + lane*8 (and +512)
  const bf16* qb = qp + (size_t)((b*SM + m0) >> 4) * 8192 + h*1024 + lane8;
  const bf16x8 qf0 = ld8any(qb), qf1 = ld8any(qb + 512);

  const bf16* kbF = Kh + (size_t)hb * 98304 + lane8;   // 96 tiles * 1024
  const bf16* vbF = VT + (size_t)hb * 98304 + lane8;   // 4 dt * 96 kt * 256
  const bf16* pbF = peT + lane8;

  float Mrun = -1.0e30f, Srun = 0.0f;
  const float span1024 = spanv[h] * 1024.0f;
  f32x4 o[4];
#pragma unroll
  for (int dt = 0; dt < 4; ++dt) o[dt] = f32x4{0.f,0.f,0.f,0.f};

  // prefetched operand fragments (single-buffered; WAR ordering via reg deps)
  bf16x8 kf[5][2], pf[4][2], vf[4][3];

  const int ch0 = w << 3;          // this wave's first chunk
  const int l00 = ch0 << 6;

  // ---- prologue: first-chunk operands ----
  {
    const int tk0 = (m0 + l00) >> 4;
#pragma unroll
    for (int t = 0; t < 5; ++t) {
      const bf16* kr = kbF + (size_t)(tk0 + t) * 1024;
      kf[t][0] = ld8any(kr); kf[t][1] = ld8any(kr + 512);
    }
#pragma unroll
    for (int t = 0; t < 4; ++t) {
      const bf16* pr = pbF + (size_t)((l00 >> 4) + t) * 1024;
      pf[t][0] = ld8any(pr); pf[t][1] = ld8any(pr + 512);
    }
#pragma unroll
    for (int dt = 0; dt < 4; ++dt) {
      const bf16* v0 = vbF + (size_t)dt * 24576 + (size_t)tk0 * 256;
#pragma unroll
      for (int ks = 0; ks < 3; ++ks) vf[dt][ks] = ld8any(v0 + ks*512);
    }
    __builtin_amdgcn_sched_barrier(0);
  }

  const int posw = col16 * PSTR1 + q4;        // write base (scalar f32)
  const int posr = col16 * (PSTR1 - 1) + q4;  // read base (b128-aligned)
  const int pww  = col16 * BSTR1 + q4;        // P write base (b64-aligned)
  const int pwr  = col16 * BSTR1 + kq;        // P read base (b128-aligned)

  for (int ch = 0; ch < 8; ++ch) {
    const int l0 = (ch0 + ch) << 6;

    // ---- pos MFMAs (swapped: A=pe rows, D rows = l, cols = q-row) ----
    f32x4 pacc[4];
#pragma unroll
    for (int t = 0; t < 4; ++t) {
      f32x4 a = {0.f,0.f,0.f,0.f};
      a = mfma16(pf[t][0], qf0, a);
      a = mfma16(pf[t][1], qf1, a);
      pacc[t] = a;
    }
#pragma unroll
    for (int t = 0; t < 4; ++t)
#pragma unroll
      for (int r = 0; r < 4; ++r)
        pos_s[posw + 16*t + r] = pacc[t][r];

    // ---- cont MFMAs (swapped: A=K rows, D rows = band pos, cols = q-row) ----
    f32x4 cacc[5];
#pragma unroll
    for (int t = 0; t < 5; ++t) {
      f32x4 a = {0.f,0.f,0.f,0.f};
      a = mfma16(kf[t][0], qf0, a);
      a = mfma16(kf[t][1], qf1, a);
      cacc[t] = a;
    }

    // ---- issue next chunk's K/pe (kf/pf regs now dead); pinned ----
    {
      const int l0n = (ch < 7) ? l0 + 64 : l0;
      const int tkn = (m0 + l0n) >> 4;
      const int tpn = l0n >> 4;
#pragma unroll
      for (int t = 0; t < 5; ++t) {
        const bf16* kr = kbF + (size_t)(tkn + t) * 1024;
        kf[t][0] = ld8any(kr); kf[t][1] = ld8any(kr + 512);
      }
#pragma unroll
      for (int t = 0; t < 4; ++t) {
        const bf16* pr = pbF + (size_t)(tpn + t) * 1024;
        pf[t][0] = ld8any(pr); pf[t][1] = ld8any(pr + 512);
      }
      __builtin_amdgcn_sched_barrier(0);
    }

    // ---- per-lane softmax over this row's 64-key window ----
    float sc[5][4];
    float mc = -1.0e30f;
#pragma unroll
    for (int t = 0; t < 5; ++t) {
      const f32x4 pv4 = *reinterpret_cast<const f32x4*>(&pos_s[posr + 16*t]);
#pragma unroll
      for (int r = 0; r < 4; ++r) {
        const int l = 16*t + q4 + r - col16;
        float v = (cacc[t][r] + pv4[r]) * 0.125f;
        v = ((unsigned)l < 64u) ? v : -1.0e30f;
        sc[t][r] = v;
        mc = fmaxf(mc, v);
      }
    }
    mc = fmaxf(mc, __shfl_xor(mc, 16));
    mc = fmaxf(mc, __shfl_xor(mc, 32));
    const float Mnew = fmaxf(Mrun, mc);
    const float alpha = __expf(Mrun - Mnew);
    float ls = 0.0f;
#pragma unroll
    for (int t = 0; t < 5; ++t) {
      short4_ pk;
#pragma unroll
      for (int r = 0; r < 4; ++r) {
        const float p = __expf(sc[t][r] - Mnew);   // 0 for masked slots
        ls += p;
        const float lg = (float)(l0 + 16*t + q4 + r - col16);
        float mv = (lg - 1023.0f + span1024) * 0.03125f + 1.0f;
        mv = fminf(fmaxf(mv, 0.0f), 1.0f);
        pk[r] = bf_bits(p * mv);
      }
      *reinterpret_cast<short4_*>(&P_s[pww + 16*t]) = pk;
    }
    ls += __shfl_xor(ls, 16);
    ls += __shfl_xor(ls, 32);
    Srun = Srun * alpha + ls;
    Mrun = Mnew;

    // ---- PV (swapped: A=V^T rows=d, B=P cols=q-row) ----
#pragma unroll
    for (int dt = 0; dt < 4; ++dt)
#pragma unroll
      for (int r = 0; r < 4; ++r) o[dt][r] *= alpha;
#pragma unroll
    for (int ks = 0; ks < 3; ++ks) {
      const bf16x8 ap = ld8any(&P_s[pwr + ks*32]);
#pragma unroll
      for (int dt = 0; dt < 4; ++dt)
        o[dt] = mfma16(vf[dt][ks], ap, o[dt]);
    }

    // ---- issue next chunk's V (vf regs now dead); pinned ----
    {
      const int tkn = (m0 + ((ch < 7) ? l0 + 64 : l0)) >> 4;
#pragma unroll
      for (int dt = 0; dt < 4; ++dt) {
        const bf16* v0 = vbF + (size_t)dt * 24576 + (size_t)tkn * 256;
#pragma unroll
        for (int ks = 0; ks < 3; ++ks) vf[dt][ks] = ld8any(v0 + ks*512);
      }
      __builtin_amdgcn_sched_barrier(0);
    }
  }

  // ---- merge the two online-softmax partials ----
  if (w == 1) {
#pragma unroll
    for (int dt = 0; dt < 4; ++dt)
#pragma unroll
      for (int r = 0; r < 4; ++r) mrg[lane*18 + dt*4 + r] = o[dt][r];
    mrg[lane*18 + 16] = Mrun;
    mrg[lane*18 + 17] = Srun;
  }
  __syncthreads();
  if (w == 0) {
    const float M1 = mrg[lane*18 + 16], S1 = mrg[lane*18 + 17];
    const float Mf = fmaxf(Mrun, M1);
    const float e0 = __expf(Mrun - Mf), e1 = __expf(M1 - Mf);
    const float inv = 1.0f / (Srun * e0 + S1 * e1);
    // fragment-linear ctx stores (row&15 = col16, col = h*64 + dt*16 + q4 + r)
    bf16* crb = ctx + (size_t)((b*SM + m0) >> 4) * 8192
              + (size_t)(h*1024 + (quad>>1)*128 + col16*8 + (quad&1)*4);
#pragma unroll
    for (int dt = 0; dt < 4; ++dt) {
      short4_ pk;
#pragma unroll
      for (int r = 0; r < 4; ++r)
        pk[r] = bf_bits((o[dt][r]*e0 + mrg[lane*18 + dt*4 + r]*e1) * inv);
      *reinterpret_cast<short4_*>(crb + (size_t)(dt>>1)*512 + (dt&1)*256) = pk;
    }
  }
}

// ---------------------------------------------------------------------------
// Fallback path kernels (round-6 proven, old row-major layouts).
// ---------------------------------------------------------------------------
template <int MODE, typename TX, typename TW, typename TY>
__global__ __launch_bounds__(256) void gemmbn64(const TX* __restrict__ X,
                                                const TW* __restrict__ W,
                                                TY* __restrict__ Y) {
  __shared__ __align__(16) bf16 tile[(MODE == 2) ? 64 * T2STR : 8];
  const int id   = blockIdx.x;
  const int s_   = id >> 3;
  const int xblk = (id & 7) + 8 * (s_ >> 3);
  const int yblk = s_ & 7;
  const int tid  = threadIdx.x;
  const int lane = tid & 63, w = tid >> 6;
  const int col16 = lane & 15, quad = lane >> 4, kq = quad << 3;
  const int wm = w >> 1, wn = w & 1;
  const int m0 = xblk * 128 + wm * 64;
  const int n0 = yblk * 64 + wn * 32;
  const TX* xr = X + (size_t)(m0 + col16) * SH + kq;
  const TW* wr = W + (size_t)(n0 + col16) * SH + kq;
  f32x4 acc[4][2];
#pragma unroll
  for (int i = 0; i < 4; ++i)
#pragma unroll
    for (int j = 0; j < 2; ++j) acc[i][j] = f32x4{0.f,0.f,0.f,0.f};
#pragma unroll
  for (int k0 = 0; k0 < SH; k0 += 32) {
    bf16x8 af[4], bfr[2];
#pragma unroll
    for (int t = 0; t < 4; ++t) af[t]  = ld8any(xr + (size_t)(t*16) * SH + k0);
#pragma unroll
    for (int t = 0; t < 2; ++t) bfr[t] = ld8any(wr + (size_t)(t*16) * SH + k0);
#pragma unroll
    for (int mt = 0; mt < 4; ++mt)
#pragma unroll
      for (int nt = 0; nt < 2; ++nt)
        acc[mt][nt] = mfma16(af[mt], bfr[nt], acc[mt][nt]);
  }

  if constexpr (MODE == 0) {
#pragma unroll
    for (int mt = 0; mt < 4; ++mt)
#pragma unroll
      for (int r = 0; r < 4; ++r) {
        const int row = m0 + mt*16 + quad*4 + r;
        TY* yr = Y + (size_t)row * SH + n0 + col16;
        st1(yr,      acc[mt][0][r]);
        st1(yr + 16, acc[mt][1][r]);
      }
  } else if constexpr (MODE == 1) {
#pragma unroll
    for (int mt = 0; mt < 4; ++mt)
#pragma unroll
      for (int r = 0; r < 4; ++r) {
        const int row = m0 + mt*16 + quad*4 + r;
        const int b = row / SN, sr = row - b * SN;
        bf16* yr = (bf16*)Y + (size_t)((b*NH + yblk)*SN + sr) * HD
                 + wn*32 + col16;
        yr[0]  = __float2bfloat16(acc[mt][0][r]);
        yr[16] = __float2bfloat16(acc[mt][1][r]);
      }
  } else {
#pragma unroll
    for (int mt = 0; mt < 4; ++mt)
#pragma unroll
      for (int r = 0; r < 4; ++r) {
        const int row_loc = wm*64 + mt*16 + quad*4 + r;
#pragma unroll
        for (int nt = 0; nt < 2; ++nt) {
          const int d = wn*32 + nt*16 + col16;
          tile[d * T2STR + row_loc] = __float2bfloat16(acc[mt][nt][r]);
        }
      }
    __syncthreads();
    const int d  = tid >> 2;
    const int hq = tid & 3;
    const bf16* src = tile + d * T2STR + hq * 32;
    const int row0 = xblk*128 + hq*32;
    const int b = row0 / SN, sr0 = row0 - b * SN;
    bf16* dst = (bf16*)Y + (size_t)((b*NH + yblk)*HD + d) * SN + sr0;
#pragma unroll
    for (int i = 0; i < 4; ++i)
      reinterpret_cast<uint4*>(dst)[i] = reinterpret_cast<const uint4*>(src)[i];
  }
}

#define MT 16
#define CSTR 84
#define PSTR 65
#define BSTR 104
#define QSTR 72

__global__ __launch_bounds__(128) void attn_kernel_fb(
    const float* __restrict__ query, const float* __restrict__ Wq,
    const bf16* __restrict__ Kh, const bf16* __restrict__ VT,
    const bf16* __restrict__ peT, const float* __restrict__ spanv,
    bf16* __restrict__ ctx) {
  __shared__ __align__(16) float cont_lds[MT][CSTR];
  __shared__ __align__(16) float pos_lds[MT][PSTR];
  __shared__ __align__(16) bf16  P_lds[MT][BSTR];
  __shared__ __align__(16) bf16  q_lds[MT*QSTR];
  __shared__ float alpha_lds[MT];
  __shared__ float S_lds[MT];

  const int id = blockIdx.x;
  const int h  = id & 7;
  const int s_ = id >> 3;
  const int m0 = (s_ & 31) * MT;
  const int b  = s_ >> 5;
  const int hb = b * 8 + h;
  const int tid  = threadIdx.x;
  const int lane = tid & 63;
  const int w    = tid >> 6;
  const int col16 = lane & 15, quad = lane >> 4, kq = quad << 3;
  const int wr = quad << 2;

  for (int i = tid; i < MT * BSTR; i += 128)
    (&P_lds[0][0])[i] = __float2bfloat16(0.0f);

  bf16x8 qf0, qf1;
  {
    f32x4 qa0 = {0.f,0.f,0.f,0.f}, qa1 = qa0;
    const float* xq = query + (size_t)(b*SM + m0 + col16) * SH + kq;
    const float* w0 = Wq + (size_t)(h*HD + w*32 + col16) * SH + kq;
    const float* w1 = w0 + (size_t)16 * SH;
#pragma unroll
    for (int k0 = 0; k0 < SH; k0 += 32) {
      bf16x8 xa = ld8any(xq + k0);
      qa0 = mfma16(xa, ld8any(w0 + k0), qa0);
      qa1 = mfma16(xa, ld8any(w1 + k0), qa1);
    }
#pragma unroll
    for (int r = 0; r < 4; ++r) {
      q_lds[(wr + r)*QSTR + w*32 + col16]      = __float2bfloat16(qa0[r]);
      q_lds[(wr + r)*QSTR + w*32 + 16 + col16] = __float2bfloat16(qa1[r]);
    }
    __syncthreads();
    qf0 = ld8any(&q_lds[col16*QSTR + kq]);
    qf1 = ld8any(&q_lds[col16*QSTR + kq + 32]);
  }

  const bf16* kb = Kh + (size_t)(hb * SN) * HD + kq;
  const bf16* vb = VT + (size_t)(hb * HD) * SN;

  const int srow = tid >> 3, sj = tid & 7;
  float Mrun = -1.0e30f, Srun = 0.0f;
  const float span = spanv[h];
  const int dt0 = w * 16, dt1 = (w + 2) * 16;
  f32x4 o0 = {0.f,0.f,0.f,0.f}, o1 = o0;

  for (int ch = 0; ch < 16; ++ch) {
    const int l0 = ch << 6;
    const int nb_ = m0 + l0;

    f32x4 ca0 = {0.f,0.f,0.f,0.f}, ca1 = ca0, ca2 = ca0, pa0 = ca0, pa1 = ca0;
    {
      const bf16* kr0 = kb + (size_t)(nb_ + w*16 + col16) * HD;
      ca0 = mfma16(qf0, ld8any(kr0),           ca0);
      ca0 = mfma16(qf1, ld8any(kr0 + 32),      ca0);
      const bf16* kr1 = kr0 + 32 * HD;
      ca1 = mfma16(qf0, ld8any(kr1),           ca1);
      ca1 = mfma16(qf1, ld8any(kr1 + 32),      ca1);
      if (w == 0) {
        const bf16* kr2 = kr0 + 64 * HD;
        ca2 = mfma16(qf0, ld8any(kr2),         ca2);
        ca2 = mfma16(qf1, ld8any(kr2 + 32),    ca2);
      }
      const bf16* pr0 = peT + (size_t)(l0 + w*16 + col16) * HD + kq;
      pa0 = mfma16(qf0, ld8any(pr0),           pa0);
      pa0 = mfma16(qf1, ld8any(pr0 + 32),      pa0);
      const bf16* pr1 = pr0 + 32 * HD;
      pa1 = mfma16(qf0, ld8any(pr1),           pa1);
      pa1 = mfma16(qf1, ld8any(pr1 + 32),      pa1);
    }
#pragma unroll
    for (int r = 0; r < 4; ++r) {
      cont_lds[wr + r][w*16 + col16]      = ca0[r];
      cont_lds[wr + r][w*16 + 32 + col16] = ca1[r];
      if (w == 0) cont_lds[wr + r][64 + col16] = ca2[r];
      pos_lds[wr + r][w*16 + col16]       = pa0[r];
      pos_lds[wr + r][w*16 + 32 + col16]  = pa1[r];
    }
    __syncthreads();

    float sc[8];
    float mc = -1.0e30f;
    const float* crow = &cont_lds[srow][srow + sj*8];
    const float* prow = &pos_lds[srow][sj*8];
#pragma unroll
    for (int i = 0; i < 8; ++i) {
      float v = (crow[i] + prow[i]) * 0.125f;
      sc[i] = v;
      mc = fmaxf(mc, v);
    }
    mc = fmaxf(mc, __shfl_xor(mc, 1));
    mc = fmaxf(mc, __shfl_xor(mc, 2));
    mc = fmaxf(mc, __shfl_xor(mc, 4));
    const float Mnew = fmaxf(Mrun, mc);
    const float alpha = __expf(Mrun - Mnew);
    float ls = 0.0f;
    bf16* pwrow = &P_lds[srow][srow + sj*8];
#pragma unroll
    for (int i = 0; i < 8; ++i) {
      float p = __expf(sc[i] - Mnew);
      ls += p;
      const float tpl = (float)(l0 + sj*8 + i) - 1023.0f;
      float mv = (tpl + span * 1024.0f) * 0.03125f + 1.0f;
      mv = fminf(fmaxf(mv, 0.0f), 1.0f);
      pwrow[i] = __float2bfloat16(p * mv);
    }
    ls += __shfl_xor(ls, 1);
    ls += __shfl_xor(ls, 2);
    ls += __shfl_xor(ls, 4);
    Srun = Srun * alpha + ls;
    Mrun = Mnew;
    if (sj == 0) { alpha_lds[srow] = alpha; S_lds[srow] = Srun; }
    __syncthreads();

    float al[4];
#pragma unroll
    for (int r = 0; r < 4; ++r) al[r] = alpha_lds[wr + r];
#pragma unroll
    for (int r = 0; r < 4; ++r) { o0[r] *= al[r]; o1[r] *= al[r]; }
#pragma unroll
    for (int ks = 0; ks < 3; ++ks) {
      const bf16x8 ap = ld8any(&P_lds[col16][ks*32 + kq]);
      const bf16* v0 = vb + (size_t)(dt0 + col16) * SN + nb_ + ks*32 + kq;
      const bf16* v1 = vb + (size_t)(dt1 + col16) * SN + nb_ + ks*32 + kq;
      o0 = mfma16(ap, ld8any(v0), o0);
      o1 = mfma16(ap, ld8any(v1), o1);
    }
  }

  bf16* cr = ctx + (size_t)(b*SM + m0 + wr) * SH + h*HD + col16;
#pragma unroll
  for (int r = 0; r < 4; ++r) {
    const float inv = 1.0f / S_lds[wr + r];
    cr[(size_t)r * SH + dt0] = __float2bfloat16(o0[r] * inv);
    cr[(size_t)r * SH + dt1] = __float2bfloat16(o1[r] * inv);
  }
}

// ---------------------------------------------------------------------------
extern "C" void kernel_launch(void* const* d_in, const int* in_sizes, int n_in,
                              void* d_out, int out_size, void* d_ws, size_t ws_size,
                              hipStream_t stream) {
  const float* query  = (const float*)d_in[0];
  const float* key    = (const float*)d_in[1];
  const float* value  = (const float*)d_in[2];
  const float* key_pe = (const float*)d_in[3];
  const float* Wq     = (const float*)d_in[4];
  const float* Wk     = (const float*)d_in[5];
  const float* Wv     = (const float*)d_in[6];
  const float* Wo     = (const float*)d_in[7];
  const float* spanv  = (const float*)d_in[8];
  float* out = (float*)d_out;

  bf16* ws = (bf16*)d_ws;
  if (ws_size >= (size_t)48365568) {
    // Path C: fully fragment-linear pipeline, 48.4 MB ws.
    bf16* stg    = ws;                    // 6291456 el: keyF -> valueF -> qF
    bf16* k_head = stg    + 6291456;      // kF
    bf16* vT     = k_head + 6291456;      // vF
    bf16* qp     = vT     + 6291456;      // qpF (fragment-linear)
    bf16* ctx    = qp     + 2097152;      // ctxF (fragment-linear)
    bf16* peT    = ctx    + 2097152;      // peF
    bf16* Wb     = peT    + 65536;        // fragment-linear weights
    bf16* Wq_b = Wb, *Wk_b = Wb + 262144, *Wv_b = Wb + 524288, *Wo_b = Wb + 786432;

    conv_w4f<<<dim3(128, 4), 256, 0, stream>>>(Wq, Wk, Wv, Wo, Wb);
    transpose_pe<1><<<256, 256, 0, stream>>>(key_pe, peT);

    conv_frag<float><<<3072, 256, 0, stream>>>(key, stg);
    gemmF<1, bf16><<<768, 256, 0, stream>>>(stg, Wk_b, k_head);
    conv_frag<float><<<3072, 256, 0, stream>>>(value, stg);
    gemmF<2, bf16><<<768, 256, 0, stream>>>(stg, Wv_b, vT);
    conv_frag<float><<<1024, 256, 0, stream>>>(query, stg);   // qF (reuses stg)
    gemmF<3, bf16><<<256, 256, 0, stream>>>(stg, Wq_b, qp);

    attn2w<<<2048, 128, 0, stream>>>(qp, k_head, vT, peT, spanv, ctx);
    gemmF<0, float><<<256, 256, 0, stream>>>(ctx, Wo_b, out);
  } else {
    // Path B (fallback): fused-q attention, f32 GEMM reads, 29.5 MB ws.
    bf16* k_head = ws;
    bf16* vT     = k_head + 6291456;
    bf16* ctx    = vT     + 6291456;
    bf16* peT    = ctx    + 2097152;
    gemmbn64<1, float, float, bf16><<<768, 256, 0, stream>>>(key,   Wk, k_head);
    gemmbn64<2, float, float, bf16><<<768, 256, 0, stream>>>(value, Wv, vT);
    transpose_pe<0><<<256, 256, 0, stream>>>(key_pe, peT);
    attn_kernel_fb<<<2048, 128, 0, stream>>>(query, Wq, k_head, vT,
                                             peT, spanv, ctx);
    gemmbn64<0, bf16, float, float><<<256, 256, 0, stream>>>(ctx, Wo, out);
  }
}

// Round 8
// 190.396 us; speedup vs baseline: 1.9534x; 1.0679x over previous
//
#include <hip/hip_runtime.h>
#include <hip/hip_bf16.h>
#include <type_traits>

typedef __hip_bfloat16 bf16;
typedef short bf16x8 __attribute__((ext_vector_type(8)));
typedef float f32x4 __attribute__((ext_vector_type(4)));
typedef short short4_ __attribute__((ext_vector_type(4)));

#define NB 8      // batch
#define SM 512    // block size M
#define SL 1024   // attn span L
#define SH 512    // hidden
#define NH 8      // heads
#define HD 64     // head dim
#define SN 1536   // M + L (key length)

static __device__ __forceinline__ short bf_bits(float x) {
  union { bf16 b; short s; } u; u.b = __float2bfloat16(x); return u.s;
}
static __device__ __forceinline__ bf16x8 ld8any(const bf16* p) {
  return *reinterpret_cast<const bf16x8*>(p);
}
static __device__ __forceinline__ bf16x8 ld8any(const float* p) {
  float4 a = *reinterpret_cast<const float4*>(p);
  float4 b = *reinterpret_cast<const float4*>(p + 4);
  bf16x8 r;
  r[0] = bf_bits(a.x); r[1] = bf_bits(a.y); r[2] = bf_bits(a.z); r[3] = bf_bits(a.w);
  r[4] = bf_bits(b.x); r[5] = bf_bits(b.y); r[6] = bf_bits(b.z); r[7] = bf_bits(b.w);
  return r;
}
static __device__ __forceinline__ void st1(bf16* p, float v) { *p = __float2bfloat16(v); }
static __device__ __forceinline__ void st1(float* p, float v) { *p = v; }
static __device__ __forceinline__ f32x4 mfma16(bf16x8 a, bf16x8 b, f32x4 c) {
  return __builtin_amdgcn_mfma_f32_16x16x32_bf16(a, b, c, 0, 0, 0);
}

// ---------------------------------------------------------------------------
// Universal fragment-linear layout for an [R x C] matrix (C = 512):
//   FRAGIDX(row,col) = (row>>4)*8192 + (col>>5)*512
//                    + ((col>>3)&3)*128 + (row&15)*8 + (col&7)
// One wave MFMA fragment (16 rows x 32 cols) = 1KB contiguous, lane*16B.
// ---------------------------------------------------------------------------
static __device__ __forceinline__ void frag_store8(const float* __restrict__ src,
                                                   bf16* __restrict__ dst, int i) {
  const size_t flat = (size_t)i * 8;
  const int row = (int)(flat >> 9), k = (int)(flat & 511);
  const size_t a = (size_t)(row >> 4) * 8192 + (size_t)(k >> 5) * 512
                 + (size_t)(((k >> 3) & 3) * 128 + (row & 15) * 8);
  *reinterpret_cast<bf16x8*>(dst + a) = ld8any(src + flat);
}

// ---------------------------------------------------------------------------
// prep_all: ALL input-side conversions in ONE launch (5 old kernels merged).
//  [0,3072)    key   -> kS  (fragment-linear, 12288x512)
//  [3072,6144) value -> vS
//  [6144,7168) query -> qS  (4096x512; staged in the ctx region)
//  [7168,7680) Wq/Wk/Wv/Wo -> Wb (fragment-linear, 4 x 512x512)
//  [7680,7936) key_pe -> peF (fragment-linear pe^T)
// ---------------------------------------------------------------------------
__global__ __launch_bounds__(256) void prep_all(
    const float* __restrict__ key, const float* __restrict__ value,
    const float* __restrict__ query,
    const float* __restrict__ Wq, const float* __restrict__ Wk,
    const float* __restrict__ Wv, const float* __restrict__ Wo,
    const float* __restrict__ pe,
    bf16* __restrict__ kS, bf16* __restrict__ vS, bf16* __restrict__ qS,
    bf16* __restrict__ Wb, bf16* __restrict__ peF) {
  const int id = blockIdx.x, tid = threadIdx.x;
  if (id < 3072) {
    frag_store8(key, kS, id * 256 + tid);
  } else if (id < 6144) {
    frag_store8(value, vS, (id - 3072) * 256 + tid);
  } else if (id < 7168) {
    frag_store8(query, qS, (id - 6144) * 256 + tid);
  } else if (id < 7680) {
    const int s = id - 7168;
    const float* srcs[4] = {Wq, Wk, Wv, Wo};
    frag_store8(srcs[s >> 7], Wb + (size_t)(s >> 7) * 262144,
                (s & 127) * 256 + tid);
  } else {
    const int idx = (id - 7680) * 256 + tid;
    const int l = idx >> 6, d = idx & 63;
    peF[(size_t)((l>>4)*2 + (d>>5))*512
        + (size_t)((((d>>3)&3)*16 + (l&15))*8 + (d&7))]
      = __float2bfloat16(pe[d * SL + l]);
  }
}

// ---------------------------------------------------------------------------
// gemm_dev: Y[R x 512] = X @ W^T, X/W fragment-linear (coalesced 1KB
// fragment loads). BM=128, BN=64, 4 waves, wave tile 64x32, XCD swizzle.
// Double-buffered K-loop, sched_barrier-pinned load issue.
// MODE 0: row-major TY. MODE 1: kF. MODE 2: vF (LDS transpose). MODE 3: qpF.
// ---------------------------------------------------------------------------
#define T2STR 136

#define GLOADF(AF, BF, KT)                                                   \
  {                                                                          \
    AF[0] = ld8any(xr +         (size_t)(KT) * 512);                         \
    AF[1] = ld8any(xr + 8192  + (size_t)(KT) * 512);                         \
    AF[2] = ld8any(xr + 16384 + (size_t)(KT) * 512);                         \
    AF[3] = ld8any(xr + 24576 + (size_t)(KT) * 512);                         \
    BF[0] = ld8any(wr +         (size_t)(KT) * 512);                         \
    BF[1] = ld8any(wr + 8192  + (size_t)(KT) * 512);                         \
  }

template <int MODE, typename TY>
static __device__ __forceinline__ void gemm_dev(const bf16* __restrict__ XF,
                                                const bf16* __restrict__ WF,
                                                TY* __restrict__ Y,
                                                int id, bf16* tile) {
  const int s_   = id >> 3;
  const int xblk = (id & 7) + 8 * (s_ >> 3);
  const int yblk = s_ & 7;
  const int tid  = threadIdx.x;
  const int lane = tid & 63, w = tid >> 6;
  const int col16 = lane & 15, quad = lane >> 4;
  const int lane8 = lane * 8;
  const int wm = w >> 1, wn = w & 1;
  const int m0 = xblk * 128 + wm * 64;
  const int n0 = yblk * 64 + wn * 32;
  const bf16* xr = XF + (size_t)(m0 >> 4) * 8192 + lane8;
  const bf16* wr = WF + (size_t)(n0 >> 4) * 8192 + lane8;
  f32x4 acc[4][2];
#pragma unroll
  for (int i = 0; i < 4; ++i)
#pragma unroll
    for (int j = 0; j < 2; ++j) acc[i][j] = f32x4{0.f,0.f,0.f,0.f};

  bf16x8 afA[4], bfA[2], afB[4], bfB[2];
  GLOADF(afA, bfA, 0);
  __builtin_amdgcn_sched_barrier(0);
#pragma unroll
  for (int kt = 0; kt < 16; kt += 2) {
    GLOADF(afB, bfB, kt + 1);
    __builtin_amdgcn_sched_barrier(0);
#pragma unroll
    for (int mt = 0; mt < 4; ++mt)
#pragma unroll
      for (int nt = 0; nt < 2; ++nt)
        acc[mt][nt] = mfma16(afA[mt], bfA[nt], acc[mt][nt]);
    const int ktn = (kt + 2 < 16) ? kt + 2 : kt;  // last: dead reload
    GLOADF(afA, bfA, ktn);
    __builtin_amdgcn_sched_barrier(0);
#pragma unroll
    for (int mt = 0; mt < 4; ++mt)
#pragma unroll
      for (int nt = 0; nt < 2; ++nt)
        acc[mt][nt] = mfma16(afB[mt], bfB[nt], acc[mt][nt]);
  }

  if constexpr (MODE == 0) {
#pragma unroll
    for (int mt = 0; mt < 4; ++mt)
#pragma unroll
      for (int r = 0; r < 4; ++r) {
        const int row = m0 + mt*16 + quad*4 + r;
        TY* yr = Y + (size_t)row * SH + n0 + col16;
        st1(yr,      acc[mt][0][r]);
        st1(yr + 16, acc[mt][1][r]);
      }
  } else if constexpr (MODE == 1) {
    const int dq = col16 >> 3, de = col16 & 7;
#pragma unroll
    for (int mt = 0; mt < 4; ++mt)
#pragma unroll
      for (int r = 0; r < 4; ++r) {
        const int row = m0 + mt*16 + quad*4 + r;
        const int b = row / SN, sr = row - b * SN;
        bf16* yr = (bf16*)Y
            + ((((size_t)(b*NH + yblk)*96 + (sr>>4))*2 + wn)*512)
            + (size_t)((sr&15)*8 + dq*128 + de);
        yr[0]   = __float2bfloat16(acc[mt][0][r]);
        yr[256] = __float2bfloat16(acc[mt][1][r]);
      }
  } else if constexpr (MODE == 3) {
    const int dq2 = col16 >> 3, de = col16 & 7;
#pragma unroll
    for (int mt = 0; mt < 4; ++mt)
#pragma unroll
      for (int r = 0; r < 4; ++r) {
        bf16* yr = (bf16*)Y + (size_t)((m0>>4) + mt) * 8192
                 + (size_t)(yblk*2 + wn) * 512
                 + (size_t)(dq2*128 + (quad*4 + r)*8 + de);
        yr[0]   = __float2bfloat16(acc[mt][0][r]);
        yr[256] = __float2bfloat16(acc[mt][1][r]);
      }
  } else {
    // vF via LDS transpose: tile[d][row_loc]
#pragma unroll
    for (int mt = 0; mt < 4; ++mt)
#pragma unroll
      for (int r = 0; r < 4; ++r) {
        const int row_loc = wm*64 + mt*16 + quad*4 + r;
#pragma unroll
        for (int nt = 0; nt < 2; ++nt) {
          const int d = wn*32 + nt*16 + col16;
          tile[d * T2STR + row_loc] = __float2bfloat16(acc[mt][nt][r]);
        }
      }
    __syncthreads();
    const int d  = tid >> 2;      // 0..63
    const int hq = tid & 3;       // 32-row quarter
    const bf16* src = tile + d * T2STR + hq * 32;
    const int row0 = xblk*128 + hq*32;
    const int b = row0 / SN, sr0 = row0 - b * SN;
    const int hb2 = b*NH + yblk;
    bf16* dstF = (bf16*)Y + (((size_t)hb2*4 + (d>>4))*96)*256 + (size_t)(d&15)*8;
#pragma unroll
    for (int i = 0; i < 4; ++i) {
      const int key = sr0 + i*8;
      const size_t off = (size_t)(key>>4)*256 + (size_t)((key>>3)&1)*128;
      *reinterpret_cast<uint4*>(dstF + off) = reinterpret_cast<const uint4*>(src)[i];
    }
  }
}

// Merged K+Q projection: [0,768) K-proj (mode 1), [768,1024) Q-proj (mode 3).
__global__ __launch_bounds__(256) void gemmKQ(
    const bf16* __restrict__ XK, const bf16* __restrict__ WK, bf16* __restrict__ YK,
    const bf16* __restrict__ XQ, const bf16* __restrict__ WQ, bf16* __restrict__ YQ) {
  __shared__ bf16 dummy[8];
  const int id = blockIdx.x;
  if (id < 768) gemm_dev<1, bf16>(XK, WK, YK, id, dummy);
  else          gemm_dev<3, bf16>(XQ, WQ, YQ, id - 768, dummy);
}

__global__ __launch_bounds__(256) void gemmV(
    const bf16* __restrict__ XF, const bf16* __restrict__ WF, bf16* __restrict__ Y) {
  __shared__ __align__(16) bf16 tile[64 * T2STR];
  gemm_dev<2, bf16>(XF, WF, Y, blockIdx.x, tile);
}

__global__ __launch_bounds__(256) void gemmO(
    const bf16* __restrict__ XF, const bf16* __restrict__ WF, float* __restrict__ Y) {
  __shared__ bf16 dummy[8];
  gemm_dev<0, float>(XF, WF, Y, blockIdx.x, dummy);
}

// ---------------------------------------------------------------------------
// Barrier-free wave-private fused attention (round-6 proven, 52.9 us).
// One 64-lane wave owns 16 query rows; grid 2048 x 64 threads.
// Operand-swapped MFMAs keep lane&15 == query-row in EVERY phase.
// All operand loads FULLY COALESCED 1KB bursts (base + lane*16B);
// sched_barrier(0) pins the prefetch issue points. Fragment-linear q in,
// fragment-linear ctx out (feeds gemmO's coalesced X reads).
// ---------------------------------------------------------------------------
#define PSTR1 69    // pos stride (f32): scalar writes, b128-aligned reads
#define BSTR1 104   // P stride (bf16): b64 writes, b128 reads aligned

__global__ __launch_bounds__(64, 2) void attn1w(
    const bf16* __restrict__ qp, const bf16* __restrict__ Kh,
    const bf16* __restrict__ VT, const bf16* __restrict__ peT,
    const float* __restrict__ spanv, bf16* __restrict__ ctx) {
  __shared__ __align__(16) float pos_s[16 * PSTR1];
  __shared__ __align__(16) bf16  P_s[16 * BSTR1];

  const int id = blockIdx.x;
  const int h  = id & 7;
  const int s_ = id >> 3;
  const int m0 = (s_ & 31) * 16;
  const int b  = s_ >> 5;
  const int hb = b * 8 + h;
  const int lane  = threadIdx.x;
  const int col16 = lane & 15, quad = lane >> 4, kq = quad << 3;
  const int q4 = quad << 2;
  const int lane8 = lane * 8;

  // zero P band once (cols 80..103 stay zero; read by ks=2 PV fragment)
  for (int i = lane; i < 16 * BSTR1; i += 64)
    P_s[i] = __float2bfloat16(0.0f);

  // q from fragment-linear qp: rt*8192 + h*1024 + lane*8 (and +512)
  const bf16* qb = qp + (size_t)((b*SM + m0) >> 4) * 8192 + h*1024 + lane8;
  const bf16x8 qf0 = ld8any(qb), qf1 = ld8any(qb + 512);

  const bf16* kbF = Kh + (size_t)hb * 98304 + lane8;   // 96 tiles * 1024
  const bf16* vbF = VT + (size_t)hb * 98304 + lane8;   // 4 dt * 96 kt * 256
  const bf16* pbF = peT + lane8;

  float Mrun = -1.0e30f, Srun = 0.0f;
  const float span1024 = spanv[h] * 1024.0f;
  f32x4 o[4];
#pragma unroll
  for (int dt = 0; dt < 4; ++dt) o[dt] = f32x4{0.f,0.f,0.f,0.f};

  // prefetched operand fragments (single-buffered; WAR ordering via reg deps)
  bf16x8 kf[5][2], pf[4][2], vf[4][3];

  // ---- prologue: chunk-0 operands ----
  {
    const int tk0 = m0 >> 4;
#pragma unroll
    for (int t = 0; t < 5; ++t) {
      const bf16* kr = kbF + (size_t)(tk0 + t) * 1024;
      kf[t][0] = ld8any(kr); kf[t][1] = ld8any(kr + 512);
    }
#pragma unroll
    for (int t = 0; t < 4; ++t) {
      const bf16* pr = pbF + (size_t)t * 1024;
      pf[t][0] = ld8any(pr); pf[t][1] = ld8any(pr + 512);
    }
#pragma unroll
    for (int dt = 0; dt < 4; ++dt) {
      const bf16* v0 = vbF + (size_t)dt * 24576 + (size_t)tk0 * 256;
#pragma unroll
      for (int ks = 0; ks < 3; ++ks) vf[dt][ks] = ld8any(v0 + ks*512);
    }
    __builtin_amdgcn_sched_barrier(0);
  }

  const int posw = col16 * PSTR1 + q4;        // write base (scalar f32)
  const int posr = col16 * (PSTR1 - 1) + q4;  // read base (b128-aligned)
  const int pww  = col16 * BSTR1 + q4;        // P write base (b64-aligned)
  const int pwr  = col16 * BSTR1 + kq;        // P read base (b128-aligned)

  for (int ch = 0; ch < 16; ++ch) {
    const int l0 = ch << 6;

    // ---- pos MFMAs (swapped: A=pe rows, D rows = l, cols = q-row) ----
    f32x4 pacc[4];
#pragma unroll
    for (int t = 0; t < 4; ++t) {
      f32x4 a = {0.f,0.f,0.f,0.f};
      a = mfma16(pf[t][0], qf0, a);
      a = mfma16(pf[t][1], qf1, a);
      pacc[t] = a;
    }
    // scalar writes: pos_s[qrow][l], qrow = col16, l = 16t + q4 + r
#pragma unroll
    for (int t = 0; t < 4; ++t)
#pragma unroll
      for (int r = 0; r < 4; ++r)
        pos_s[posw + 16*t + r] = pacc[t][r];

    // ---- cont MFMAs (swapped: A=K rows, D rows = band pos, cols = q-row) ----
    f32x4 cacc[5];
#pragma unroll
    for (int t = 0; t < 5; ++t) {
      f32x4 a = {0.f,0.f,0.f,0.f};
      a = mfma16(kf[t][0], qf0, a);
      a = mfma16(kf[t][1], qf1, a);
      cacc[t] = a;
    }

    // ---- issue next chunk's K/pe (kf/pf regs now dead); pinned early so
    //      they stay in flight across the softmax below ----
    {
      const int l0n = (ch < 15) ? l0 + 64 : l0;
      const int tkn = (m0 + l0n) >> 4;
      const int tpn = l0n >> 4;
#pragma unroll
      for (int t = 0; t < 5; ++t) {
        const bf16* kr = kbF + (size_t)(tkn + t) * 1024;
        kf[t][0] = ld8any(kr); kf[t][1] = ld8any(kr + 512);
      }
#pragma unroll
      for (int t = 0; t < 4; ++t) {
        const bf16* pr = pbF + (size_t)(tpn + t) * 1024;
        pf[t][0] = ld8any(pr); pf[t][1] = ld8any(pr + 512);
      }
      __builtin_amdgcn_sched_barrier(0);
    }

    // ---- per-lane softmax over this row's 64-key window ----
    // lane's cont value (t,r): band pos bp = 16t+q4+r, l = bp - col16.
    float sc[5][4];
    float mc = -1.0e30f;
#pragma unroll
    for (int t = 0; t < 5; ++t) {
      const f32x4 pv4 = *reinterpret_cast<const f32x4*>(&pos_s[posr + 16*t]);
#pragma unroll
      for (int r = 0; r < 4; ++r) {
        const int l = 16*t + q4 + r - col16;
        float v = (cacc[t][r] + pv4[r]) * 0.125f;
        v = ((unsigned)l < 64u) ? v : -1.0e30f;
        sc[t][r] = v;
        mc = fmaxf(mc, v);
      }
    }
    mc = fmaxf(mc, __shfl_xor(mc, 16));
    mc = fmaxf(mc, __shfl_xor(mc, 32));
    const float Mnew = fmaxf(Mrun, mc);
    const float alpha = __expf(Mrun - Mnew);
    float ls = 0.0f;
#pragma unroll
    for (int t = 0; t < 5; ++t) {
      short4_ pk;
#pragma unroll
      for (int r = 0; r < 4; ++r) {
        const float p = __expf(sc[t][r] - Mnew);   // 0 for masked slots
        ls += p;
        const float lg = (float)(l0 + 16*t + q4 + r - col16);
        float mv = (lg - 1023.0f + span1024) * 0.03125f + 1.0f;
        mv = fminf(fmaxf(mv, 0.0f), 1.0f);
        pk[r] = bf_bits(p * mv);
      }
      *reinterpret_cast<short4_*>(&P_s[pww + 16*t]) = pk;
    }
    ls += __shfl_xor(ls, 16);
    ls += __shfl_xor(ls, 32);
    Srun = Srun * alpha + ls;
    Mrun = Mnew;

    // ---- PV (swapped: A=V^T rows=d, B=P cols=q-row) ----
#pragma unroll
    for (int dt = 0; dt < 4; ++dt)
#pragma unroll
      for (int r = 0; r < 4; ++r) o[dt][r] *= alpha;
#pragma unroll
    for (int ks = 0; ks < 3; ++ks) {
      const bf16x8 ap = ld8any(&P_s[pwr + ks*32]);
#pragma unroll
      for (int dt = 0; dt < 4; ++dt)
        o[dt] = mfma16(vf[dt][ks], ap, o[dt]);
    }

    // ---- issue next chunk's V (vf regs now dead); pinned early ----
    {
      const int tkn = (m0 + ((ch < 15) ? l0 + 64 : l0)) >> 4;
#pragma unroll
      for (int dt = 0; dt < 4; ++dt) {
        const bf16* v0 = vbF + (size_t)dt * 24576 + (size_t)tkn * 256;
#pragma unroll
        for (int ks = 0; ks < 3; ++ks) vf[dt][ks] = ld8any(v0 + ks*512);
      }
      __builtin_amdgcn_sched_barrier(0);
    }
  }

  // ---- epilogue: lane-local normalize, fragment-linear ctx stores ----
  const float inv = 1.0f / Srun;
  bf16* crb = ctx + (size_t)((b*SM + m0) >> 4) * 8192
            + (size_t)(h*1024 + (quad>>1)*128 + col16*8 + (quad&1)*4);
#pragma unroll
  for (int dt = 0; dt < 4; ++dt) {
    short4_ pk;
#pragma unroll
    for (int r = 0; r < 4; ++r) pk[r] = bf_bits(o[dt][r] * inv);
    *reinterpret_cast<short4_*>(crb + (size_t)(dt>>1)*512 + (dt&1)*256) = pk;
  }
}

// ---------------------------------------------------------------------------
// Fallback path kernels (round-6 proven, old row-major layouts).
// ---------------------------------------------------------------------------
template <int MODE, typename TX, typename TW, typename TY>
__global__ __launch_bounds__(256) void gemmbn64(const TX* __restrict__ X,
                                                const TW* __restrict__ W,
                                                TY* __restrict__ Y) {
  __shared__ __align__(16) bf16 tile[(MODE == 2) ? 64 * T2STR : 8];
  const int id   = blockIdx.x;
  const int s_   = id >> 3;
  const int xblk = (id & 7) + 8 * (s_ >> 3);
  const int yblk = s_ & 7;
  const int tid  = threadIdx.x;
  const int lane = tid & 63, w = tid >> 6;
  const int col16 = lane & 15, quad = lane >> 4, kq = quad << 3;
  const int wm = w >> 1, wn = w & 1;
  const int m0 = xblk * 128 + wm * 64;
  const int n0 = yblk * 64 + wn * 32;
  const TX* xr = X + (size_t)(m0 + col16) * SH + kq;
  const TW* wr = W + (size_t)(n0 + col16) * SH + kq;
  f32x4 acc[4][2];
#pragma unroll
  for (int i = 0; i < 4; ++i)
#pragma unroll
    for (int j = 0; j < 2; ++j) acc[i][j] = f32x4{0.f,0.f,0.f,0.f};
#pragma unroll
  for (int k0 = 0; k0 < SH; k0 += 32) {
    bf16x8 af[4], bfr[2];
#pragma unroll
    for (int t = 0; t < 4; ++t) af[t]  = ld8any(xr + (size_t)(t*16) * SH + k0);
#pragma unroll
    for (int t = 0; t < 2; ++t) bfr[t] = ld8any(wr + (size_t)(t*16) * SH + k0);
#pragma unroll
    for (int mt = 0; mt < 4; ++mt)
#pragma unroll
      for (int nt = 0; nt < 2; ++nt)
        acc[mt][nt] = mfma16(af[mt], bfr[nt], acc[mt][nt]);
  }

  if constexpr (MODE == 0) {
#pragma unroll
    for (int mt = 0; mt < 4; ++mt)
#pragma unroll
      for (int r = 0; r < 4; ++r) {
        const int row = m0 + mt*16 + quad*4 + r;
        TY* yr = Y + (size_t)row * SH + n0 + col16;
        st1(yr,      acc[mt][0][r]);
        st1(yr + 16, acc[mt][1][r]);
      }
  } else if constexpr (MODE == 1) {
#pragma unroll
    for (int mt = 0; mt < 4; ++mt)
#pragma unroll
      for (int r = 0; r < 4; ++r) {
        const int row = m0 + mt*16 + quad*4 + r;
        const int b = row / SN, sr = row - b * SN;
        bf16* yr = (bf16*)Y + (size_t)((b*NH + yblk)*SN + sr) * HD
                 + wn*32 + col16;
        yr[0]  = __float2bfloat16(acc[mt][0][r]);
        yr[16] = __float2bfloat16(acc[mt][1][r]);
      }
  } else {
#pragma unroll
    for (int mt = 0; mt < 4; ++mt)
#pragma unroll
      for (int r = 0; r < 4; ++r) {
        const int row_loc = wm*64 + mt*16 + quad*4 + r;
#pragma unroll
        for (int nt = 0; nt < 2; ++nt) {
          const int d = wn*32 + nt*16 + col16;
          tile[d * T2STR + row_loc] = __float2bfloat16(acc[mt][nt][r]);
        }
      }
    __syncthreads();
    const int d  = tid >> 2;
    const int hq = tid & 3;
    const bf16* src = tile + d * T2STR + hq * 32;
    const int row0 = xblk*128 + hq*32;
    const int b = row0 / SN, sr0 = row0 - b * SN;
    bf16* dst = (bf16*)Y + (size_t)((b*NH + yblk)*HD + d) * SN + sr0;
#pragma unroll
    for (int i = 0; i < 4; ++i)
      reinterpret_cast<uint4*>(dst)[i] = reinterpret_cast<const uint4*>(src)[i];
  }
}

__global__ void transpose_pe_fb(const float* __restrict__ pe, bf16* __restrict__ peT) {
  int idx = blockIdx.x * 256 + threadIdx.x;
  int l = idx >> 6, d = idx & 63;
  peT[idx] = __float2bfloat16(pe[d * SL + l]);
}

#define MT 16
#define CSTR 84
#define PSTR 65
#define BSTR 104
#define QSTR 72

__global__ __launch_bounds__(128) void attn_kernel_fb(
    const float* __restrict__ query, const float* __restrict__ Wq,
    const bf16* __restrict__ Kh, const bf16* __restrict__ VT,
    const bf16* __restrict__ peT, const float* __restrict__ spanv,
    bf16* __restrict__ ctx) {
  __shared__ __align__(16) float cont_lds[MT][CSTR];
  __shared__ __align__(16) float pos_lds[MT][PSTR];
  __shared__ __align__(16) bf16  P_lds[MT][BSTR];
  __shared__ __align__(16) bf16  q_lds[MT*QSTR];
  __shared__ float alpha_lds[MT];
  __shared__ float S_lds[MT];

  const int id = blockIdx.x;
  const int h  = id & 7;
  const int s_ = id >> 3;
  const int m0 = (s_ & 31) * MT;
  const int b  = s_ >> 5;
  const int hb = b * 8 + h;
  const int tid  = threadIdx.x;
  const int lane = tid & 63;
  const int w    = tid >> 6;
  const int col16 = lane & 15, quad = lane >> 4, kq = quad << 3;
  const int wr = quad << 2;

  for (int i = tid; i < MT * BSTR; i += 128)
    (&P_lds[0][0])[i] = __float2bfloat16(0.0f);

  bf16x8 qf0, qf1;
  {
    f32x4 qa0 = {0.f,0.f,0.f,0.f}, qa1 = qa0;
    const float* xq = query + (size_t)(b*SM + m0 + col16) * SH + kq;
    const float* w0 = Wq + (size_t)(h*HD + w*32 + col16) * SH + kq;
    const float* w1 = w0 + (size_t)16 * SH;
#pragma unroll
    for (int k0 = 0; k0 < SH; k0 += 32) {
      bf16x8 xa = ld8any(xq + k0);
      qa0 = mfma16(xa, ld8any(w0 + k0), qa0);
      qa1 = mfma16(xa, ld8any(w1 + k0), qa1);
    }
#pragma unroll
    for (int r = 0; r < 4; ++r) {
      q_lds[(wr + r)*QSTR + w*32 + col16]      = __float2bfloat16(qa0[r]);
      q_lds[(wr + r)*QSTR + w*32 + 16 + col16] = __float2bfloat16(qa1[r]);
    }
    __syncthreads();
    qf0 = ld8any(&q_lds[col16*QSTR + kq]);
    qf1 = ld8any(&q_lds[col16*QSTR + kq + 32]);
  }

  const bf16* kb = Kh + (size_t)(hb * SN) * HD + kq;
  const bf16* vb = VT + (size_t)(hb * HD) * SN;

  const int srow = tid >> 3, sj = tid & 7;
  float Mrun = -1.0e30f, Srun = 0.0f;
  const float span = spanv[h];
  const int dt0 = w * 16, dt1 = (w + 2) * 16;
  f32x4 o0 = {0.f,0.f,0.f,0.f}, o1 = o0;

  for (int ch = 0; ch < 16; ++ch) {
    const int l0 = ch << 6;
    const int nb_ = m0 + l0;

    f32x4 ca0 = {0.f,0.f,0.f,0.f}, ca1 = ca0, ca2 = ca0, pa0 = ca0, pa1 = ca0;
    {
      const bf16* kr0 = kb + (size_t)(nb_ + w*16 + col16) * HD;
      ca0 = mfma16(qf0, ld8any(kr0),           ca0);
      ca0 = mfma16(qf1, ld8any(kr0 + 32),      ca0);
      const bf16* kr1 = kr0 + 32 * HD;
      ca1 = mfma16(qf0, ld8any(kr1),           ca1);
      ca1 = mfma16(qf1, ld8any(kr1 + 32),      ca1);
      if (w == 0) {
        const bf16* kr2 = kr0 + 64 * HD;
        ca2 = mfma16(qf0, ld8any(kr2),         ca2);
        ca2 = mfma16(qf1, ld8any(kr2 + 32),    ca2);
      }
      const bf16* pr0 = peT + (size_t)(l0 + w*16 + col16) * HD + kq;
      pa0 = mfma16(qf0, ld8any(pr0),           pa0);
      pa0 = mfma16(qf1, ld8any(pr0 + 32),      pa0);
      const bf16* pr1 = pr0 + 32 * HD;
      pa1 = mfma16(qf0, ld8any(pr1),           pa1);
      pa1 = mfma16(qf1, ld8any(pr1 + 32),      pa1);
    }
#pragma unroll
    for (int r = 0; r < 4; ++r) {
      cont_lds[wr + r][w*16 + col16]      = ca0[r];
      cont_lds[wr + r][w*16 + 32 + col16] = ca1[r];
      if (w == 0) cont_lds[wr + r][64 + col16] = ca2[r];
      pos_lds[wr + r][w*16 + col16]       = pa0[r];
      pos_lds[wr + r][w*16 + 32 + col16]  = pa1[r];
    }
    __syncthreads();

    float sc[8];
    float mc = -1.0e30f;
    const float* crow = &cont_lds[srow][srow + sj*8];
    const float* prow = &pos_lds[srow][sj*8];
#pragma unroll
    for (int i = 0; i < 8; ++i) {
      float v = (crow[i] + prow[i]) * 0.125f;
      sc[i] = v;
      mc = fmaxf(mc, v);
    }
    mc = fmaxf(mc, __shfl_xor(mc, 1));
    mc = fmaxf(mc, __shfl_xor(mc, 2));
    mc = fmaxf(mc, __shfl_xor(mc, 4));
    const float Mnew = fmaxf(Mrun, mc);
    const float alpha = __expf(Mrun - Mnew);
    float ls = 0.0f;
    bf16* pwrow = &P_lds[srow][srow + sj*8];
#pragma unroll
    for (int i = 0; i < 8; ++i) {
      float p = __expf(sc[i] - Mnew);
      ls += p;
      const float tpl = (float)(l0 + sj*8 + i) - 1023.0f;
      float mv = (tpl + span * 1024.0f) * 0.03125f + 1.0f;
      mv = fminf(fmaxf(mv, 0.0f), 1.0f);
      pwrow[i] = __float2bfloat16(p * mv);
    }
    ls += __shfl_xor(ls, 1);
    ls += __shfl_xor(ls, 2);
    ls += __shfl_xor(ls, 4);
    Srun = Srun * alpha + ls;
    Mrun = Mnew;
    if (sj == 0) { alpha_lds[srow] = alpha; S_lds[srow] = Srun; }
    __syncthreads();

    float al[4];
#pragma unroll
    for (int r = 0; r < 4; ++r) al[r] = alpha_lds[wr + r];
#pragma unroll
    for (int r = 0; r < 4; ++r) { o0[r] *= al[r]; o1[r] *= al[r]; }
#pragma unroll
    for (int ks = 0; ks < 3; ++ks) {
      const bf16x8 ap = ld8any(&P_lds[col16][ks*32 + kq]);
      const bf16* v0 = vb + (size_t)(dt0 + col16) * SN + nb_ + ks*32 + kq;
      const bf16* v1 = vb + (size_t)(dt1 + col16) * SN + nb_ + ks*32 + kq;
      o0 = mfma16(ap, ld8any(v0), o0);
      o1 = mfma16(ap, ld8any(v1), o1);
    }
  }

  bf16* cr = ctx + (size_t)(b*SM + m0 + wr) * SH + h*HD + col16;
#pragma unroll
  for (int r = 0; r < 4; ++r) {
    const float inv = 1.0f / S_lds[wr + r];
    cr[(size_t)r * SH + dt0] = __float2bfloat16(o0[r] * inv);
    cr[(size_t)r * SH + dt1] = __float2bfloat16(o1[r] * inv);
  }
}

// ---------------------------------------------------------------------------
extern "C" void kernel_launch(void* const* d_in, const int* in_sizes, int n_in,
                              void* d_out, int out_size, void* d_ws, size_t ws_size,
                              hipStream_t stream) {
  const float* query  = (const float*)d_in[0];
  const float* key    = (const float*)d_in[1];
  const float* value  = (const float*)d_in[2];
  const float* key_pe = (const float*)d_in[3];
  const float* Wq     = (const float*)d_in[4];
  const float* Wk     = (const float*)d_in[5];
  const float* Wv     = (const float*)d_in[6];
  const float* Wo     = (const float*)d_in[7];
  const float* spanv  = (const float*)d_in[8];
  float* out = (float*)d_out;

  bf16* ws = (bf16*)d_ws;
  if (ws_size >= (size_t)48365568) {
    // Path C: fully fragment-linear pipeline, 5 launches, 48.4 MB ws.
    // B0: stgK -> vF.  B1: stgV.  B2: kF.  ctxC: qF staging -> attn ctx.
    bf16* B0   = ws;                      // 6291456
    bf16* B1   = B0  + 6291456;           // 6291456
    bf16* B2   = B1  + 6291456;           // 6291456
    bf16* qp   = B2  + 6291456;           // 2097152
    bf16* ctxC = qp  + 2097152;           // 2097152 (qF staging, then ctx)
    bf16* peF  = ctxC + 2097152;          // 65536
    bf16* Wb   = peF + 65536;             // 1048576
    bf16* Wq_b = Wb, *Wk_b = Wb + 262144, *Wv_b = Wb + 524288, *Wo_b = Wb + 786432;

    // L1: all conversions in one launch.
    prep_all<<<7936, 256, 0, stream>>>(key, value, query, Wq, Wk, Wv, Wo,
                                       key_pe, B0, B1, ctxC, Wb, peF);
    // L2: K-projection (B0->B2) + Q-projection (ctxC->qp), disjoint R/W.
    gemmKQ<<<1024, 256, 0, stream>>>(B0, Wk_b, B2, ctxC, Wq_b, qp);
    // L3: V-projection into the now-dead stgK region (B1->B0).
    gemmV<<<768, 256, 0, stream>>>(B1, Wv_b, B0);
    // L4: fused attention (overwrites ctxC).
    attn1w<<<2048, 64, 0, stream>>>(qp, B2, B0, peF, spanv, ctxC);
    // L5: output projection.
    gemmO<<<256, 256, 0, stream>>>(ctxC, Wo_b, out);
  } else {
    // Path B (fallback): fused-q attention, f32 GEMM reads, 29.5 MB ws.
    bf16* k_head = ws;
    bf16* vT     = k_head + 6291456;
    bf16* ctx    = vT     + 6291456;
    bf16* peT    = ctx    + 2097152;
    gemmbn64<1, float, float, bf16><<<768, 256, 0, stream>>>(key,   Wk, k_head);
    gemmbn64<2, float, float, bf16><<<768, 256, 0, stream>>>(value, Wv, vT);
    transpose_pe_fb<<<256, 256, 0, stream>>>(key_pe, peT);
    attn_kernel_fb<<<2048, 128, 0, stream>>>(query, Wq, k_head, vT,
                                             peT, spanv, ctx);
    gemmbn64<0, bf16, float, float><<<256, 256, 0, stream>>>(ctx, Wo, out);
  }
}

// Round 9
// 186.177 us; speedup vs baseline: 1.9977x; 1.0227x over previous
//
#include <hip/hip_runtime.h>
#include <hip/hip_bf16.h>
#include <type_traits>

typedef __hip_bfloat16 bf16;
typedef short bf16x8 __attribute__((ext_vector_type(8)));
typedef float f32x4 __attribute__((ext_vector_type(4)));
typedef short short4_ __attribute__((ext_vector_type(4)));

#define NB 8      // batch
#define SM 512    // block size M
#define SL 1024   // attn span L
#define SH 512    // hidden
#define NH 8      // heads
#define HD 64     // head dim
#define SN 1536   // M + L (key length)

static __device__ __forceinline__ short bf_bits(float x) {
  union { bf16 b; short s; } u; u.b = __float2bfloat16(x); return u.s;
}
static __device__ __forceinline__ bf16x8 ld8any(const bf16* p) {
  return *reinterpret_cast<const bf16x8*>(p);
}
static __device__ __forceinline__ bf16x8 ld8any(const float* p) {
  float4 a = *reinterpret_cast<const float4*>(p);
  float4 b = *reinterpret_cast<const float4*>(p + 4);
  bf16x8 r;
  r[0] = bf_bits(a.x); r[1] = bf_bits(a.y); r[2] = bf_bits(a.z); r[3] = bf_bits(a.w);
  r[4] = bf_bits(b.x); r[5] = bf_bits(b.y); r[6] = bf_bits(b.z); r[7] = bf_bits(b.w);
  return r;
}
static __device__ __forceinline__ void st1(bf16* p, float v) { *p = __float2bfloat16(v); }
static __device__ __forceinline__ void st1(float* p, float v) { *p = v; }
static __device__ __forceinline__ f32x4 mfma16(bf16x8 a, bf16x8 b, f32x4 c) {
  return __builtin_amdgcn_mfma_f32_16x16x32_bf16(a, b, c, 0, 0, 0);
}

// ---------------------------------------------------------------------------
// Universal fragment-linear layout for an [R x C] matrix (C = 512):
//   FRAGIDX(row,col) = (row>>4)*8192 + (col>>5)*512
//                    + ((col>>3)&3)*128 + (row&15)*8 + (col&7)
// One wave MFMA fragment (16 rows x 32 cols) = 1KB contiguous, lane*16B.
// ---------------------------------------------------------------------------

// ---------------------------------------------------------------------------
// prep_all v2: all input conversions, ONE launch, LDS-staged so BOTH the
// f32 row-major reads AND the fragment-linear bf16 writes are coalesced
// (v1 wrote 16B chunks at 256B stride = 64 lines/wave-store).
//  [0,768)     key   (16 rows/block) -> kS
//  [768,1536)  value -> vS
//  [1536,1792) query -> qS (ctx region)
//  [1792,1920) Wq/Wk/Wv/Wo -> Wb
//  [1920,1952) key_pe -> peF (tiny, old path)
// ---------------------------------------------------------------------------
__global__ __launch_bounds__(256) void prep_all(
    const float* __restrict__ key, const float* __restrict__ value,
    const float* __restrict__ query,
    const float* __restrict__ Wq, const float* __restrict__ Wk,
    const float* __restrict__ Wv, const float* __restrict__ Wo,
    const float* __restrict__ pe,
    bf16* __restrict__ kS, bf16* __restrict__ vS, bf16* __restrict__ qS,
    bf16* __restrict__ Wb, bf16* __restrict__ peF) {
  __shared__ __align__(16) bf16 t[16 * 520];
  const int id = blockIdx.x, tid = threadIdx.x;
  if (id < 1920) {
    const float* src; bf16* dst;
    if (id < 768)       { src = key   + (size_t)id * 8192;
                          dst = kS    + (size_t)id * 8192; }
    else if (id < 1536) { src = value + (size_t)(id - 768) * 8192;
                          dst = vS    + (size_t)(id - 768) * 8192; }
    else if (id < 1792) { src = query + (size_t)(id - 1536) * 8192;
                          dst = qS    + (size_t)(id - 1536) * 8192; }
    else {
      const int s = id - 1792;
      const float* ws_[4] = {Wq, Wk, Wv, Wo};
      src = ws_[s >> 5] + (size_t)(s & 31) * 8192;
      dst = Wb + (size_t)(s >> 5) * 262144 + (size_t)(s & 31) * 8192;
    }
    // stage 16 rows x 512 cols into LDS (row stride 520 = bank spread)
#pragma unroll
    for (int j = 0; j < 4; ++j) {
      const int i = j * 2048 + tid * 8;
      const bf16x8 v = ld8any(src + i);
      *reinterpret_cast<bf16x8*>(&t[(i >> 9) * 520 + (i & 511)]) = v;
    }
    __syncthreads();
    // emit fragment-linear: a = kt5*512 + q*128 + rowl*8 + de (coalesced)
#pragma unroll
    for (int j = 0; j < 4; ++j) {
      const int a = j * 2048 + tid * 8;
      const int kt5 = a >> 9, rest = a & 511;
      const int q = rest >> 7, rowl = (rest >> 3) & 15;
      *reinterpret_cast<bf16x8*>(dst + a) =
          *reinterpret_cast<const bf16x8*>(&t[rowl * 520 + kt5 * 32 + q * 8]);
    }
  } else {
    const int idx = (id - 1920) * 256 + tid;
    const int l = idx >> 6, d = idx & 63;
    peF[(size_t)((l >> 4) * 2 + (d >> 5)) * 512
        + (size_t)((((d >> 3) & 3) * 16 + (l & 15)) * 8 + (d & 7))]
      = __float2bfloat16(pe[d * SL + l]);
  }
}

// ---------------------------------------------------------------------------
// gemm_dev2: Y[R x 512] = X @ W^T, X/W fragment-linear.
// v9: BM=128 x BN=128 block, 4 waves, wave tile 64x64 -> 16 MFMAs per
// 8-load batch (2x arithmetic intensity of v8) and 4 yblk (halved X
// re-reads). Double-buffered K-loop, sched_barrier-pinned load issue.
// grid = (R/128)*4, yblk = id&3, xblk = id>>2.
// MODE 0: row-major TY. MODE 1: kF. MODE 2: vF (LDS transpose). MODE 3: qpF.
// ---------------------------------------------------------------------------
#define T2STR 136

#define GL2(AF, BF, KT)                                                      \
  {                                                                          \
    AF[0] = ld8any(xr +         (size_t)(KT) * 512);                         \
    AF[1] = ld8any(xr + 8192  + (size_t)(KT) * 512);                         \
    AF[2] = ld8any(xr + 16384 + (size_t)(KT) * 512);                         \
    AF[3] = ld8any(xr + 24576 + (size_t)(KT) * 512);                         \
    BF[0] = ld8any(wr +         (size_t)(KT) * 512);                         \
    BF[1] = ld8any(wr + 8192  + (size_t)(KT) * 512);                         \
    BF[2] = ld8any(wr + 16384 + (size_t)(KT) * 512);                         \
    BF[3] = ld8any(wr + 24576 + (size_t)(KT) * 512);                         \
  }

template <int MODE, typename TY>
static __device__ __forceinline__ void gemm_dev2(const bf16* __restrict__ XF,
                                                 const bf16* __restrict__ WF,
                                                 TY* __restrict__ Y,
                                                 int id, bf16* tile) {
  const int yblk = id & 3, xblk = id >> 2;
  const int tid  = threadIdx.x;
  const int lane = tid & 63, w = tid >> 6;
  const int col16 = lane & 15, quad = lane >> 4;
  const int lane8 = lane * 8;
  const int wm = w >> 1, wn = w & 1;
  const int m0 = xblk * 128 + wm * 64;
  const int n0 = yblk * 128 + wn * 64;
  const bf16* xr = XF + (size_t)(m0 >> 4) * 8192 + lane8;
  const bf16* wr = WF + (size_t)(n0 >> 4) * 8192 + lane8;
  f32x4 acc[4][4];
#pragma unroll
  for (int i = 0; i < 4; ++i)
#pragma unroll
    for (int j = 0; j < 4; ++j) acc[i][j] = f32x4{0.f,0.f,0.f,0.f};

  bf16x8 afA[4], bfA[4], afB[4], bfB[4];
  GL2(afA, bfA, 0);
  __builtin_amdgcn_sched_barrier(0);
#pragma unroll
  for (int kt = 0; kt < 16; kt += 2) {
    GL2(afB, bfB, kt + 1);
    __builtin_amdgcn_sched_barrier(0);
#pragma unroll
    for (int mt = 0; mt < 4; ++mt)
#pragma unroll
      for (int nt = 0; nt < 4; ++nt)
        acc[mt][nt] = mfma16(afA[mt], bfA[nt], acc[mt][nt]);
    const int ktn = (kt + 2 < 16) ? kt + 2 : kt;  // last: dead reload
    GL2(afA, bfA, ktn);
    __builtin_amdgcn_sched_barrier(0);
#pragma unroll
    for (int mt = 0; mt < 4; ++mt)
#pragma unroll
      for (int nt = 0; nt < 4; ++nt)
        acc[mt][nt] = mfma16(afB[mt], bfB[nt], acc[mt][nt]);
  }

  if constexpr (MODE == 0) {
#pragma unroll
    for (int mt = 0; mt < 4; ++mt)
#pragma unroll
      for (int r = 0; r < 4; ++r) {
        const int row = m0 + mt*16 + quad*4 + r;
        TY* yr = Y + (size_t)row * SH + n0 + col16;
#pragma unroll
        for (int nt = 0; nt < 4; ++nt) st1(yr + nt*16, acc[mt][nt][r]);
      }
  } else if constexpr (MODE == 1) {
    // kF: head h = n0>>6; within-half idx = key8 + q*128 + de.
    const int dq = col16 >> 3, de = col16 & 7;
    const int head = n0 >> 6;
#pragma unroll
    for (int mt = 0; mt < 4; ++mt)
#pragma unroll
      for (int r = 0; r < 4; ++r) {
        const int row = m0 + mt*16 + quad*4 + r;
        const int b = row / SN, sr = row - b * SN;
        bf16* yr = (bf16*)Y
            + (((size_t)(b*NH + head)*96 + (sr>>4))*2)*512
            + (size_t)((sr&15)*8 + de);
#pragma unroll
        for (int nt = 0; nt < 4; ++nt)
          yr[(nt>>1)*512 + ((nt&1)*2 + dq)*128] = __float2bfloat16(acc[mt][nt][r]);
      }
  } else if constexpr (MODE == 3) {
    // qpF fragment-linear: col = n0 + nt*16 + col16.
    const int dq = col16 >> 3, de = col16 & 7;
    const int c5b = n0 >> 5;
#pragma unroll
    for (int mt = 0; mt < 4; ++mt)
#pragma unroll
      for (int r = 0; r < 4; ++r) {
        bf16* yr = (bf16*)Y + (size_t)((m0>>4) + mt) * 8192
                 + (size_t)((quad*4 + r)*8 + de);
#pragma unroll
        for (int nt = 0; nt < 4; ++nt)
          yr[(c5b + (nt>>1))*512 + ((nt&1)*2 + dq)*128] = __float2bfloat16(acc[mt][nt][r]);
      }
  } else {
    // vF via LDS transpose: tile[d 0..127][row_loc 0..127]
#pragma unroll
    for (int mt = 0; mt < 4; ++mt)
#pragma unroll
      for (int r = 0; r < 4; ++r) {
        const int row_loc = wm*64 + mt*16 + quad*4 + r;
#pragma unroll
        for (int nt = 0; nt < 4; ++nt) {
          const int d = wn*64 + nt*16 + col16;
          tile[d * T2STR + row_loc] = __float2bfloat16(acc[mt][nt][r]);
        }
      }
    __syncthreads();
    const int d  = tid >> 1;      // 0..127
    const int hq = tid & 1;       // 64-row half
    const bf16* src = tile + d * T2STR + hq * 64;
    const int row0 = xblk*128 + hq*64;
    const int b = row0 / SN, sr0 = row0 - b * SN;
    const int head = yblk*2 + (d >> 6);
    const int dd = d & 63;
    bf16* dstF = (bf16*)Y + (((size_t)(b*NH + head)*4 + (dd>>4))*96)*256
               + (size_t)(dd&15)*8;
#pragma unroll
    for (int i = 0; i < 8; ++i) {
      const int key = sr0 + i*8;
      const size_t off = (size_t)(key>>4)*256 + (size_t)((key>>3)&1)*128;
      *reinterpret_cast<uint4*>(dstF + off) = reinterpret_cast<const uint4*>(src)[i];
    }
  }
}

// Merged K+Q projection: [0,384) K-proj (mode 1), [384,512) Q-proj (mode 3).
__global__ __launch_bounds__(256, 2) void gemmKQ(
    const bf16* __restrict__ XK, const bf16* __restrict__ WK, bf16* __restrict__ YK,
    const bf16* __restrict__ XQ, const bf16* __restrict__ WQ, bf16* __restrict__ YQ) {
  __shared__ bf16 dummy[8];
  const int id = blockIdx.x;
  if (id < 384) gemm_dev2<1, bf16>(XK, WK, YK, id, dummy);
  else          gemm_dev2<3, bf16>(XQ, WQ, YQ, id - 384, dummy);
}

__global__ __launch_bounds__(256, 2) void gemmV(
    const bf16* __restrict__ XF, const bf16* __restrict__ WF, bf16* __restrict__ Y) {
  __shared__ __align__(16) bf16 tile[128 * T2STR];
  gemm_dev2<2, bf16>(XF, WF, Y, blockIdx.x, tile);
}

__global__ __launch_bounds__(256, 2) void gemmO(
    const bf16* __restrict__ XF, const bf16* __restrict__ WF, float* __restrict__ Y) {
  __shared__ bf16 dummy[8];
  gemm_dev2<0, float>(XF, WF, Y, blockIdx.x, dummy);
}

// ---------------------------------------------------------------------------
// Barrier-free wave-private fused attention (round-6/8 proven, ~47 us).
// One 64-lane wave owns 16 query rows; grid 2048 x 64 threads.
// Operand-swapped MFMAs keep lane&15 == query-row in EVERY phase.
// All operand loads FULLY COALESCED 1KB bursts (base + lane*16B);
// sched_barrier(0) pins the prefetch issue points. Fragment-linear q in,
// fragment-linear ctx out (feeds gemmO's coalesced X reads).
// ---------------------------------------------------------------------------
#define PSTR1 69    // pos stride (f32): scalar writes, b128-aligned reads
#define BSTR1 104   // P stride (bf16): b64 writes, b128 reads aligned

__global__ __launch_bounds__(64, 2) void attn1w(
    const bf16* __restrict__ qp, const bf16* __restrict__ Kh,
    const bf16* __restrict__ VT, const bf16* __restrict__ peT,
    const float* __restrict__ spanv, bf16* __restrict__ ctx) {
  __shared__ __align__(16) float pos_s[16 * PSTR1];
  __shared__ __align__(16) bf16  P_s[16 * BSTR1];

  const int id = blockIdx.x;
  const int h  = id & 7;
  const int s_ = id >> 3;
  const int m0 = (s_ & 31) * 16;
  const int b  = s_ >> 5;
  const int hb = b * 8 + h;
  const int lane  = threadIdx.x;
  const int col16 = lane & 15, quad = lane >> 4, kq = quad << 3;
  const int q4 = quad << 2;
  const int lane8 = lane * 8;

  // zero P band once (cols 80..103 stay zero; read by ks=2 PV fragment)
  for (int i = lane; i < 16 * BSTR1; i += 64)
    P_s[i] = __float2bfloat16(0.0f);

  // q from fragment-linear qp: rt*8192 + h*1024 + lane*8 (and +512)
  const bf16* qb = qp + (size_t)((b*SM + m0) >> 4) * 8192 + h*1024 + lane8;
  const bf16x8 qf0 = ld8any(qb), qf1 = ld8any(qb + 512);

  const bf16* kbF = Kh + (size_t)hb * 98304 + lane8;   // 96 tiles * 1024
  const bf16* vbF = VT + (size_t)hb * 98304 + lane8;   // 4 dt * 96 kt * 256
  const bf16* pbF = peT + lane8;

  float Mrun = -1.0e30f, Srun = 0.0f;
  const float span1024 = spanv[h] * 1024.0f;
  f32x4 o[4];
#pragma unroll
  for (int dt = 0; dt < 4; ++dt) o[dt] = f32x4{0.f,0.f,0.f,0.f};

  // prefetched operand fragments (single-buffered; WAR ordering via reg deps)
  bf16x8 kf[5][2], pf[4][2], vf[4][3];

  // ---- prologue: chunk-0 operands ----
  {
    const int tk0 = m0 >> 4;
#pragma unroll
    for (int t = 0; t < 5; ++t) {
      const bf16* kr = kbF + (size_t)(tk0 + t) * 1024;
      kf[t][0] = ld8any(kr); kf[t][1] = ld8any(kr + 512);
    }
#pragma unroll
    for (int t = 0; t < 4; ++t) {
      const bf16* pr = pbF + (size_t)t * 1024;
      pf[t][0] = ld8any(pr); pf[t][1] = ld8any(pr + 512);
    }
#pragma unroll
    for (int dt = 0; dt < 4; ++dt) {
      const bf16* v0 = vbF + (size_t)dt * 24576 + (size_t)tk0 * 256;
#pragma unroll
      for (int ks = 0; ks < 3; ++ks) vf[dt][ks] = ld8any(v0 + ks*512);
    }
    __builtin_amdgcn_sched_barrier(0);
  }

  const int posw = col16 * PSTR1 + q4;        // write base (scalar f32)
  const int posr = col16 * (PSTR1 - 1) + q4;  // read base (b128-aligned)
  const int pww  = col16 * BSTR1 + q4;        // P write base (b64-aligned)
  const int pwr  = col16 * BSTR1 + kq;        // P read base (b128-aligned)

  for (int ch = 0; ch < 16; ++ch) {
    const int l0 = ch << 6;

    // ---- pos MFMAs (swapped: A=pe rows, D rows = l, cols = q-row) ----
    f32x4 pacc[4];
#pragma unroll
    for (int t = 0; t < 4; ++t) {
      f32x4 a = {0.f,0.f,0.f,0.f};
      a = mfma16(pf[t][0], qf0, a);
      a = mfma16(pf[t][1], qf1, a);
      pacc[t] = a;
    }
    // scalar writes: pos_s[qrow][l], qrow = col16, l = 16t + q4 + r
#pragma unroll
    for (int t = 0; t < 4; ++t)
#pragma unroll
      for (int r = 0; r < 4; ++r)
        pos_s[posw + 16*t + r] = pacc[t][r];

    // ---- cont MFMAs (swapped: A=K rows, D rows = band pos, cols = q-row) ----
    f32x4 cacc[5];
#pragma unroll
    for (int t = 0; t < 5; ++t) {
      f32x4 a = {0.f,0.f,0.f,0.f};
      a = mfma16(kf[t][0], qf0, a);
      a = mfma16(kf[t][1], qf1, a);
      cacc[t] = a;
    }

    // ---- issue next chunk's K/pe (kf/pf regs now dead); pinned early so
    //      they stay in flight across the softmax below ----
    {
      const int l0n = (ch < 15) ? l0 + 64 : l0;
      const int tkn = (m0 + l0n) >> 4;
      const int tpn = l0n >> 4;
#pragma unroll
      for (int t = 0; t < 5; ++t) {
        const bf16* kr = kbF + (size_t)(tkn + t) * 1024;
        kf[t][0] = ld8any(kr); kf[t][1] = ld8any(kr + 512);
      }
#pragma unroll
      for (int t = 0; t < 4; ++t) {
        const bf16* pr = pbF + (size_t)(tpn + t) * 1024;
        pf[t][0] = ld8any(pr); pf[t][1] = ld8any(pr + 512);
      }
      __builtin_amdgcn_sched_barrier(0);
    }

    // ---- per-lane softmax over this row's 64-key window ----
    // lane's cont value (t,r): band pos bp = 16t+q4+r, l = bp - col16.
    float sc[5][4];
    float mc = -1.0e30f;
#pragma unroll
    for (int t = 0; t < 5; ++t) {
      const f32x4 pv4 = *reinterpret_cast<const f32x4*>(&pos_s[posr + 16*t]);
#pragma unroll
      for (int r = 0; r < 4; ++r) {
        const int l = 16*t + q4 + r - col16;
        float v = (cacc[t][r] + pv4[r]) * 0.125f;
        v = ((unsigned)l < 64u) ? v : -1.0e30f;
        sc[t][r] = v;
        mc = fmaxf(mc, v);
      }
    }
    mc = fmaxf(mc, __shfl_xor(mc, 16));
    mc = fmaxf(mc, __shfl_xor(mc, 32));
    const float Mnew = fmaxf(Mrun, mc);
    const float alpha = __expf(Mrun - Mnew);
    float ls = 0.0f;
#pragma unroll
    for (int t = 0; t < 5; ++t) {
      short4_ pk;
#pragma unroll
      for (int r = 0; r < 4; ++r) {
        const float p = __expf(sc[t][r] - Mnew);   // 0 for masked slots
        ls += p;
        const float lg = (float)(l0 + 16*t + q4 + r - col16);
        float mv = (lg - 1023.0f + span1024) * 0.03125f + 1.0f;
        mv = fminf(fmaxf(mv, 0.0f), 1.0f);
        pk[r] = bf_bits(p * mv);
      }
      *reinterpret_cast<short4_*>(&P_s[pww + 16*t]) = pk;
    }
    ls += __shfl_xor(ls, 16);
    ls += __shfl_xor(ls, 32);
    Srun = Srun * alpha + ls;
    Mrun = Mnew;

    // ---- PV (swapped: A=V^T rows=d, B=P cols=q-row) ----
#pragma unroll
    for (int dt = 0; dt < 4; ++dt)
#pragma unroll
      for (int r = 0; r < 4; ++r) o[dt][r] *= alpha;
#pragma unroll
    for (int ks = 0; ks < 3; ++ks) {
      const bf16x8 ap = ld8any(&P_s[pwr + ks*32]);
#pragma unroll
      for (int dt = 0; dt < 4; ++dt)
        o[dt] = mfma16(vf[dt][ks], ap, o[dt]);
    }

    // ---- issue next chunk's V (vf regs now dead); pinned early ----
    {
      const int tkn = (m0 + ((ch < 15) ? l0 + 64 : l0)) >> 4;
#pragma unroll
      for (int dt = 0; dt < 4; ++dt) {
        const bf16* v0 = vbF + (size_t)dt * 24576 + (size_t)tkn * 256;
#pragma unroll
        for (int ks = 0; ks < 3; ++ks) vf[dt][ks] = ld8any(v0 + ks*512);
      }
      __builtin_amdgcn_sched_barrier(0);
    }
  }

  // ---- epilogue: lane-local normalize, fragment-linear ctx stores ----
  const float inv = 1.0f / Srun;
  bf16* crb = ctx + (size_t)((b*SM + m0) >> 4) * 8192
            + (size_t)(h*1024 + (quad>>1)*128 + col16*8 + (quad&1)*4);
#pragma unroll
  for (int dt = 0; dt < 4; ++dt) {
    short4_ pk;
#pragma unroll
    for (int r = 0; r < 4; ++r) pk[r] = bf_bits(o[dt][r] * inv);
    *reinterpret_cast<short4_*>(crb + (size_t)(dt>>1)*512 + (dt&1)*256) = pk;
  }
}

// ---------------------------------------------------------------------------
// Fallback path kernels (round-6 proven, old row-major layouts).
// ---------------------------------------------------------------------------
template <int MODE, typename TX, typename TW, typename TY>
__global__ __launch_bounds__(256) void gemmbn64(const TX* __restrict__ X,
                                                const TW* __restrict__ W,
                                                TY* __restrict__ Y) {
  __shared__ __align__(16) bf16 tile[(MODE == 2) ? 64 * T2STR : 8];
  const int id   = blockIdx.x;
  const int s_   = id >> 3;
  const int xblk = (id & 7) + 8 * (s_ >> 3);
  const int yblk = s_ & 7;
  const int tid  = threadIdx.x;
  const int lane = tid & 63, w = tid >> 6;
  const int col16 = lane & 15, quad = lane >> 4, kq = quad << 3;
  const int wm = w >> 1, wn = w & 1;
  const int m0 = xblk * 128 + wm * 64;
  const int n0 = yblk * 64 + wn * 32;
  const TX* xr = X + (size_t)(m0 + col16) * SH + kq;
  const TW* wr = W + (size_t)(n0 + col16) * SH + kq;
  f32x4 acc[4][2];
#pragma unroll
  for (int i = 0; i < 4; ++i)
#pragma unroll
    for (int j = 0; j < 2; ++j) acc[i][j] = f32x4{0.f,0.f,0.f,0.f};
#pragma unroll
  for (int k0 = 0; k0 < SH; k0 += 32) {
    bf16x8 af[4], bfr[2];
#pragma unroll
    for (int t = 0; t < 4; ++t) af[t]  = ld8any(xr + (size_t)(t*16) * SH + k0);
#pragma unroll
    for (int t = 0; t < 2; ++t) bfr[t] = ld8any(wr + (size_t)(t*16) * SH + k0);
#pragma unroll
    for (int mt = 0; mt < 4; ++mt)
#pragma unroll
      for (int nt = 0; nt < 2; ++nt)
        acc[mt][nt] = mfma16(af[mt], bfr[nt], acc[mt][nt]);
  }

  if constexpr (MODE == 0) {
#pragma unroll
    for (int mt = 0; mt < 4; ++mt)
#pragma unroll
      for (int r = 0; r < 4; ++r) {
        const int row = m0 + mt*16 + quad*4 + r;
        TY* yr = Y + (size_t)row * SH + n0 + col16;
        st1(yr,      acc[mt][0][r]);
        st1(yr + 16, acc[mt][1][r]);
      }
  } else if constexpr (MODE == 1) {
#pragma unroll
    for (int mt = 0; mt < 4; ++mt)
#pragma unroll
      for (int r = 0; r < 4; ++r) {
        const int row = m0 + mt*16 + quad*4 + r;
        const int b = row / SN, sr = row - b * SN;
        bf16* yr = (bf16*)Y + (size_t)((b*NH + yblk)*SN + sr) * HD
                 + wn*32 + col16;
        yr[0]  = __float2bfloat16(acc[mt][0][r]);
        yr[16] = __float2bfloat16(acc[mt][1][r]);
      }
  } else {
#pragma unroll
    for (int mt = 0; mt < 4; ++mt)
#pragma unroll
      for (int r = 0; r < 4; ++r) {
        const int row_loc = wm*64 + mt*16 + quad*4 + r;
#pragma unroll
        for (int nt = 0; nt < 2; ++nt) {
          const int d = wn*32 + nt*16 + col16;
          tile[d * T2STR + row_loc] = __float2bfloat16(acc[mt][nt][r]);
        }
      }
    __syncthreads();
    const int d  = tid >> 2;
    const int hq = tid & 3;
    const bf16* src = tile + d * T2STR + hq * 32;
    const int row0 = xblk*128 + hq*32;
    const int b = row0 / SN, sr0 = row0 - b * SN;
    bf16* dst = (bf16*)Y + (size_t)((b*NH + yblk)*HD + d) * SN + sr0;
#pragma unroll
    for (int i = 0; i < 4; ++i)
      reinterpret_cast<uint4*>(dst)[i] = reinterpret_cast<const uint4*>(src)[i];
  }
}

__global__ void transpose_pe_fb(const float* __restrict__ pe, bf16* __restrict__ peT) {
  int idx = blockIdx.x * 256 + threadIdx.x;
  int l = idx >> 6, d = idx & 63;
  peT[idx] = __float2bfloat16(pe[d * SL + l]);
}

#define MT 16
#define CSTR 84
#define PSTR 65
#define BSTR 104
#define QSTR 72

__global__ __launch_bounds__(128) void attn_kernel_fb(
    const float* __restrict__ query, const float* __restrict__ Wq,
    const bf16* __restrict__ Kh, const bf16* __restrict__ VT,
    const bf16* __restrict__ peT, const float* __restrict__ spanv,
    bf16* __restrict__ ctx) {
  __shared__ __align__(16) float cont_lds[MT][CSTR];
  __shared__ __align__(16) float pos_lds[MT][PSTR];
  __shared__ __align__(16) bf16  P_lds[MT][BSTR];
  __shared__ __align__(16) bf16  q_lds[MT*QSTR];
  __shared__ float alpha_lds[MT];
  __shared__ float S_lds[MT];

  const int id = blockIdx.x;
  const int h  = id & 7;
  const int s_ = id >> 3;
  const int m0 = (s_ & 31) * MT;
  const int b  = s_ >> 5;
  const int hb = b * 8 + h;
  const int tid  = threadIdx.x;
  const int lane = tid & 63;
  const int w    = tid >> 6;
  const int col16 = lane & 15, quad = lane >> 4, kq = quad << 3;
  const int wr = quad << 2;

  for (int i = tid; i < MT * BSTR; i += 128)
    (&P_lds[0][0])[i] = __float2bfloat16(0.0f);

  bf16x8 qf0, qf1;
  {
    f32x4 qa0 = {0.f,0.f,0.f,0.f}, qa1 = qa0;
    const float* xq = query + (size_t)(b*SM + m0 + col16) * SH + kq;
    const float* w0 = Wq + (size_t)(h*HD + w*32 + col16) * SH + kq;
    const float* w1 = w0 + (size_t)16 * SH;
#pragma unroll
    for (int k0 = 0; k0 < SH; k0 += 32) {
      bf16x8 xa = ld8any(xq + k0);
      qa0 = mfma16(xa, ld8any(w0 + k0), qa0);
      qa1 = mfma16(xa, ld8any(w1 + k0), qa1);
    }
#pragma unroll
    for (int r = 0; r < 4; ++r) {
      q_lds[(wr + r)*QSTR + w*32 + col16]      = __float2bfloat16(qa0[r]);
      q_lds[(wr + r)*QSTR + w*32 + 16 + col16] = __float2bfloat16(qa1[r]);
    }
    __syncthreads();
    qf0 = ld8any(&q_lds[col16*QSTR + kq]);
    qf1 = ld8any(&q_lds[col16*QSTR + kq + 32]);
  }

  const bf16* kb = Kh + (size_t)(hb * SN) * HD + kq;
  const bf16* vb = VT + (size_t)(hb * HD) * SN;

  const int srow = tid >> 3, sj = tid & 7;
  float Mrun = -1.0e30f, Srun = 0.0f;
  const float span = spanv[h];
  const int dt0 = w * 16, dt1 = (w + 2) * 16;
  f32x4 o0 = {0.f,0.f,0.f,0.f}, o1 = o0;

  for (int ch = 0; ch < 16; ++ch) {
    const int l0 = ch << 6;
    const int nb_ = m0 + l0;

    f32x4 ca0 = {0.f,0.f,0.f,0.f}, ca1 = ca0, ca2 = ca0, pa0 = ca0, pa1 = ca0;
    {
      const bf16* kr0 = kb + (size_t)(nb_ + w*16 + col16) * HD;
      ca0 = mfma16(qf0, ld8any(kr0),           ca0);
      ca0 = mfma16(qf1, ld8any(kr0 + 32),      ca0);
      const bf16* kr1 = kr0 + 32 * HD;
      ca1 = mfma16(qf0, ld8any(kr1),           ca1);
      ca1 = mfma16(qf1, ld8any(kr1 + 32),      ca1);
      if (w == 0) {
        const bf16* kr2 = kr0 + 64 * HD;
        ca2 = mfma16(qf0, ld8any(kr2),         ca2);
        ca2 = mfma16(qf1, ld8any(kr2 + 32),    ca2);
      }
      const bf16* pr0 = peT + (size_t)(l0 + w*16 + col16) * HD + kq;
      pa0 = mfma16(qf0, ld8any(pr0),           pa0);
      pa0 = mfma16(qf1, ld8any(pr0 + 32),      pa0);
      const bf16* pr1 = pr0 + 32 * HD;
      pa1 = mfma16(qf0, ld8any(pr1),           pa1);
      pa1 = mfma16(qf1, ld8any(pr1 + 32),      pa1);
    }
#pragma unroll
    for (int r = 0; r < 4; ++r) {
      cont_lds[wr + r][w*16 + col16]      = ca0[r];
      cont_lds[wr + r][w*16 + 32 + col16] = ca1[r];
      if (w == 0) cont_lds[wr + r][64 + col16] = ca2[r];
      pos_lds[wr + r][w*16 + col16]       = pa0[r];
      pos_lds[wr + r][w*16 + 32 + col16]  = pa1[r];
    }
    __syncthreads();

    float sc[8];
    float mc = -1.0e30f;
    const float* crow = &cont_lds[srow][srow + sj*8];
    const float* prow = &pos_lds[srow][sj*8];
#pragma unroll
    for (int i = 0; i < 8; ++i) {
      float v = (crow[i] + prow[i]) * 0.125f;
      sc[i] = v;
      mc = fmaxf(mc, v);
    }
    mc = fmaxf(mc, __shfl_xor(mc, 1));
    mc = fmaxf(mc, __shfl_xor(mc, 2));
    mc = fmaxf(mc, __shfl_xor(mc, 4));
    const float Mnew = fmaxf(Mrun, mc);
    const float alpha = __expf(Mrun - Mnew);
    float ls = 0.0f;
    bf16* pwrow = &P_lds[srow][srow + sj*8];
#pragma unroll
    for (int i = 0; i < 8; ++i) {
      float p = __expf(sc[i] - Mnew);
      ls += p;
      const float tpl = (float)(l0 + sj*8 + i) - 1023.0f;
      float mv = (tpl + span * 1024.0f) * 0.03125f + 1.0f;
      mv = fminf(fmaxf(mv, 0.0f), 1.0f);
      pwrow[i] = __float2bfloat16(p * mv);
    }
    ls += __shfl_xor(ls, 1);
    ls += __shfl_xor(ls, 2);
    ls += __shfl_xor(ls, 4);
    Srun = Srun * alpha + ls;
    Mrun = Mnew;
    if (sj == 0) { alpha_lds[srow] = alpha; S_lds[srow] = Srun; }
    __syncthreads();

    float al[4];
#pragma unroll
    for (int r = 0; r < 4; ++r) al[r] = alpha_lds[wr + r];
#pragma unroll
    for (int r = 0; r < 4; ++r) { o0[r] *= al[r]; o1[r] *= al[r]; }
#pragma unroll
    for (int ks = 0; ks < 3; ++ks) {
      const bf16x8 ap = ld8any(&P_lds[col16][ks*32 + kq]);
      const bf16* v0 = vb + (size_t)(dt0 + col16) * SN + nb_ + ks*32 + kq;
      const bf16* v1 = vb + (size_t)(dt1 + col16) * SN + nb_ + ks*32 + kq;
      o0 = mfma16(ap, ld8any(v0), o0);
      o1 = mfma16(ap, ld8any(v1), o1);
    }
  }

  bf16* cr = ctx + (size_t)(b*SM + m0 + wr) * SH + h*HD + col16;
#pragma unroll
  for (int r = 0; r < 4; ++r) {
    const float inv = 1.0f / S_lds[wr + r];
    cr[(size_t)r * SH + dt0] = __float2bfloat16(o0[r] * inv);
    cr[(size_t)r * SH + dt1] = __float2bfloat16(o1[r] * inv);
  }
}

// ---------------------------------------------------------------------------
extern "C" void kernel_launch(void* const* d_in, const int* in_sizes, int n_in,
                              void* d_out, int out_size, void* d_ws, size_t ws_size,
                              hipStream_t stream) {
  const float* query  = (const float*)d_in[0];
  const float* key    = (const float*)d_in[1];
  const float* value  = (const float*)d_in[2];
  const float* key_pe = (const float*)d_in[3];
  const float* Wq     = (const float*)d_in[4];
  const float* Wk     = (const float*)d_in[5];
  const float* Wv     = (const float*)d_in[6];
  const float* Wo     = (const float*)d_in[7];
  const float* spanv  = (const float*)d_in[8];
  float* out = (float*)d_out;

  bf16* ws = (bf16*)d_ws;
  if (ws_size >= (size_t)48365568) {
    // Path C: fully fragment-linear pipeline, 5 launches, 48.4 MB ws.
    // B0: stgK -> vF.  B1: stgV.  B2: kF.  ctxC: qF staging -> attn ctx.
    bf16* B0   = ws;                      // 6291456
    bf16* B1   = B0  + 6291456;           // 6291456
    bf16* B2   = B1  + 6291456;           // 6291456
    bf16* qp   = B2  + 6291456;           // 2097152
    bf16* ctxC = qp  + 2097152;           // 2097152 (qF staging, then ctx)
    bf16* peF  = ctxC + 2097152;          // 65536
    bf16* Wb   = peF + 65536;             // 1048576
    bf16* Wq_b = Wb, *Wk_b = Wb + 262144, *Wv_b = Wb + 524288, *Wo_b = Wb + 786432;

    // L1: all conversions, LDS-staged, coalesced both sides.
    prep_all<<<1952, 256, 0, stream>>>(key, value, query, Wq, Wk, Wv, Wo,
                                       key_pe, B0, B1, ctxC, Wb, peF);
    // L2: K-projection (B0->B2) + Q-projection (ctxC->qp), disjoint R/W.
    gemmKQ<<<512, 256, 0, stream>>>(B0, Wk_b, B2, ctxC, Wq_b, qp);
    // L3: V-projection into the now-dead stgK region (B1->B0).
    gemmV<<<384, 256, 0, stream>>>(B1, Wv_b, B0);
    // L4: fused attention (overwrites ctxC).
    attn1w<<<2048, 64, 0, stream>>>(qp, B2, B0, peF, spanv, ctxC);
    // L5: output projection.
    gemmO<<<128, 256, 0, stream>>>(ctxC, Wo_b, out);
  } else {
    // Path B (fallback): fused-q attention, f32 GEMM reads, 29.5 MB ws.
    bf16* k_head = ws;
    bf16* vT     = k_head + 6291456;
    bf16* ctx    = vT     + 6291456;
    bf16* peT    = ctx    + 2097152;
    gemmbn64<1, float, float, bf16><<<768, 256, 0, stream>>>(key,   Wk, k_head);
    gemmbn64<2, float, float, bf16><<<768, 256, 0, stream>>>(value, Wv, vT);
    transpose_pe_fb<<<256, 256, 0, stream>>>(key_pe, peT);
    attn_kernel_fb<<<2048, 128, 0, stream>>>(query, Wq, k_head, vT,
                                             peT, spanv, ctx);
    gemmbn64<0, bf16, float, float><<<256, 256, 0, stream>>>(ctx, Wo, out);
  }
}

// Round 10
// 183.687 us; speedup vs baseline: 2.0247x; 1.0136x over previous
//
#include <hip/hip_runtime.h>
#include <hip/hip_bf16.h>
#include <type_traits>

typedef __hip_bfloat16 bf16;
typedef short bf16x8 __attribute__((ext_vector_type(8)));
typedef float f32x4 __attribute__((ext_vector_type(4)));
typedef short short4_ __attribute__((ext_vector_type(4)));

#define NB 8      // batch
#define SM 512    // block size M
#define SL 1024   // attn span L
#define SH 512    // hidden
#define NH 8      // heads
#define HD 64     // head dim
#define SN 1536   // M + L (key length)

static __device__ __forceinline__ short bf_bits(float x) {
  union { bf16 b; short s; } u; u.b = __float2bfloat16(x); return u.s;
}
static __device__ __forceinline__ bf16x8 ld8any(const bf16* p) {
  return *reinterpret_cast<const bf16x8*>(p);
}
static __device__ __forceinline__ bf16x8 ld8any(const float* p) {
  float4 a = *reinterpret_cast<const float4*>(p);
  float4 b = *reinterpret_cast<const float4*>(p + 4);
  bf16x8 r;
  r[0] = bf_bits(a.x); r[1] = bf_bits(a.y); r[2] = bf_bits(a.z); r[3] = bf_bits(a.w);
  r[4] = bf_bits(b.x); r[5] = bf_bits(b.y); r[6] = bf_bits(b.z); r[7] = bf_bits(b.w);
  return r;
}
static __device__ __forceinline__ void st1(bf16* p, float v) { *p = __float2bfloat16(v); }
static __device__ __forceinline__ void st1(float* p, float v) { *p = v; }
static __device__ __forceinline__ f32x4 mfma16(bf16x8 a, bf16x8 b, f32x4 c) {
  return __builtin_amdgcn_mfma_f32_16x16x32_bf16(a, b, c, 0, 0, 0);
}

// ---------------------------------------------------------------------------
// Universal fragment-linear layout for an [R x C] matrix (C = 512):
//   FRAGIDX(row,col) = (row>>4)*8192 + (col>>5)*512
//                    + ((col>>3)&3)*128 + (row&15)*8 + (col&7)
// One wave MFMA fragment (16 rows x 32 cols) = 1KB contiguous, lane*16B.
// ---------------------------------------------------------------------------

// ---------------------------------------------------------------------------
// prep_all: all input conversions, ONE launch, LDS-staged so BOTH the
// f32 row-major reads AND the fragment-linear bf16 writes are coalesced.
// ---------------------------------------------------------------------------
__global__ __launch_bounds__(256) void prep_all(
    const float* __restrict__ key, const float* __restrict__ value,
    const float* __restrict__ query,
    const float* __restrict__ Wq, const float* __restrict__ Wk,
    const float* __restrict__ Wv, const float* __restrict__ Wo,
    const float* __restrict__ pe,
    bf16* __restrict__ kS, bf16* __restrict__ vS, bf16* __restrict__ qS,
    bf16* __restrict__ Wb, bf16* __restrict__ peF) {
  __shared__ __align__(16) bf16 t[16 * 520];
  const int id = blockIdx.x, tid = threadIdx.x;
  if (id < 1920) {
    const float* src; bf16* dst;
    if (id < 768)       { src = key   + (size_t)id * 8192;
                          dst = kS    + (size_t)id * 8192; }
    else if (id < 1536) { src = value + (size_t)(id - 768) * 8192;
                          dst = vS    + (size_t)(id - 768) * 8192; }
    else if (id < 1792) { src = query + (size_t)(id - 1536) * 8192;
                          dst = qS    + (size_t)(id - 1536) * 8192; }
    else {
      const int s = id - 1792;
      const float* ws_[4] = {Wq, Wk, Wv, Wo};
      src = ws_[s >> 5] + (size_t)(s & 31) * 8192;
      dst = Wb + (size_t)(s >> 5) * 262144 + (size_t)(s & 31) * 8192;
    }
#pragma unroll
    for (int j = 0; j < 4; ++j) {
      const int i = j * 2048 + tid * 8;
      const bf16x8 v = ld8any(src + i);
      *reinterpret_cast<bf16x8*>(&t[(i >> 9) * 520 + (i & 511)]) = v;
    }
    __syncthreads();
#pragma unroll
    for (int j = 0; j < 4; ++j) {
      const int a = j * 2048 + tid * 8;
      const int kt5 = a >> 9, rest = a & 511;
      const int q = rest >> 7, rowl = (rest >> 3) & 15;
      *reinterpret_cast<bf16x8*>(dst + a) =
          *reinterpret_cast<const bf16x8*>(&t[rowl * 520 + kt5 * 32 + q * 8]);
    }
  } else {
    const int idx = (id - 1920) * 256 + tid;
    const int l = idx >> 6, d = idx & 63;
    peF[(size_t)((l >> 4) * 2 + (d >> 5)) * 512
        + (size_t)((((d >> 3) & 3) * 16 + (l & 15)) * 8 + (d & 7))]
      = __float2bfloat16(pe[d * SL + l]);
  }
}

// ---------------------------------------------------------------------------
// gemm_dev2: Y[R x 512] = X @ W^T, X/W fragment-linear, BM=128 x BN=128,
// 4 waves, wave tile 64x64. Double-buffered, sched_barrier-pinned.
// MODE 0: row-major TY. MODE 1: kF. MODE 2: vF (LDS transpose). MODE 3: qpF.
// ---------------------------------------------------------------------------
#define T2STR 136

#define GL2(AF, BF, KT)                                                      \
  {                                                                          \
    AF[0] = ld8any(xr +         (size_t)(KT) * 512);                         \
    AF[1] = ld8any(xr + 8192  + (size_t)(KT) * 512);                         \
    AF[2] = ld8any(xr + 16384 + (size_t)(KT) * 512);                         \
    AF[3] = ld8any(xr + 24576 + (size_t)(KT) * 512);                         \
    BF[0] = ld8any(wr +         (size_t)(KT) * 512);                         \
    BF[1] = ld8any(wr + 8192  + (size_t)(KT) * 512);                         \
    BF[2] = ld8any(wr + 16384 + (size_t)(KT) * 512);                         \
    BF[3] = ld8any(wr + 24576 + (size_t)(KT) * 512);                         \
  }

template <int MODE, typename TY>
static __device__ __forceinline__ void gemm_dev2(const bf16* __restrict__ XF,
                                                 const bf16* __restrict__ WF,
                                                 TY* __restrict__ Y,
                                                 int id, bf16* tile) {
  const int yblk = id & 3, xblk = id >> 2;
  const int tid  = threadIdx.x;
  const int lane = tid & 63, w = tid >> 6;
  const int col16 = lane & 15, quad = lane >> 4;
  const int lane8 = lane * 8;
  const int wm = w >> 1, wn = w & 1;
  const int m0 = xblk * 128 + wm * 64;
  const int n0 = yblk * 128 + wn * 64;
  const bf16* xr = XF + (size_t)(m0 >> 4) * 8192 + lane8;
  const bf16* wr = WF + (size_t)(n0 >> 4) * 8192 + lane8;
  f32x4 acc[4][4];
#pragma unroll
  for (int i = 0; i < 4; ++i)
#pragma unroll
    for (int j = 0; j < 4; ++j) acc[i][j] = f32x4{0.f,0.f,0.f,0.f};

  bf16x8 afA[4], bfA[4], afB[4], bfB[4];
  GL2(afA, bfA, 0);
  __builtin_amdgcn_sched_barrier(0);
#pragma unroll
  for (int kt = 0; kt < 16; kt += 2) {
    GL2(afB, bfB, kt + 1);
    __builtin_amdgcn_sched_barrier(0);
#pragma unroll
    for (int mt = 0; mt < 4; ++mt)
#pragma unroll
      for (int nt = 0; nt < 4; ++nt)
        acc[mt][nt] = mfma16(afA[mt], bfA[nt], acc[mt][nt]);
    const int ktn = (kt + 2 < 16) ? kt + 2 : kt;  // last: dead reload
    GL2(afA, bfA, ktn);
    __builtin_amdgcn_sched_barrier(0);
#pragma unroll
    for (int mt = 0; mt < 4; ++mt)
#pragma unroll
      for (int nt = 0; nt < 4; ++nt)
        acc[mt][nt] = mfma16(afB[mt], bfB[nt], acc[mt][nt]);
  }

  if constexpr (MODE == 0) {
#pragma unroll
    for (int mt = 0; mt < 4; ++mt)
#pragma unroll
      for (int r = 0; r < 4; ++r) {
        const int row = m0 + mt*16 + quad*4 + r;
        TY* yr = Y + (size_t)row * SH + n0 + col16;
#pragma unroll
        for (int nt = 0; nt < 4; ++nt) st1(yr + nt*16, acc[mt][nt][r]);
      }
  } else if constexpr (MODE == 1) {
    const int dq = col16 >> 3, de = col16 & 7;
    const int head = n0 >> 6;
#pragma unroll
    for (int mt = 0; mt < 4; ++mt)
#pragma unroll
      for (int r = 0; r < 4; ++r) {
        const int row = m0 + mt*16 + quad*4 + r;
        const int b = row / SN, sr = row - b * SN;
        bf16* yr = (bf16*)Y
            + (((size_t)(b*NH + head)*96 + (sr>>4))*2)*512
            + (size_t)((sr&15)*8 + de);
#pragma unroll
        for (int nt = 0; nt < 4; ++nt)
          yr[(nt>>1)*512 + ((nt&1)*2 + dq)*128] = __float2bfloat16(acc[mt][nt][r]);
      }
  } else if constexpr (MODE == 3) {
    const int dq = col16 >> 3, de = col16 & 7;
    const int c5b = n0 >> 5;
#pragma unroll
    for (int mt = 0; mt < 4; ++mt)
#pragma unroll
      for (int r = 0; r < 4; ++r) {
        bf16* yr = (bf16*)Y + (size_t)((m0>>4) + mt) * 8192
                 + (size_t)((quad*4 + r)*8 + de);
#pragma unroll
        for (int nt = 0; nt < 4; ++nt)
          yr[(c5b + (nt>>1))*512 + ((nt&1)*2 + dq)*128] = __float2bfloat16(acc[mt][nt][r]);
      }
  } else {
    // vF via LDS transpose: tile[d 0..127][row_loc 0..127]
#pragma unroll
    for (int mt = 0; mt < 4; ++mt)
#pragma unroll
      for (int r = 0; r < 4; ++r) {
        const int row_loc = wm*64 + mt*16 + quad*4 + r;
#pragma unroll
        for (int nt = 0; nt < 4; ++nt) {
          const int d = wn*64 + nt*16 + col16;
          tile[d * T2STR + row_loc] = __float2bfloat16(acc[mt][nt][r]);
        }
      }
    __syncthreads();
    const int d  = tid >> 1;      // 0..127
    const int hq = tid & 1;       // 64-row half
    const bf16* src = tile + d * T2STR + hq * 64;
    const int row0 = xblk*128 + hq*64;
    const int b = row0 / SN, sr0 = row0 - b * SN;
    const int head = yblk*2 + (d >> 6);
    const int dd = d & 63;
    bf16* dstF = (bf16*)Y + (((size_t)(b*NH + head)*4 + (dd>>4))*96)*256
               + (size_t)(dd&15)*8;
#pragma unroll
    for (int i = 0; i < 8; ++i) {
      const int key = sr0 + i*8;
      const size_t off = (size_t)(key>>4)*256 + (size_t)((key>>3)&1)*128;
      *reinterpret_cast<uint4*>(dstF + off) = reinterpret_cast<const uint4*>(src)[i];
    }
  }
}

// Merged K+Q projection: [0,384) K-proj (mode 1), [384,512) Q-proj (mode 3).
__global__ __launch_bounds__(256, 2) void gemmKQ(
    const bf16* __restrict__ XK, const bf16* __restrict__ WK, bf16* __restrict__ YK,
    const bf16* __restrict__ XQ, const bf16* __restrict__ WQ, bf16* __restrict__ YQ) {
  __shared__ bf16 dummy[8];
  const int id = blockIdx.x;
  if (id < 384) gemm_dev2<1, bf16>(XK, WK, YK, id, dummy);
  else          gemm_dev2<3, bf16>(XQ, WQ, YQ, id - 384, dummy);
}

__global__ __launch_bounds__(256, 2) void gemmV(
    const bf16* __restrict__ XF, const bf16* __restrict__ WF, bf16* __restrict__ Y) {
  __shared__ __align__(16) bf16 tile[128 * T2STR];
  gemm_dev2<2, bf16>(XF, WF, Y, blockIdx.x, tile);
}

// ---------------------------------------------------------------------------
// gemmO: 64x32 wave tile (BM=128, BN=64), grid (4096/128)*8 = 256 blocks
// -> full-GPU coverage (the 128x128 variant only filled half the CUs).
// ---------------------------------------------------------------------------
#define GLO(AF, BF, KT)                                                      \
  {                                                                          \
    AF[0] = ld8any(xr +         (size_t)(KT) * 512);                         \
    AF[1] = ld8any(xr + 8192  + (size_t)(KT) * 512);                         \
    AF[2] = ld8any(xr + 16384 + (size_t)(KT) * 512);                         \
    AF[3] = ld8any(xr + 24576 + (size_t)(KT) * 512);                         \
    BF[0] = ld8any(wr +         (size_t)(KT) * 512);                         \
    BF[1] = ld8any(wr + 8192  + (size_t)(KT) * 512);                         \
  }

__global__ __launch_bounds__(256, 2) void gemmO(
    const bf16* __restrict__ XF, const bf16* __restrict__ WF, float* __restrict__ Y) {
  const int id   = blockIdx.x;
  const int s_   = id >> 3;
  const int xblk = (id & 7) + 8 * (s_ >> 3);
  const int yblk = s_ & 7;
  const int tid  = threadIdx.x;
  const int lane = tid & 63, w = tid >> 6;
  const int col16 = lane & 15, quad = lane >> 4;
  const int lane8 = lane * 8;
  const int wm = w >> 1, wn = w & 1;
  const int m0 = xblk * 128 + wm * 64;
  const int n0 = yblk * 64 + wn * 32;
  const bf16* xr = XF + (size_t)(m0 >> 4) * 8192 + lane8;
  const bf16* wr = WF + (size_t)(n0 >> 4) * 8192 + lane8;
  f32x4 acc[4][2];
#pragma unroll
  for (int i = 0; i < 4; ++i)
#pragma unroll
    for (int j = 0; j < 2; ++j) acc[i][j] = f32x4{0.f,0.f,0.f,0.f};

  bf16x8 afA[4], bfA[2], afB[4], bfB[2];
  GLO(afA, bfA, 0);
  __builtin_amdgcn_sched_barrier(0);
#pragma unroll
  for (int kt = 0; kt < 16; kt += 2) {
    GLO(afB, bfB, kt + 1);
    __builtin_amdgcn_sched_barrier(0);
#pragma unroll
    for (int mt = 0; mt < 4; ++mt)
#pragma unroll
      for (int nt = 0; nt < 2; ++nt)
        acc[mt][nt] = mfma16(afA[mt], bfA[nt], acc[mt][nt]);
    const int ktn = (kt + 2 < 16) ? kt + 2 : kt;
    GLO(afA, bfA, ktn);
    __builtin_amdgcn_sched_barrier(0);
#pragma unroll
    for (int mt = 0; mt < 4; ++mt)
#pragma unroll
      for (int nt = 0; nt < 2; ++nt)
        acc[mt][nt] = mfma16(afB[mt], bfB[nt], acc[mt][nt]);
  }
#pragma unroll
  for (int mt = 0; mt < 4; ++mt)
#pragma unroll
    for (int r = 0; r < 4; ++r) {
      const int row = m0 + mt*16 + quad*4 + r;
      float* yr = Y + (size_t)row * SH + n0 + col16;
      yr[0]  = acc[mt][0][r];
      yr[16] = acc[mt][1][r];
    }
}

// ---------------------------------------------------------------------------
// Barrier-free wave-private fused attention (v10).
// One 64-lane wave owns 16 query rows; grid 2048 x 64 threads.
// Operand-swapped MFMAs keep lane&15 == query-row in EVERY phase; coalesced
// 1KB fragment loads; sched_barrier-pinned register prefetch.
// v10 VALU cuts (softmax hot loop):
//  - mask fold: validity is ch-invariant -> per-lane bias[t][r] in {0,-1e30},
//    per-slot cmp+cndmask+mul+add -> add+fma.
//  - mv ramp: affine in (t,r,ch) -> precomputed mvs[t][r] + per-chunk offset,
//    per-slot cvt+fma+min+max -> add+clamp.
//  - defer-max (T13): skip O-rescale & keep old max when growth <= 8
//    (wave-uniform; P bounded by e^8, bf16-safe).
// ---------------------------------------------------------------------------
#define PSTR1 69    // pos stride (f32): scalar writes, b128-aligned reads
#define BSTR1 104   // P stride (bf16): b64 writes, b128 reads aligned

__global__ __launch_bounds__(64, 2) void attn1w(
    const bf16* __restrict__ qp, const bf16* __restrict__ Kh,
    const bf16* __restrict__ VT, const bf16* __restrict__ peT,
    const float* __restrict__ spanv, bf16* __restrict__ ctx) {
  __shared__ __align__(16) float pos_s[16 * PSTR1];
  __shared__ __align__(16) bf16  P_s[16 * BSTR1];

  const int id = blockIdx.x;
  const int h  = id & 7;
  const int s_ = id >> 3;
  const int m0 = (s_ & 31) * 16;
  const int b  = s_ >> 5;
  const int hb = b * 8 + h;
  const int lane  = threadIdx.x;
  const int col16 = lane & 15, quad = lane >> 4, kq = quad << 3;
  const int q4 = quad << 2;
  const int lane8 = lane * 8;

  // zero P band once (cols 80..103 stay zero; read by ks=2 PV fragment)
  for (int i = lane; i < 16 * BSTR1; i += 64)
    P_s[i] = __float2bfloat16(0.0f);

  // q from fragment-linear qp: rt*8192 + h*1024 + lane*8 (and +512)
  const bf16* qb = qp + (size_t)((b*SM + m0) >> 4) * 8192 + h*1024 + lane8;
  const bf16x8 qf0 = ld8any(qb), qf1 = ld8any(qb + 512);

  const bf16* kbF = Kh + (size_t)hb * 98304 + lane8;   // 96 tiles * 1024
  const bf16* vbF = VT + (size_t)hb * 98304 + lane8;   // 4 dt * 96 kt * 256
  const bf16* pbF = peT + lane8;

  float Mrun = -1.0e30f, Srun = 0.0f;
  const float span1024 = spanv[h] * 1024.0f;
  f32x4 o[4];
#pragma unroll
  for (int dt = 0; dt < 4; ++dt) o[dt] = f32x4{0.f,0.f,0.f,0.f};

  // loop-invariant per-lane softmax constants (registers are free here:
  // 112 VGPR base, cap 256 at 2 waves/SIMD)
  float bias_[5][4], mvs_[5][4];
  {
    const float mvb = ((float)(q4 - col16 - 1023) + span1024) * 0.03125f + 1.0f;
#pragma unroll
    for (int t = 0; t < 5; ++t)
#pragma unroll
      for (int r = 0; r < 4; ++r) {
        const int l = 16*t + q4 + r - col16;
        bias_[t][r] = ((unsigned)l < 64u) ? 0.0f : -1.0e30f;
        mvs_[t][r]  = mvb + (float)(16*t + r) * 0.03125f;
      }
  }

  // prefetched operand fragments (single-buffered; WAR ordering via reg deps)
  bf16x8 kf[5][2], pf[4][2], vf[4][3];

  // ---- prologue: chunk-0 operands ----
  {
    const int tk0 = m0 >> 4;
#pragma unroll
    for (int t = 0; t < 5; ++t) {
      const bf16* kr = kbF + (size_t)(tk0 + t) * 1024;
      kf[t][0] = ld8any(kr); kf[t][1] = ld8any(kr + 512);
    }
#pragma unroll
    for (int t = 0; t < 4; ++t) {
      const bf16* pr = pbF + (size_t)t * 1024;
      pf[t][0] = ld8any(pr); pf[t][1] = ld8any(pr + 512);
    }
#pragma unroll
    for (int dt = 0; dt < 4; ++dt) {
      const bf16* v0 = vbF + (size_t)dt * 24576 + (size_t)tk0 * 256;
#pragma unroll
      for (int ks = 0; ks < 3; ++ks) vf[dt][ks] = ld8any(v0 + ks*512);
    }
    __builtin_amdgcn_sched_barrier(0);
  }

  const int posw = col16 * PSTR1 + q4;        // write base (scalar f32)
  const int posr = col16 * (PSTR1 - 1) + q4;  // read base (b128-aligned)
  const int pww  = col16 * BSTR1 + q4;        // P write base (b64-aligned)
  const int pwr  = col16 * BSTR1 + kq;        // P read base (b128-aligned)

  for (int ch = 0; ch < 16; ++ch) {
    const int l0 = ch << 6;

    // ---- pos MFMAs (swapped: A=pe rows, D rows = l, cols = q-row) ----
    f32x4 pacc[4];
#pragma unroll
    for (int t = 0; t < 4; ++t) {
      f32x4 a = {0.f,0.f,0.f,0.f};
      a = mfma16(pf[t][0], qf0, a);
      a = mfma16(pf[t][1], qf1, a);
      pacc[t] = a;
    }
#pragma unroll
    for (int t = 0; t < 4; ++t)
#pragma unroll
      for (int r = 0; r < 4; ++r)
        pos_s[posw + 16*t + r] = pacc[t][r];

    // ---- cont MFMAs (swapped: A=K rows, D rows = band pos, cols = q-row) ----
    f32x4 cacc[5];
#pragma unroll
    for (int t = 0; t < 5; ++t) {
      f32x4 a = {0.f,0.f,0.f,0.f};
      a = mfma16(kf[t][0], qf0, a);
      a = mfma16(kf[t][1], qf1, a);
      cacc[t] = a;
    }

    // ---- issue next chunk's K/pe (kf/pf regs now dead); pinned ----
    {
      const int l0n = (ch < 15) ? l0 + 64 : l0;
      const int tkn = (m0 + l0n) >> 4;
      const int tpn = l0n >> 4;
#pragma unroll
      for (int t = 0; t < 5; ++t) {
        const bf16* kr = kbF + (size_t)(tkn + t) * 1024;
        kf[t][0] = ld8any(kr); kf[t][1] = ld8any(kr + 512);
      }
#pragma unroll
      for (int t = 0; t < 4; ++t) {
        const bf16* pr = pbF + (size_t)(tpn + t) * 1024;
        pf[t][0] = ld8any(pr); pf[t][1] = ld8any(pr + 512);
      }
      __builtin_amdgcn_sched_barrier(0);
    }

    // ---- per-lane softmax over this row's 64-key window ----
    float sc[5][4];
    float mc = -1.0e30f;
#pragma unroll
    for (int t = 0; t < 5; ++t) {
      const f32x4 pv4 = *reinterpret_cast<const f32x4*>(&pos_s[posr + 16*t]);
#pragma unroll
      for (int r = 0; r < 4; ++r) {
        const float v = fmaf(cacc[t][r] + pv4[r], 0.125f, bias_[t][r]);
        sc[t][r] = v;
        mc = fmaxf(mc, v);
      }
    }
    mc = fmaxf(mc, __shfl_xor(mc, 16));
    mc = fmaxf(mc, __shfl_xor(mc, 32));
    const float Mnew = fmaxf(Mrun, mc);
    const bool defer = __all(Mnew - Mrun <= 8.0f);
    const float Mb = defer ? Mrun : Mnew;      // wave-uniform select
    const float chf = (float)ch * 2.0f;        // l0 * 0.03125
    float ls = 0.0f;
#pragma unroll
    for (int t = 0; t < 5; ++t) {
      short4_ pk;
#pragma unroll
      for (int r = 0; r < 4; ++r) {
        const float p = __expf(sc[t][r] - Mb);  // 0 for masked slots
        ls += p;
        float mv = mvs_[t][r] + chf;
        mv = fminf(fmaxf(mv, 0.0f), 1.0f);
        pk[r] = bf_bits(p * mv);
      }
      *reinterpret_cast<short4_*>(&P_s[pww + 16*t]) = pk;
    }
    ls += __shfl_xor(ls, 16);
    ls += __shfl_xor(ls, 32);

    if (defer) {
      Srun += ls;                 // no rescale, Mrun unchanged
    } else {
      const float alpha = __expf(Mrun - Mnew);
      Srun = Srun * alpha + ls;
      Mrun = Mnew;
#pragma unroll
      for (int dt = 0; dt < 4; ++dt)
#pragma unroll
        for (int r = 0; r < 4; ++r) o[dt][r] *= alpha;
    }

    // ---- PV (swapped: A=V^T rows=d, B=P cols=q-row) ----
#pragma unroll
    for (int ks = 0; ks < 3; ++ks) {
      const bf16x8 ap = ld8any(&P_s[pwr + ks*32]);
#pragma unroll
      for (int dt = 0; dt < 4; ++dt)
        o[dt] = mfma16(vf[dt][ks], ap, o[dt]);
    }

    // ---- issue next chunk's V (vf regs now dead); pinned ----
    {
      const int tkn = (m0 + ((ch < 15) ? l0 + 64 : l0)) >> 4;
#pragma unroll
      for (int dt = 0; dt < 4; ++dt) {
        const bf16* v0 = vbF + (size_t)dt * 24576 + (size_t)tkn * 256;
#pragma unroll
        for (int ks = 0; ks < 3; ++ks) vf[dt][ks] = ld8any(v0 + ks*512);
      }
      __builtin_amdgcn_sched_barrier(0);
    }
  }

  // ---- epilogue: lane-local normalize, fragment-linear ctx stores ----
  const float inv = 1.0f / Srun;
  bf16* crb = ctx + (size_t)((b*SM + m0) >> 4) * 8192
            + (size_t)(h*1024 + (quad>>1)*128 + col16*8 + (quad&1)*4);
#pragma unroll
  for (int dt = 0; dt < 4; ++dt) {
    short4_ pk;
#pragma unroll
    for (int r = 0; r < 4; ++r) pk[r] = bf_bits(o[dt][r] * inv);
    *reinterpret_cast<short4_*>(crb + (size_t)(dt>>1)*512 + (dt&1)*256) = pk;
  }
}

// ---------------------------------------------------------------------------
// Fallback path kernels (round-6 proven, old row-major layouts).
// ---------------------------------------------------------------------------
template <int MODE, typename TX, typename TW, typename TY>
__global__ __launch_bounds__(256) void gemmbn64(const TX* __restrict__ X,
                                                const TW* __restrict__ W,
                                                TY* __restrict__ Y) {
  __shared__ __align__(16) bf16 tile[(MODE == 2) ? 64 * T2STR : 8];
  const int id   = blockIdx.x;
  const int s_   = id >> 3;
  const int xblk = (id & 7) + 8 * (s_ >> 3);
  const int yblk = s_ & 7;
  const int tid  = threadIdx.x;
  const int lane = tid & 63, w = tid >> 6;
  const int col16 = lane & 15, quad = lane >> 4, kq = quad << 3;
  const int wm = w >> 1, wn = w & 1;
  const int m0 = xblk * 128 + wm * 64;
  const int n0 = yblk * 64 + wn * 32;
  const TX* xr = X + (size_t)(m0 + col16) * SH + kq;
  const TW* wr = W + (size_t)(n0 + col16) * SH + kq;
  f32x4 acc[4][2];
#pragma unroll
  for (int i = 0; i < 4; ++i)
#pragma unroll
    for (int j = 0; j < 2; ++j) acc[i][j] = f32x4{0.f,0.f,0.f,0.f};
#pragma unroll
  for (int k0 = 0; k0 < SH; k0 += 32) {
    bf16x8 af[4], bfr[2];
#pragma unroll
    for (int t = 0; t < 4; ++t) af[t]  = ld8any(xr + (size_t)(t*16) * SH + k0);
#pragma unroll
    for (int t = 0; t < 2; ++t) bfr[t] = ld8any(wr + (size_t)(t*16) * SH + k0);
#pragma unroll
    for (int mt = 0; mt < 4; ++mt)
#pragma unroll
      for (int nt = 0; nt < 2; ++nt)
        acc[mt][nt] = mfma16(af[mt], bfr[nt], acc[mt][nt]);
  }

  if constexpr (MODE == 0) {
#pragma unroll
    for (int mt = 0; mt < 4; ++mt)
#pragma unroll
      for (int r = 0; r < 4; ++r) {
        const int row = m0 + mt*16 + quad*4 + r;
        TY* yr = Y + (size_t)row * SH + n0 + col16;
        st1(yr,      acc[mt][0][r]);
        st1(yr + 16, acc[mt][1][r]);
      }
  } else if constexpr (MODE == 1) {
#pragma unroll
    for (int mt = 0; mt < 4; ++mt)
#pragma unroll
      for (int r = 0; r < 4; ++r) {
        const int row = m0 + mt*16 + quad*4 + r;
        const int b = row / SN, sr = row - b * SN;
        bf16* yr = (bf16*)Y + (size_t)((b*NH + yblk)*SN + sr) * HD
                 + wn*32 + col16;
        yr[0]  = __float2bfloat16(acc[mt][0][r]);
        yr[16] = __float2bfloat16(acc[mt][1][r]);
      }
  } else {
#pragma unroll
    for (int mt = 0; mt < 4; ++mt)
#pragma unroll
      for (int r = 0; r < 4; ++r) {
        const int row_loc = wm*64 + mt*16 + quad*4 + r;
#pragma unroll
        for (int nt = 0; nt < 2; ++nt) {
          const int d = wn*32 + nt*16 + col16;
          tile[d * T2STR + row_loc] = __float2bfloat16(acc[mt][nt][r]);
        }
      }
    __syncthreads();
    const int d  = tid >> 2;
    const int hq = tid & 3;
    const bf16* src = tile + d * T2STR + hq * 32;
    const int row0 = xblk*128 + hq*32;
    const int b = row0 / SN, sr0 = row0 - b * SN;
    bf16* dst = (bf16*)Y + (size_t)((b*NH + yblk)*HD + d) * SN + sr0;
#pragma unroll
    for (int i = 0; i < 4; ++i)
      reinterpret_cast<uint4*>(dst)[i] = reinterpret_cast<const uint4*>(src)[i];
  }
}

__global__ void transpose_pe_fb(const float* __restrict__ pe, bf16* __restrict__ peT) {
  int idx = blockIdx.x * 256 + threadIdx.x;
  int l = idx >> 6, d = idx & 63;
  peT[idx] = __float2bfloat16(pe[d * SL + l]);
}

#define MT 16
#define CSTR 84
#define PSTR 65
#define BSTR 104
#define QSTR 72

__global__ __launch_bounds__(128) void attn_kernel_fb(
    const float* __restrict__ query, const float* __restrict__ Wq,
    const bf16* __restrict__ Kh, const bf16* __restrict__ VT,
    const bf16* __restrict__ peT, const float* __restrict__ spanv,
    bf16* __restrict__ ctx) {
  __shared__ __align__(16) float cont_lds[MT][CSTR];
  __shared__ __align__(16) float pos_lds[MT][PSTR];
  __shared__ __align__(16) bf16  P_lds[MT][BSTR];
  __shared__ __align__(16) bf16  q_lds[MT*QSTR];
  __shared__ float alpha_lds[MT];
  __shared__ float S_lds[MT];

  const int id = blockIdx.x;
  const int h  = id & 7;
  const int s_ = id >> 3;
  const int m0 = (s_ & 31) * MT;
  const int b  = s_ >> 5;
  const int hb = b * 8 + h;
  const int tid  = threadIdx.x;
  const int lane = tid & 63;
  const int w    = tid >> 6;
  const int col16 = lane & 15, quad = lane >> 4, kq = quad << 3;
  const int wr = quad << 2;

  for (int i = tid; i < MT * BSTR; i += 128)
    (&P_lds[0][0])[i] = __float2bfloat16(0.0f);

  bf16x8 qf0, qf1;
  {
    f32x4 qa0 = {0.f,0.f,0.f,0.f}, qa1 = qa0;
    const float* xq = query + (size_t)(b*SM + m0 + col16) * SH + kq;
    const float* w0 = Wq + (size_t)(h*HD + w*32 + col16) * SH + kq;
    const float* w1 = w0 + (size_t)16 * SH;
#pragma unroll
    for (int k0 = 0; k0 < SH; k0 += 32) {
      bf16x8 xa = ld8any(xq + k0);
      qa0 = mfma16(xa, ld8any(w0 + k0), qa0);
      qa1 = mfma16(xa, ld8any(w1 + k0), qa1);
    }
#pragma unroll
    for (int r = 0; r < 4; ++r) {
      q_lds[(wr + r)*QSTR + w*32 + col16]      = __float2bfloat16(qa0[r]);
      q_lds[(wr + r)*QSTR + w*32 + 16 + col16] = __float2bfloat16(qa1[r]);
    }
    __syncthreads();
    qf0 = ld8any(&q_lds[col16*QSTR + kq]);
    qf1 = ld8any(&q_lds[col16*QSTR + kq + 32]);
  }

  const bf16* kb = Kh + (size_t)(hb * SN) * HD + kq;
  const bf16* vb = VT + (size_t)(hb * HD) * SN;

  const int srow = tid >> 3, sj = tid & 7;
  float Mrun = -1.0e30f, Srun = 0.0f;
  const float span = spanv[h];
  const int dt0 = w * 16, dt1 = (w + 2) * 16;
  f32x4 o0 = {0.f,0.f,0.f,0.f}, o1 = o0;

  for (int ch = 0; ch < 16; ++ch) {
    const int l0 = ch << 6;
    const int nb_ = m0 + l0;

    f32x4 ca0 = {0.f,0.f,0.f,0.f}, ca1 = ca0, ca2 = ca0, pa0 = ca0, pa1 = ca0;
    {
      const bf16* kr0 = kb + (size_t)(nb_ + w*16 + col16) * HD;
      ca0 = mfma16(qf0, ld8any(kr0),           ca0);
      ca0 = mfma16(qf1, ld8any(kr0 + 32),      ca0);
      const bf16* kr1 = kr0 + 32 * HD;
      ca1 = mfma16(qf0, ld8any(kr1),           ca1);
      ca1 = mfma16(qf1, ld8any(kr1 + 32),      ca1);
      if (w == 0) {
        const bf16* kr2 = kr0 + 64 * HD;
        ca2 = mfma16(qf0, ld8any(kr2),         ca2);
        ca2 = mfma16(qf1, ld8any(kr2 + 32),    ca2);
      }
      const bf16* pr0 = peT + (size_t)(l0 + w*16 + col16) * HD + kq;
      pa0 = mfma16(qf0, ld8any(pr0),           pa0);
      pa0 = mfma16(qf1, ld8any(pr0 + 32),      pa0);
      const bf16* pr1 = pr0 + 32 * HD;
      pa1 = mfma16(qf0, ld8any(pr1),           pa1);
      pa1 = mfma16(qf1, ld8any(pr1 + 32),      pa1);
    }
#pragma unroll
    for (int r = 0; r < 4; ++r) {
      cont_lds[wr + r][w*16 + col16]      = ca0[r];
      cont_lds[wr + r][w*16 + 32 + col16] = ca1[r];
      if (w == 0) cont_lds[wr + r][64 + col16] = ca2[r];
      pos_lds[wr + r][w*16 + col16]       = pa0[r];
      pos_lds[wr + r][w*16 + 32 + col16]  = pa1[r];
    }
    __syncthreads();

    float sc[8];
    float mc = -1.0e30f;
    const float* crow = &cont_lds[srow][srow + sj*8];
    const float* prow = &pos_lds[srow][sj*8];
#pragma unroll
    for (int i = 0; i < 8; ++i) {
      float v = (crow[i] + prow[i]) * 0.125f;
      sc[i] = v;
      mc = fmaxf(mc, v);
    }
    mc = fmaxf(mc, __shfl_xor(mc, 1));
    mc = fmaxf(mc, __shfl_xor(mc, 2));
    mc = fmaxf(mc, __shfl_xor(mc, 4));
    const float Mnew = fmaxf(Mrun, mc);
    const float alpha = __expf(Mrun - Mnew);
    float ls = 0.0f;
    bf16* pwrow = &P_lds[srow][srow + sj*8];
#pragma unroll
    for (int i = 0; i < 8; ++i) {
      float p = __expf(sc[i] - Mnew);
      ls += p;
      const float tpl = (float)(l0 + sj*8 + i) - 1023.0f;
      float mv = (tpl + span * 1024.0f) * 0.03125f + 1.0f;
      mv = fminf(fmaxf(mv, 0.0f), 1.0f);
      pwrow[i] = __float2bfloat16(p * mv);
    }
    ls += __shfl_xor(ls, 1);
    ls += __shfl_xor(ls, 2);
    ls += __shfl_xor(ls, 4);
    Srun = Srun * alpha + ls;
    Mrun = Mnew;
    if (sj == 0) { alpha_lds[srow] = alpha; S_lds[srow] = Srun; }
    __syncthreads();

    float al[4];
#pragma unroll
    for (int r = 0; r < 4; ++r) al[r] = alpha_lds[wr + r];
#pragma unroll
    for (int r = 0; r < 4; ++r) { o0[r] *= al[r]; o1[r] *= al[r]; }
#pragma unroll
    for (int ks = 0; ks < 3; ++ks) {
      const bf16x8 ap = ld8any(&P_lds[col16][ks*32 + kq]);
      const bf16* v0 = vb + (size_t)(dt0 + col16) * SN + nb_ + ks*32 + kq;
      const bf16* v1 = vb + (size_t)(dt1 + col16) * SN + nb_ + ks*32 + kq;
      o0 = mfma16(ap, ld8any(v0), o0);
      o1 = mfma16(ap, ld8any(v1), o1);
    }
  }

  bf16* cr = ctx + (size_t)(b*SM + m0 + wr) * SH + h*HD + col16;
#pragma unroll
  for (int r = 0; r < 4; ++r) {
    const float inv = 1.0f / S_lds[wr + r];
    cr[(size_t)r * SH + dt0] = __float2bfloat16(o0[r] * inv);
    cr[(size_t)r * SH + dt1] = __float2bfloat16(o1[r] * inv);
  }
}

// ---------------------------------------------------------------------------
extern "C" void kernel_launch(void* const* d_in, const int* in_sizes, int n_in,
                              void* d_out, int out_size, void* d_ws, size_t ws_size,
                              hipStream_t stream) {
  const float* query  = (const float*)d_in[0];
  const float* key    = (const float*)d_in[1];
  const float* value  = (const float*)d_in[2];
  const float* key_pe = (const float*)d_in[3];
  const float* Wq     = (const float*)d_in[4];
  const float* Wk     = (const float*)d_in[5];
  const float* Wv     = (const float*)d_in[6];
  const float* Wo     = (const float*)d_in[7];
  const float* spanv  = (const float*)d_in[8];
  float* out = (float*)d_out;

  bf16* ws = (bf16*)d_ws;
  if (ws_size >= (size_t)48365568) {
    // Path C: fully fragment-linear pipeline, 5 launches, 48.4 MB ws.
    bf16* B0   = ws;                      // stgK -> vF
    bf16* B1   = B0  + 6291456;           // stgV
    bf16* B2   = B1  + 6291456;           // kF
    bf16* qp   = B2  + 6291456;           // qpF
    bf16* ctxC = qp  + 2097152;           // qF staging, then attn ctx
    bf16* peF  = ctxC + 2097152;
    bf16* Wb   = peF + 65536;
    bf16* Wq_b = Wb, *Wk_b = Wb + 262144, *Wv_b = Wb + 524288, *Wo_b = Wb + 786432;

    prep_all<<<1952, 256, 0, stream>>>(key, value, query, Wq, Wk, Wv, Wo,
                                       key_pe, B0, B1, ctxC, Wb, peF);
    gemmKQ<<<512, 256, 0, stream>>>(B0, Wk_b, B2, ctxC, Wq_b, qp);
    gemmV<<<384, 256, 0, stream>>>(B1, Wv_b, B0);
    attn1w<<<2048, 64, 0, stream>>>(qp, B2, B0, peF, spanv, ctxC);
    gemmO<<<256, 256, 0, stream>>>(ctxC, Wo_b, out);
  } else {
    // Path B (fallback): fused-q attention, f32 GEMM reads, 29.5 MB ws.
    bf16* k_head = ws;
    bf16* vT     = k_head + 6291456;
    bf16* ctx    = vT     + 6291456;
    bf16* peT    = ctx    + 2097152;
    gemmbn64<1, float, float, bf16><<<768, 256, 0, stream>>>(key,   Wk, k_head);
    gemmbn64<2, float, float, bf16><<<768, 256, 0, stream>>>(value, Wv, vT);
    transpose_pe_fb<<<256, 256, 0, stream>>>(key_pe, peT);
    attn_kernel_fb<<<2048, 128, 0, stream>>>(query, Wq, k_head, vT,
                                             peT, spanv, ctx);
    gemmbn64<0, bf16, float, float><<<256, 256, 0, stream>>>(ctx, Wo, out);
  }
}